// Round 3
// baseline (5808.508 us; speedup 1.0000x reference)
//
#include <hip/hip_runtime.h>
#include <hip/hip_bf16.h>

#define N_NODES 10000
#define N_EDGES 320000
#define HDIM 128
#define NODE_IN 64
#define EDGE_IN 16
#define NLAYERS 4
#define EPSV 1e-8f
#define EPB 8   // edges per block in edge kernel

__device__ __forceinline__ float silu_f(float z) { return z / (1.0f + __expf(-z)); }

// dtype-dispatched load: DT=0 -> fp32, DT=1 -> bf16
template<int DT> __device__ __forceinline__ float ld(const void* p, size_t i);
template<> __device__ __forceinline__ float ld<0>(const void* p, size_t i) {
    return ((const float*)p)[i];
}
template<> __device__ __forceinline__ float ld<1>(const void* p, size_t i) {
    return __bfloat162float(((const __hip_bfloat16*)p)[i]);
}

// probe: mask is all ones. fp32 word0 = 0x3F800000 ; bf16 pair = 0x3F803F80
__global__ void probe_kernel(const unsigned* __restrict__ mask_bits, int* __restrict__ dflag) {
    if (threadIdx.x == 0 && blockIdx.x == 0)
        *dflag = (mask_bits[0] == 0x3F800000u) ? 0 : 1;
}

// ---------------- t_emb: silu(t*W1+b1)@W2+b2  (1x128) ----------------
template<int DT>
__global__ void temb_kernel(const int* dflag, const void* t, const void* tw1, const void* tb1,
                            const void* tw2, const void* tb2, float* t_emb) {
    if (*dflag != DT) return;
    __shared__ float s_a[HDIM];
    int j = threadIdx.x;
    float tv = ld<DT>(t, 0);
    s_a[j] = silu_f(tv * ld<DT>(tw1, j) + ld<DT>(tb1, j));
    __syncthreads();
    float acc = ld<DT>(tb2, j);
    for (int k = 0; k < HDIM; ++k) acc += s_a[k] * ld<DT>(tw2, k * HDIM + j);
    t_emb[j] = acc;
}

// ---------------- h_feat = h @ node_emb_w + b + t_emb ----------------
template<int DT>
__global__ void hfeat_kernel(const int* dflag, const void* h, const void* new_, const void* neb,
                             const float* __restrict__ t_emb, float* __restrict__ h_feat) {
    if (*dflag != DT) return;
    __shared__ float s_h[NODE_IN];
    int n = blockIdx.x, j = threadIdx.x;
    if (j < NODE_IN) s_h[j] = ld<DT>(h, (size_t)n * NODE_IN + j);
    __syncthreads();
    float acc = ld<DT>(neb, j) + t_emb[j];
#pragma unroll 8
    for (int i = 0; i < NODE_IN; ++i) acc += s_h[i] * ld<DT>(new_, i * HDIM + j);
    h_feat[(size_t)n * HDIM + j] = acc;
}

// ---------------- x init (-> f32 ws) ----------------
template<int DT>
__global__ void xinit_kernel(const int* dflag, const void* x, float* __restrict__ x_cur) {
    if (*dflag != DT) return;
    int idx = blockIdx.x * blockDim.x + threadIdx.x;
    if (idx < N_NODES * 3) x_cur[idx] = ld<DT>(x, idx);
}

// ---------------- edge kernel: messages + atomics ----------------
template<int DT>
__global__ __launch_bounds__(256) void edge_kernel(
    const int* __restrict__ dflag,
    const int* __restrict__ ei, const void* ea, const void* eew, const void* eeb,
    const float* __restrict__ h_feat, const float* __restrict__ x_cur,
    const void* ew1, const void* eb1, const void* ew2, const void* eb2,
    const void* cw1, const void* cb1, const void* cw2, int layer,
    float* __restrict__ agg_h, float* __restrict__ agg_x) {
    if (*dflag != DT) return;

    __shared__ float s_ein[EPB][388];   // [hr(128) | hc(128) | d2(1) | ef(128)] pad->388
    __shared__ float s_y[EPB][HDIM];
    __shared__ float s_m[EPB][HDIM];
    __shared__ float s_diff[EPB][3];
    __shared__ float s_dist[EPB];
    __shared__ float s_w[EPB];
    __shared__ int s_row[EPB], s_col[EPB];

    const int tid = threadIdx.x;
    const int e0 = blockIdx.x * EPB;
    const int j = tid & (HDIM - 1);
    const int sub = tid >> 7;      // 0..1
    const int eb = sub * 4;        // this half-block owns edges eb..eb+3

    const size_t w1o = (size_t)layer * 385 * HDIM;
    const size_t b1o = (size_t)layer * HDIM;
    const size_t w2o = (size_t)layer * HDIM * HDIM;
    const size_t c1o = (size_t)layer * HDIM * HDIM;
    const size_t c2o = (size_t)layer * HDIM;

    // phase 0: indices, diff, dist
    if (tid < EPB) {
        int e = e0 + tid;
        int r = ei[e], c = ei[N_EDGES + e];
        s_row[tid] = r; s_col[tid] = c;
        float dx = x_cur[r * 3 + 0] - x_cur[c * 3 + 0];
        float dy = x_cur[r * 3 + 1] - x_cur[c * 3 + 1];
        float dz = x_cur[r * 3 + 2] - x_cur[c * 3 + 2];
        float d2 = dx * dx + dy * dy + dz * dz;
        s_diff[tid][0] = dx; s_diff[tid][1] = dy; s_diff[tid][2] = dz;
        s_ein[tid][256] = d2;
        s_dist[tid] = sqrtf(d2 + EPSV);
    }
    __syncthreads();

    // phase 1: build edge_in rows (h[row], h[col], d2, edge_feat)
    for (int e = sub; e < EPB; e += 2) {
        int r = s_row[e], c = s_col[e];
        s_ein[e][j] = h_feat[(size_t)r * HDIM + j];
        s_ein[e][HDIM + j] = h_feat[(size_t)c * HDIM + j];
        float ef = ld<DT>(eeb, j);
#pragma unroll
        for (int k = 0; k < EDGE_IN; ++k)
            ef += ld<DT>(ea, (size_t)(e0 + e) * EDGE_IN + k) * ld<DT>(eew, k * HDIM + j);
        s_ein[e][257 + j] = ef;
    }
    __syncthreads();

    // phase 2: y1 = silu(edge_in @ w1 + b1)   (385 -> 128)
    {
        float b = ld<DT>(eb1, b1o + j);
        float a0 = b, a1 = b, a2 = b, a3 = b;
        for (int i0 = 0; i0 < 384; i0 += 4) {
            float4 p0 = *(const float4*)&s_ein[eb + 0][i0];
            float4 p1 = *(const float4*)&s_ein[eb + 1][i0];
            float4 p2 = *(const float4*)&s_ein[eb + 2][i0];
            float4 p3 = *(const float4*)&s_ein[eb + 3][i0];
            float w0 = ld<DT>(ew1, w1o + (size_t)(i0 + 0) * HDIM + j);
            float w1v = ld<DT>(ew1, w1o + (size_t)(i0 + 1) * HDIM + j);
            float w2v = ld<DT>(ew1, w1o + (size_t)(i0 + 2) * HDIM + j);
            float w3v = ld<DT>(ew1, w1o + (size_t)(i0 + 3) * HDIM + j);
            a0 += p0.x * w0 + p0.y * w1v + p0.z * w2v + p0.w * w3v;
            a1 += p1.x * w0 + p1.y * w1v + p1.z * w2v + p1.w * w3v;
            a2 += p2.x * w0 + p2.y * w1v + p2.z * w2v + p2.w * w3v;
            a3 += p3.x * w0 + p3.y * w1v + p3.z * w2v + p3.w * w3v;
        }
        float wl = ld<DT>(ew1, w1o + (size_t)384 * HDIM + j);
        a0 += s_ein[eb + 0][384] * wl;
        a1 += s_ein[eb + 1][384] * wl;
        a2 += s_ein[eb + 2][384] * wl;
        a3 += s_ein[eb + 3][384] * wl;
        s_y[eb + 0][j] = silu_f(a0);
        s_y[eb + 1][j] = silu_f(a1);
        s_y[eb + 2][j] = silu_f(a2);
        s_y[eb + 3][j] = silu_f(a3);
    }
    __syncthreads();

    // phase 3: m = silu(y1 @ w2 + b2)
    {
        float b = ld<DT>(eb2, b1o + j);
        float a0 = b, a1 = b, a2 = b, a3 = b;
        for (int i0 = 0; i0 < HDIM; i0 += 4) {
            float4 p0 = *(const float4*)&s_y[eb + 0][i0];
            float4 p1 = *(const float4*)&s_y[eb + 1][i0];
            float4 p2 = *(const float4*)&s_y[eb + 2][i0];
            float4 p3 = *(const float4*)&s_y[eb + 3][i0];
            float w0 = ld<DT>(ew2, w2o + (size_t)(i0 + 0) * HDIM + j);
            float w1v = ld<DT>(ew2, w2o + (size_t)(i0 + 1) * HDIM + j);
            float w2v = ld<DT>(ew2, w2o + (size_t)(i0 + 2) * HDIM + j);
            float w3v = ld<DT>(ew2, w2o + (size_t)(i0 + 3) * HDIM + j);
            a0 += p0.x * w0 + p0.y * w1v + p0.z * w2v + p0.w * w3v;
            a1 += p1.x * w0 + p1.y * w1v + p1.z * w2v + p1.w * w3v;
            a2 += p2.x * w0 + p2.y * w1v + p2.z * w2v + p2.w * w3v;
            a3 += p3.x * w0 + p3.y * w1v + p3.z * w2v + p3.w * w3v;
        }
        s_m[eb + 0][j] = silu_f(a0);
        s_m[eb + 1][j] = silu_f(a1);
        s_m[eb + 2][j] = silu_f(a2);
        s_m[eb + 3][j] = silu_f(a3);
    }
    __syncthreads();

    // phase 4: c = silu(m @ c1 + cb)   (write s_y; s_y's old values are dead)
    {
        float b = ld<DT>(cb1, c2o + j);
        float a0 = b, a1 = b, a2 = b, a3 = b;
        for (int i0 = 0; i0 < HDIM; i0 += 4) {
            float4 p0 = *(const float4*)&s_m[eb + 0][i0];
            float4 p1 = *(const float4*)&s_m[eb + 1][i0];
            float4 p2 = *(const float4*)&s_m[eb + 2][i0];
            float4 p3 = *(const float4*)&s_m[eb + 3][i0];
            float w0 = ld<DT>(cw1, c1o + (size_t)(i0 + 0) * HDIM + j);
            float w1v = ld<DT>(cw1, c1o + (size_t)(i0 + 1) * HDIM + j);
            float w2v = ld<DT>(cw1, c1o + (size_t)(i0 + 2) * HDIM + j);
            float w3v = ld<DT>(cw1, c1o + (size_t)(i0 + 3) * HDIM + j);
            a0 += p0.x * w0 + p0.y * w1v + p0.z * w2v + p0.w * w3v;
            a1 += p1.x * w0 + p1.y * w1v + p1.z * w2v + p1.w * w3v;
            a2 += p2.x * w0 + p2.y * w1v + p2.z * w2v + p2.w * w3v;
            a3 += p3.x * w0 + p3.y * w1v + p3.z * w2v + p3.w * w3v;
        }
        s_y[eb + 0][j] = silu_f(a0);
        s_y[eb + 1][j] = silu_f(a1);
        s_y[eb + 2][j] = silu_f(a2);
        s_y[eb + 3][j] = silu_f(a3);
    }
    __syncthreads();

    // phase 5: w = tanh(c @ c2) per edge (32 lanes per edge)
    {
        int e = tid >> 5;
        int l5 = tid & 31;
        float part = 0.f;
#pragma unroll
        for (int q = 0; q < 4; ++q)
            part += s_y[e][l5 + 32 * q] * ld<DT>(cw2, c2o + l5 + 32 * q);
        for (int off = 16; off; off >>= 1) part += __shfl_down(part, off, 32);
        if (l5 == 0) s_w[e] = tanhf(part);
    }
    __syncthreads();

    // phase 6: scatter
#pragma unroll
    for (int e = eb; e < eb + 4; ++e)
        atomicAdd(&agg_h[(size_t)s_row[e] * HDIM + j], s_m[e][j]);
    if (tid < EPB * 3) {
        int e = tid / 3, k = tid - e * 3;
        float val = s_diff[e][k] / (s_dist[e] + EPSV) * s_w[e];
        atomicAdd(&agg_x[s_row[e] * 3 + k], val);
    }
}

// ---------------- node kernel: h,x update ----------------
template<int DT>
__global__ void node_kernel(const int* dflag,
                            float* __restrict__ h_feat, float* __restrict__ x_cur,
                            const float* __restrict__ agg_h, const float* __restrict__ agg_x,
                            const void* mask, const void* n1p, const void* nb1p,
                            const void* n2p, const void* nb2p, int layer) {
    if (*dflag != DT) return;
    __shared__ float s_cat[2 * HDIM];
    __shared__ float s_u[HDIM];
    int n = blockIdx.x, j = threadIdx.x;
    const size_t w1o = (size_t)layer * 2 * HDIM * HDIM;
    const size_t w2o = (size_t)layer * HDIM * HDIM;
    const size_t bo  = (size_t)layer * HDIM;
    s_cat[j] = h_feat[(size_t)n * HDIM + j];
    s_cat[HDIM + j] = agg_h[(size_t)n * HDIM + j];
    __syncthreads();
    float u = ld<DT>(nb1p, bo + j);
    for (int i0 = 0; i0 < 2 * HDIM; i0 += 4) {
        float4 c = *(const float4*)&s_cat[i0];
        u += c.x * ld<DT>(n1p, w1o + (size_t)(i0 + 0) * HDIM + j);
        u += c.y * ld<DT>(n1p, w1o + (size_t)(i0 + 1) * HDIM + j);
        u += c.z * ld<DT>(n1p, w1o + (size_t)(i0 + 2) * HDIM + j);
        u += c.w * ld<DT>(n1p, w1o + (size_t)(i0 + 3) * HDIM + j);
    }
    s_u[j] = silu_f(u);
    __syncthreads();
    float acc = ld<DT>(nb2p, bo + j);
    for (int i0 = 0; i0 < HDIM; i0 += 4) {
        float4 c = *(const float4*)&s_u[i0];
        acc += c.x * ld<DT>(n2p, w2o + (size_t)(i0 + 0) * HDIM + j);
        acc += c.y * ld<DT>(n2p, w2o + (size_t)(i0 + 1) * HDIM + j);
        acc += c.z * ld<DT>(n2p, w2o + (size_t)(i0 + 2) * HDIM + j);
        acc += c.w * ld<DT>(n2p, w2o + (size_t)(i0 + 3) * HDIM + j);
    }
    h_feat[(size_t)n * HDIM + j] += acc;
    if (j < 3) x_cur[n * 3 + j] += agg_x[n * 3 + j] * ld<DT>(mask, n);
}

// ---------------- output: v = (x_final - x_in) * mask  (dtype-matched write) ----------------
template<int DT>
__global__ void out_kernel(const int* dflag, const float* __restrict__ x_cur,
                           const void* x_in, const void* mask, void* __restrict__ out) {
    if (*dflag != DT) return;
    int idx = blockIdx.x * blockDim.x + threadIdx.x;
    if (idx < N_NODES * 3) {
        int n = idx / 3;
        float v = (x_cur[idx] - ld<DT>(x_in, idx)) * ld<DT>(mask, n);
        if (DT == 0) ((float*)out)[idx] = v;
        else         ((__hip_bfloat16*)out)[idx] = __float2bfloat16(v);
    }
}

extern "C" void kernel_launch(void* const* d_in, const int* in_sizes, int n_in,
                              void* d_out, int out_size, void* d_ws, size_t ws_size,
                              hipStream_t stream) {
    const void* h    = d_in[0];
    const void* x    = d_in[1];
    const int*  ei   = (const int*)d_in[2];
    const void* ea   = d_in[3];
    const void* t    = d_in[4];
    const void* mask = d_in[5];
    const void* tw1  = d_in[6];
    const void* tb1  = d_in[7];
    const void* tw2  = d_in[8];
    const void* tb2  = d_in[9];
    const void* new_ = d_in[10];
    const void* neb  = d_in[11];
    const void* eew  = d_in[12];
    const void* eeb  = d_in[13];
    const void* ew1  = d_in[14];
    const void* eb1  = d_in[15];
    const void* ew2  = d_in[16];
    const void* eb2  = d_in[17];
    const void* cw1  = d_in[18];
    const void* cb1  = d_in[19];
    const void* cw2  = d_in[20];
    const void* nw1  = d_in[21];
    const void* nb1  = d_in[22];
    const void* nw2  = d_in[23];
    const void* nb2  = d_in[24];

    float* W      = (float*)d_ws;
    int*   dflag  = (int*)d_ws;                       // W[0..7]
    float* t_emb  = W + 8;                            // 128
    float* h_feat = t_emb + HDIM;                     // N*128
    float* x_cur  = h_feat + (size_t)N_NODES * HDIM;  // N*3
    float* agg_h  = x_cur + (size_t)N_NODES * 3;      // N*128
    float* agg_x  = agg_h + (size_t)N_NODES * HDIM;   // N*3 (contiguous after agg_h)

    probe_kernel<<<1, 64, 0, stream>>>((const unsigned*)mask, dflag);

    temb_kernel<0><<<1, HDIM, 0, stream>>>(dflag, t, tw1, tb1, tw2, tb2, t_emb);
    temb_kernel<1><<<1, HDIM, 0, stream>>>(dflag, t, tw1, tb1, tw2, tb2, t_emb);
    hfeat_kernel<0><<<N_NODES, HDIM, 0, stream>>>(dflag, h, new_, neb, t_emb, h_feat);
    hfeat_kernel<1><<<N_NODES, HDIM, 0, stream>>>(dflag, h, new_, neb, t_emb, h_feat);
    xinit_kernel<0><<<(N_NODES * 3 + 255) / 256, 256, 0, stream>>>(dflag, x, x_cur);
    xinit_kernel<1><<<(N_NODES * 3 + 255) / 256, 256, 0, stream>>>(dflag, x, x_cur);

    for (int l = 0; l < NLAYERS; ++l) {
        hipMemsetAsync(agg_h, 0, (size_t)N_NODES * (HDIM + 3) * sizeof(float), stream);
        edge_kernel<0><<<N_EDGES / EPB, 256, 0, stream>>>(
            dflag, ei, ea, eew, eeb, h_feat, x_cur,
            ew1, eb1, ew2, eb2, cw1, cb1, cw2, l, agg_h, agg_x);
        edge_kernel<1><<<N_EDGES / EPB, 256, 0, stream>>>(
            dflag, ei, ea, eew, eeb, h_feat, x_cur,
            ew1, eb1, ew2, eb2, cw1, cb1, cw2, l, agg_h, agg_x);
        node_kernel<0><<<N_NODES, HDIM, 0, stream>>>(
            dflag, h_feat, x_cur, agg_h, agg_x, mask, nw1, nb1, nw2, nb2, l);
        node_kernel<1><<<N_NODES, HDIM, 0, stream>>>(
            dflag, h_feat, x_cur, agg_h, agg_x, mask, nw1, nb1, nw2, nb2, l);
    }

    out_kernel<0><<<(N_NODES * 3 + 255) / 256, 256, 0, stream>>>(dflag, x_cur, x, mask, d_out);
    out_kernel<1><<<(N_NODES * 3 + 255) / 256, 256, 0, stream>>>(dflag, x_cur, x, mask, d_out);
}

// Round 5
// 2081.980 us; speedup vs baseline: 2.7899x; 2.7899x over previous
//
#include <hip/hip_runtime.h>
#include <hip/hip_bf16.h>

#define N_NODES 10000
#define N_EDGES 320000
#define HDIM 128
#define NODE_IN 64
#define EDGE_IN 16
#define NLAYERS 4
#define EPSV 1e-8f
#define SACT 136       // LDS activation row stride (fp16 elems)
#define INV4096 2.44140625e-4f

typedef unsigned short ushort_t;
typedef __attribute__((ext_vector_type(8))) short s8;        // 8 fp16 bit-pattern (4 VGPRs)
typedef __attribute__((ext_vector_type(8))) _Float16 h8;
typedef __attribute__((ext_vector_type(4))) float f4;

__device__ __forceinline__ float silu_f(float z) { return z / (1.0f + __expf(-z)); }

__device__ __forceinline__ f4 mfma16(s8 a, s8 b, f4 c) {
    return __builtin_amdgcn_mfma_f32_16x16x32_f16(
        __builtin_bit_cast(h8, a), __builtin_bit_cast(h8, b), c, 0, 0, 0);
}

// fp32 -> fp16 hi + (residual*4096) lo   (rep error ~2^-23 relative)
__device__ __forceinline__ void split_f16(float x, ushort_t& hi, ushort_t& lo) {
    _Float16 h = (_Float16)x;
    float hf = (float)h;
    _Float16 l = (_Float16)((x - hf) * 4096.0f);
    hi = __builtin_bit_cast(ushort_t, h);
    lo = __builtin_bit_cast(ushort_t, l);
}

// ============ prep 1: repack W1a,W1b,W2,C1 into MFMA B-frag order, split fp16 hi/lo ============
// frag layout per 128x128 matrix: [nt(8)][kt(4)][lane(64)][j(8)] ; B[k=kt*32+(lane>>4)*8+j][n=nt*16+(lane&15)]
__global__ void repack_weights(const float* __restrict__ ew1, const float* __restrict__ ew2,
                               const float* __restrict__ cw1,
                               ushort_t* __restrict__ wf_hi, ushort_t* __restrict__ wf_lo) {
    int gid = blockIdx.x * 256 + threadIdx.x;
    const int total = NLAYERS * 4 * 16384;
    if (gid >= total) return;
    int l   = gid / (4 * 16384);
    int rem = gid % (4 * 16384);
    int m4  = rem / 16384;
    int idx = rem & 16383;
    int b    = idx >> 9;
    int lane = (idx >> 3) & 63;
    int j    = idx & 7;
    int nt = b >> 2, kt = b & 3;
    int k = kt * 32 + ((lane >> 4) << 3) + j;
    int n = (nt << 4) + (lane & 15);
    float v;
    if (m4 == 0)      v = ew1[(size_t)l * 385 * 128 + (size_t)k * 128 + n];          // W1a
    else if (m4 == 1) v = ew1[(size_t)l * 385 * 128 + (size_t)(128 + k) * 128 + n];  // W1b
    else if (m4 == 2) v = ew2[(size_t)l * 16384 + k * 128 + n];                      // W2
    else              v = cw1[(size_t)l * 16384 + k * 128 + n];                      // C1
    split_f16(v, wf_hi[gid], wf_lo[gid]);
}

// ============ prep 2: G = eew @ W1c (K padded to 32, frag-packed, split) + bias fold ============
__global__ void prep_g(const float* __restrict__ eew, const float* __restrict__ eeb,
                       const float* __restrict__ ew1, const float* __restrict__ eb1,
                       ushort_t* __restrict__ g_hi, ushort_t* __restrict__ g_lo,
                       float* __restrict__ bias1c) {
    int gid = blockIdx.x * 256 + threadIdx.x;
    const int T1 = NLAYERS * 4096;
    if (gid < T1) {
        int l = gid >> 12;
        int idx = gid & 4095;
        int nt = idx >> 9;
        int lane = (idx >> 3) & 63;
        int j = idx & 7;
        int q = lane >> 4;
        int n = (nt << 4) + (lane & 15);
        int k = q * 8 + j;
        float v = 0.f;
        if (k < EDGE_IN) {
            const float* w1c = ew1 + (size_t)l * 385 * 128 + (size_t)257 * 128;
            float acc = 0.f;
            for (int c = 0; c < HDIM; ++c) acc += eew[k * 128 + c] * w1c[(size_t)c * 128 + n];
            v = acc;
        }
        split_f16(v, g_hi[gid], g_lo[gid]);
    } else if (gid < T1 + NLAYERS * 128) {
        int r = gid - T1;
        int l = r >> 7;
        int n = r & 127;
        const float* w1c = ew1 + (size_t)l * 385 * 128 + (size_t)257 * 128;
        float acc = eb1[l * 128 + n];
        for (int c = 0; c < HDIM; ++c) acc += eeb[c] * w1c[(size_t)c * 128 + n];
        bias1c[r] = acc;
    }
}

// ============ t_emb ============
__global__ void temb_kernel(const float* t, const float* tw1, const float* tb1,
                            const float* tw2, const float* tb2, float* t_emb) {
    __shared__ float s_a[HDIM];
    int j = threadIdx.x;
    s_a[j] = silu_f(t[0] * tw1[j] + tb1[j]);
    __syncthreads();
    float acc = tb2[j];
    for (int k = 0; k < HDIM; ++k) acc += s_a[k] * tw2[k * HDIM + j];
    t_emb[j] = acc;
}

// ============ h_feat init (fp32 + split fp16 mirror) ============
__global__ void hfeat_kernel(const float* __restrict__ h, const float* __restrict__ new_,
                             const float* __restrict__ neb, const float* __restrict__ t_emb,
                             float* __restrict__ h_feat,
                             ushort_t* __restrict__ hbf_hi, ushort_t* __restrict__ hbf_lo) {
    __shared__ float s_h[NODE_IN];
    int n = blockIdx.x, j = threadIdx.x;
    if (j < NODE_IN) s_h[j] = h[(size_t)n * NODE_IN + j];
    __syncthreads();
    float acc = neb[j] + t_emb[j];
#pragma unroll 8
    for (int i = 0; i < NODE_IN; ++i) acc += s_h[i] * new_[i * HDIM + j];
    h_feat[(size_t)n * HDIM + j] = acc;
    split_f16(acc, hbf_hi[(size_t)n * HDIM + j], hbf_lo[(size_t)n * HDIM + j]);
}

__global__ void xinit_kernel(const float* x, float* x_cur) {
    int idx = blockIdx.x * blockDim.x + threadIdx.x;
    if (idx < N_NODES * 3) x_cur[idx] = x[idx];
}

// ============ MFMA edge kernel: 1 wave = 16 edges, 4 waves/block, fp16x2 ============
__global__ __launch_bounds__(256) void edge_mfma_kernel(
    const int* __restrict__ ei, const float* __restrict__ ea,
    const float* __restrict__ x_cur,
    const ushort_t* __restrict__ hbf_hi, const ushort_t* __restrict__ hbf_lo,
    const ushort_t* __restrict__ wf_hi, const ushort_t* __restrict__ wf_lo,
    const ushort_t* __restrict__ g_hi, const ushort_t* __restrict__ g_lo,
    const float* __restrict__ bias1c,
    const float* __restrict__ ew1,   // d2 row (row 256), fp32
    const float* __restrict__ eb2, const float* __restrict__ cb1, const float* __restrict__ cw2,
    int layer, float* __restrict__ agg_h, float* __restrict__ agg_x)
{
    __shared__ __align__(16) ushort_t s_acth[4][16 * SACT];
    __shared__ __align__(16) ushort_t s_actl[4][16 * SACT];
    __shared__ float s_d2[4][16], s_dist[4][16], s_diff[4][16][3];
    __shared__ int s_row[4][16];

    const int tid = threadIdx.x;
    const int w = tid >> 6, lane = tid & 63;
    const int lo = lane & 15, q = lane >> 4;
    const int e0 = blockIdx.x * 64 + w * 16;

    const ushort_t* wAh  = wf_hi + (size_t)layer * 4 * 16384;
    const ushort_t* wAl  = wf_lo + (size_t)layer * 4 * 16384;
    const ushort_t* wBh  = wAh + 16384;
    const ushort_t* wBl  = wAl + 16384;
    const ushort_t* wW2h = wAh + 32768;
    const ushort_t* wW2l = wAl + 32768;
    const ushort_t* wC1h = wAh + 49152;
    const ushort_t* wC1l = wAl + 49152;
    const ushort_t* wgh  = g_hi + (size_t)layer * 4096;
    const ushort_t* wgl  = g_lo + (size_t)layer * 4096;
    const float* wd2 = ew1 + (size_t)layer * 385 * 128 + (size_t)256 * 128;
    const float* b1v = bias1c + layer * 128;
    const float* b2v = eb2 + layer * 128;
    const float* cbv = cb1 + layer * 128;
    const float* c2v = cw2 + layer * 128;

    // ---- phase 0: geometry ----
    if (lane < 16) {
        int e = e0 + lane;
        int r = ei[e], c = ei[N_EDGES + e];
        s_row[w][lane] = r;
        float dx = x_cur[r * 3 + 0] - x_cur[c * 3 + 0];
        float dy = x_cur[r * 3 + 1] - x_cur[c * 3 + 1];
        float dz = x_cur[r * 3 + 2] - x_cur[c * 3 + 2];
        float d2 = dx * dx + dy * dy + dz * dz;
        s_d2[w][lane] = d2;
        s_dist[w][lane] = sqrtf(d2 + EPSV);
        s_diff[w][lane][0] = dx; s_diff[w][lane][1] = dy; s_diff[w][lane][2] = dz;
    }
    int er = ei[e0 + lo];
    int ec = ei[N_EDGES + e0 + lo];
    __syncthreads();   // B1

    // ---- A fragments: h_row, h_col (hi/lo), ea (split in-register, K 16->32 pad) ----
    s8 aRh[4], aRl[4], aCh[4], aCl[4];
#pragma unroll
    for (int kt = 0; kt < 4; ++kt) {
        size_t ro = (size_t)er * 128 + kt * 32 + q * 8;
        size_t co = (size_t)ec * 128 + kt * 32 + q * 8;
        aRh[kt] = *(const s8*)(hbf_hi + ro);
        aRl[kt] = *(const s8*)(hbf_lo + ro);
        aCh[kt] = *(const s8*)(hbf_hi + co);
        aCl[kt] = *(const s8*)(hbf_lo + co);
    }
    s8 aEAh = {0,0,0,0,0,0,0,0}, aEAl = {0,0,0,0,0,0,0,0};
    if (q < 2) {
        const float* eap = ea + (size_t)(e0 + lo) * 16 + q * 8;
#pragma unroll
        for (int i = 0; i < 8; ++i) {
            ushort_t hh, ll;
            split_f16(eap[i], hh, ll);
            aEAh[i] = (short)hh; aEAl[i] = (short)ll;
        }
    }

    // ---- GEMM1: y1 = silu(hR@W1a + hC@W1b + ea@G + d2*wd2 + b1') ----
    float d2r[4];
#pragma unroll
    for (int r = 0; r < 4; ++r) d2r[r] = s_d2[w][q * 4 + r];

#pragma unroll
    for (int nt = 0; nt < 8; ++nt) {
        f4 aH = {0.f, 0.f, 0.f, 0.f};
        f4 aL = {0.f, 0.f, 0.f, 0.f};
        {
            s8 bGh = *(const s8*)(wgh + ((size_t)nt * 64 + lane) * 8);
            s8 bGl = *(const s8*)(wgl + ((size_t)nt * 64 + lane) * 8);
            aH = mfma16(aEAh, bGh, aH);
            aL = mfma16(aEAh, bGl, aL);
            aL = mfma16(aEAl, bGh, aL);
        }
#pragma unroll
        for (int kt = 0; kt < 4; ++kt) {
            size_t base = ((size_t)(nt * 4 + kt) * 64 + lane) * 8;
            s8 bh = *(const s8*)(wAh + base);
            s8 bl = *(const s8*)(wAl + base);
            aH = mfma16(aRh[kt], bh, aH);
            aL = mfma16(aRh[kt], bl, aL);
            aL = mfma16(aRl[kt], bh, aL);
            s8 ch = *(const s8*)(wBh + base);
            s8 cl = *(const s8*)(wBl + base);
            aH = mfma16(aCh[kt], ch, aH);
            aL = mfma16(aCh[kt], cl, aL);
            aL = mfma16(aCl[kt], ch, aL);
        }
        float bb = b1v[nt * 16 + lo];
        float wv = wd2[nt * 16 + lo];
#pragma unroll
        for (int r = 0; r < 4; ++r) {
            float v = silu_f(aH[r] + aL[r] * INV4096 + bb + d2r[r] * wv);
            int off = (q * 4 + r) * SACT + nt * 16 + lo;
            split_f16(v, s_acth[w][off], s_actl[w][off]);
        }
    }
    __syncthreads();   // B2

    // ---- GEMM2: m = silu(y1 @ W2 + b2) ----
    s8 aYh[4], aYl[4];
#pragma unroll
    for (int kt = 0; kt < 4; ++kt) {
        aYh[kt] = *(const s8*)&s_acth[w][lo * SACT + kt * 32 + q * 8];
        aYl[kt] = *(const s8*)&s_actl[w][lo * SACT + kt * 32 + q * 8];
    }
    __syncthreads();   // B3

    int rowm[4];
#pragma unroll
    for (int r = 0; r < 4; ++r) rowm[r] = s_row[w][q * 4 + r];

    f4 mv[8];
#pragma unroll
    for (int nt = 0; nt < 8; ++nt) {
        f4 aH = {0.f, 0.f, 0.f, 0.f};
        f4 aL = {0.f, 0.f, 0.f, 0.f};
#pragma unroll
        for (int kt = 0; kt < 4; ++kt) {
            size_t base = ((size_t)(nt * 4 + kt) * 64 + lane) * 8;
            s8 bh = *(const s8*)(wW2h + base);
            s8 bl = *(const s8*)(wW2l + base);
            aH = mfma16(aYh[kt], bh, aH);
            aL = mfma16(aYh[kt], bl, aL);
            aL = mfma16(aYl[kt], bh, aL);
        }
        float bb = b2v[nt * 16 + lo];
#pragma unroll
        for (int r = 0; r < 4; ++r) aH[r] = silu_f(aH[r] + aL[r] * INV4096 + bb);
        mv[nt] = aH;
    }
    // store m (split) for GEMM3 + scatter agg_h (fp32)
#pragma unroll
    for (int nt = 0; nt < 8; ++nt) {
#pragma unroll
        for (int r = 0; r < 4; ++r) {
            int off = (q * 4 + r) * SACT + nt * 16 + lo;
            split_f16(mv[nt][r], s_acth[w][off], s_actl[w][off]);
            atomicAdd(&agg_h[(size_t)rowm[r] * HDIM + nt * 16 + lo], mv[nt][r]);
        }
    }
    __syncthreads();   // B4

    // ---- GEMM3: c = silu(m @ C1 + cb) ; w = tanh(c . c2) ----
    s8 aMh[4], aMl[4];
#pragma unroll
    for (int kt = 0; kt < 4; ++kt) {
        aMh[kt] = *(const s8*)&s_acth[w][lo * SACT + kt * 32 + q * 8];
        aMl[kt] = *(const s8*)&s_actl[w][lo * SACT + kt * 32 + q * 8];
    }

    float wpart[4] = {0.f, 0.f, 0.f, 0.f};
#pragma unroll
    for (int nt = 0; nt < 8; ++nt) {
        f4 aH = {0.f, 0.f, 0.f, 0.f};
        f4 aL = {0.f, 0.f, 0.f, 0.f};
#pragma unroll
        for (int kt = 0; kt < 4; ++kt) {
            size_t base = ((size_t)(nt * 4 + kt) * 64 + lane) * 8;
            s8 bh = *(const s8*)(wC1h + base);
            s8 bl = *(const s8*)(wC1l + base);
            aH = mfma16(aMh[kt], bh, aH);
            aL = mfma16(aMh[kt], bl, aL);
            aL = mfma16(aMl[kt], bh, aL);
        }
        float bb = cbv[nt * 16 + lo];
        float cc = c2v[nt * 16 + lo];
#pragma unroll
        for (int r = 0; r < 4; ++r)
            wpart[r] += silu_f(aH[r] + aL[r] * INV4096 + bb) * cc;
    }
#pragma unroll
    for (int r = 0; r < 4; ++r) {
#pragma unroll
        for (int mask = 1; mask < 16; mask <<= 1)
            wpart[r] += __shfl_xor(wpart[r], mask, 16);
    }
    if (lo < 3) {
#pragma unroll
        for (int r = 0; r < 4; ++r) {
            int mm = q * 4 + r;
            float wv = tanhf(wpart[r]);
            float val = s_diff[w][mm][lo] / (s_dist[w][mm] + EPSV) * wv;
            atomicAdd(&agg_x[rowm[r] * 3 + lo], val);
        }
    }
}

// ============ node kernel (fp32 VALU) ============
__global__ void node_kernel(float* __restrict__ h_feat, float* __restrict__ x_cur,
                            ushort_t* __restrict__ hbf_hi, ushort_t* __restrict__ hbf_lo,
                            const float* __restrict__ agg_h, const float* __restrict__ agg_x,
                            const float* __restrict__ mask,
                            const float* __restrict__ n1p, const float* __restrict__ nb1p,
                            const float* __restrict__ n2p, const float* __restrict__ nb2p, int layer) {
    __shared__ float s_cat[2 * HDIM];
    __shared__ float s_u[HDIM];
    int n = blockIdx.x, j = threadIdx.x;
    const size_t w1o = (size_t)layer * 2 * HDIM * HDIM;
    const size_t w2o = (size_t)layer * HDIM * HDIM;
    const size_t bo  = (size_t)layer * HDIM;
    s_cat[j] = h_feat[(size_t)n * HDIM + j];
    s_cat[HDIM + j] = agg_h[(size_t)n * HDIM + j];
    __syncthreads();
    float u = nb1p[bo + j];
    for (int i0 = 0; i0 < 2 * HDIM; i0 += 4) {
        float4 c = *(const float4*)&s_cat[i0];
        u += c.x * n1p[w1o + (size_t)(i0 + 0) * HDIM + j];
        u += c.y * n1p[w1o + (size_t)(i0 + 1) * HDIM + j];
        u += c.z * n1p[w1o + (size_t)(i0 + 2) * HDIM + j];
        u += c.w * n1p[w1o + (size_t)(i0 + 3) * HDIM + j];
    }
    s_u[j] = silu_f(u);
    __syncthreads();
    float acc = nb2p[bo + j];
    for (int i0 = 0; i0 < HDIM; i0 += 4) {
        float4 c = *(const float4*)&s_u[i0];
        acc += c.x * n2p[w2o + (size_t)(i0 + 0) * HDIM + j];
        acc += c.y * n2p[w2o + (size_t)(i0 + 1) * HDIM + j];
        acc += c.z * n2p[w2o + (size_t)(i0 + 2) * HDIM + j];
        acc += c.w * n2p[w2o + (size_t)(i0 + 3) * HDIM + j];
    }
    float nh = s_cat[j] + acc;
    h_feat[(size_t)n * HDIM + j] = nh;
    split_f16(nh, hbf_hi[(size_t)n * HDIM + j], hbf_lo[(size_t)n * HDIM + j]);
    if (j < 3) x_cur[n * 3 + j] += agg_x[n * 3 + j] * mask[n];
}

__global__ void out_kernel(const float* __restrict__ x_cur, const float* __restrict__ x_in,
                           const float* __restrict__ mask, float* __restrict__ out) {
    int idx = blockIdx.x * blockDim.x + threadIdx.x;
    if (idx < N_NODES * 3) {
        int n = idx / 3;
        out[idx] = (x_cur[idx] - x_in[idx]) * mask[n];
    }
}

extern "C" void kernel_launch(void* const* d_in, const int* in_sizes, int n_in,
                              void* d_out, int out_size, void* d_ws, size_t ws_size,
                              hipStream_t stream) {
    const float* h    = (const float*)d_in[0];
    const float* x    = (const float*)d_in[1];
    const int*   ei   = (const int*)d_in[2];
    const float* ea   = (const float*)d_in[3];
    const float* t    = (const float*)d_in[4];
    const float* mask = (const float*)d_in[5];
    const float* tw1  = (const float*)d_in[6];
    const float* tb1  = (const float*)d_in[7];
    const float* tw2  = (const float*)d_in[8];
    const float* tb2  = (const float*)d_in[9];
    const float* new_ = (const float*)d_in[10];
    const float* neb  = (const float*)d_in[11];
    const float* eew  = (const float*)d_in[12];
    const float* eeb  = (const float*)d_in[13];
    const float* ew1  = (const float*)d_in[14];
    const float* eb1  = (const float*)d_in[15];
    const float* ew2  = (const float*)d_in[16];
    const float* eb2  = (const float*)d_in[17];
    const float* cw1  = (const float*)d_in[18];
    const float* cb1  = (const float*)d_in[19];
    const float* cw2  = (const float*)d_in[20];
    const float* nw1  = (const float*)d_in[21];
    const float* nb1  = (const float*)d_in[22];
    const float* nw2  = (const float*)d_in[23];
    const float* nb2  = (const float*)d_in[24];

    float* W      = (float*)d_ws;
    float* t_emb  = W;                                   // 128
    float* h_feat = t_emb + HDIM;                        // N*128
    float* x_cur  = h_feat + (size_t)N_NODES * HDIM;     // N*3
    float* agg_h  = x_cur + (size_t)N_NODES * 3;         // N*128
    float* agg_x  = agg_h + (size_t)N_NODES * HDIM;      // N*3 (contiguous after agg_h)
    float* bias1c = agg_x + (size_t)N_NODES * 3;         // L*128
    ushort_t* hbf_hi = (ushort_t*)(bias1c + NLAYERS * HDIM);      // N*128
    ushort_t* hbf_lo = hbf_hi + (size_t)N_NODES * HDIM;           // N*128
    ushort_t* wf_hi  = hbf_lo + (size_t)N_NODES * HDIM;           // L*4*16384
    ushort_t* wf_lo  = wf_hi + (size_t)NLAYERS * 4 * 16384;       // L*4*16384
    ushort_t* g_hi   = wf_lo + (size_t)NLAYERS * 4 * 16384;       // L*4096
    ushort_t* g_lo   = g_hi + (size_t)NLAYERS * 4096;             // L*4096

    repack_weights<<<(NLAYERS * 4 * 16384 + 255) / 256, 256, 0, stream>>>(ew1, ew2, cw1, wf_hi, wf_lo);
    prep_g<<<(NLAYERS * 4096 + NLAYERS * 128 + 255) / 256, 256, 0, stream>>>(eew, eeb, ew1, eb1, g_hi, g_lo, bias1c);
    temb_kernel<<<1, HDIM, 0, stream>>>(t, tw1, tb1, tw2, tb2, t_emb);
    hfeat_kernel<<<N_NODES, HDIM, 0, stream>>>(h, new_, neb, t_emb, h_feat, hbf_hi, hbf_lo);
    xinit_kernel<<<(N_NODES * 3 + 255) / 256, 256, 0, stream>>>(x, x_cur);

    for (int l = 0; l < NLAYERS; ++l) {
        hipMemsetAsync(agg_h, 0, (size_t)N_NODES * (HDIM + 3) * sizeof(float), stream);
        edge_mfma_kernel<<<N_EDGES / 64, 256, 0, stream>>>(
            ei, ea, x_cur, hbf_hi, hbf_lo, wf_hi, wf_lo, g_hi, g_lo, bias1c,
            ew1, eb2, cb1, cw2, l, agg_h, agg_x);
        node_kernel<<<N_NODES, HDIM, 0, stream>>>(
            h_feat, x_cur, hbf_hi, hbf_lo, agg_h, agg_x, mask, nw1, nb1, nw2, nb2, l);
    }

    out_kernel<<<(N_NODES * 3 + 255) / 256, 256, 0, stream>>>(x_cur, x, mask, (float*)d_out);
}

// Round 6
// 2037.115 us; speedup vs baseline: 2.8513x; 1.0220x over previous
//
#include <hip/hip_runtime.h>
#include <hip/hip_bf16.h>

#define N_NODES 10000
#define N_EDGES 320000
#define HDIM 128
#define NODE_IN 64
#define EDGE_IN 16
#define NLAYERS 4
#define EPSV 1e-8f
#define SACT 136       // LDS activation row stride (fp16 elems)
#define INV4096 2.44140625e-4f

typedef unsigned short ushort_t;
typedef __attribute__((ext_vector_type(8))) short s8;        // 8 fp16 bit-pattern (4 VGPRs)
typedef __attribute__((ext_vector_type(8))) _Float16 h8;
typedef __attribute__((ext_vector_type(4))) float f4;

template<int MODE> struct MSel { using T = float; };
template<> struct MSel<1> { using T = _Float16; };

__device__ __forceinline__ float silu_f(float z) { return z / (1.0f + __expf(-z)); }

__device__ __forceinline__ f4 mfma16(s8 a, s8 b, f4 c) {
    return __builtin_amdgcn_mfma_f32_16x16x32_f16(
        __builtin_bit_cast(h8, a), __builtin_bit_cast(h8, b), c, 0, 0, 0);
}

// fp32 -> fp16 hi + (residual*4096) lo   (rep error ~2^-23 relative)
__device__ __forceinline__ void split_f16(float x, ushort_t& hi, ushort_t& lo) {
    _Float16 h = (_Float16)x;
    float hf = (float)h;
    _Float16 l = (_Float16)((x - hf) * 4096.0f);
    hi = __builtin_bit_cast(ushort_t, h);
    lo = __builtin_bit_cast(ushort_t, l);
}

// ============ CSR build ============
__global__ void deg_kernel(const int* __restrict__ ei, int* __restrict__ deg) {
    int e = blockIdx.x * 256 + threadIdx.x;
    if (e < N_EDGES) atomicAdd(&deg[ei[e]], 1);
}

__global__ void scan_kernel(const int* __restrict__ deg, int* __restrict__ row_start,
                            int* __restrict__ cursor) {
    __shared__ int s_part[256];
    const int CH = 40;   // 256*40 = 10240 >= N_NODES
    int t = threadIdx.x;
    int base = t * CH;
    int sum = 0;
    for (int i = 0; i < CH; ++i) { int n = base + i; if (n < N_NODES) sum += deg[n]; }
    s_part[t] = sum;
    __syncthreads();
    for (int d = 1; d < 256; d <<= 1) {
        int v = (t >= d) ? s_part[t - d] : 0;
        __syncthreads();
        s_part[t] += v;
        __syncthreads();
    }
    int off = s_part[t] - sum;
    for (int i = 0; i < CH; ++i) {
        int n = base + i;
        if (n < N_NODES) { row_start[n] = off; cursor[n] = off; off += deg[n]; }
    }
    if (t == 255) row_start[N_NODES] = s_part[255];
}

__global__ void scatter_kernel(const int* __restrict__ ei, int* __restrict__ cursor,
                               int* __restrict__ csr_eid) {
    int e = blockIdx.x * 256 + threadIdx.x;
    if (e < N_EDGES) {
        int r = ei[e];
        int pos = atomicAdd(&cursor[r], 1);
        csr_eid[pos] = e;
    }
}

// ============ prep 1: repack W1a,W1b,W2,C1 into MFMA B-frag order, split fp16 hi/lo ============
__global__ void repack_weights(const float* __restrict__ ew1, const float* __restrict__ ew2,
                               const float* __restrict__ cw1,
                               ushort_t* __restrict__ wf_hi, ushort_t* __restrict__ wf_lo) {
    int gid = blockIdx.x * 256 + threadIdx.x;
    const int total = NLAYERS * 4 * 16384;
    if (gid >= total) return;
    int l   = gid / (4 * 16384);
    int rem = gid % (4 * 16384);
    int m4  = rem / 16384;
    int idx = rem & 16383;
    int b    = idx >> 9;
    int lane = (idx >> 3) & 63;
    int j    = idx & 7;
    int nt = b >> 2, kt = b & 3;
    int k = kt * 32 + ((lane >> 4) << 3) + j;
    int n = (nt << 4) + (lane & 15);
    float v;
    if (m4 == 0)      v = ew1[(size_t)l * 385 * 128 + (size_t)k * 128 + n];
    else if (m4 == 1) v = ew1[(size_t)l * 385 * 128 + (size_t)(128 + k) * 128 + n];
    else if (m4 == 2) v = ew2[(size_t)l * 16384 + k * 128 + n];
    else              v = cw1[(size_t)l * 16384 + k * 128 + n];
    split_f16(v, wf_hi[gid], wf_lo[gid]);
}

// ============ prep 2: G = eew @ W1c (K padded to 32, frag-packed, split) + bias fold ============
__global__ void prep_g(const float* __restrict__ eew, const float* __restrict__ eeb,
                       const float* __restrict__ ew1, const float* __restrict__ eb1,
                       ushort_t* __restrict__ g_hi, ushort_t* __restrict__ g_lo,
                       float* __restrict__ bias1c) {
    int gid = blockIdx.x * 256 + threadIdx.x;
    const int T1 = NLAYERS * 4096;
    if (gid < T1) {
        int l = gid >> 12;
        int idx = gid & 4095;
        int nt = idx >> 9;
        int lane = (idx >> 3) & 63;
        int j = idx & 7;
        int q = lane >> 4;
        int n = (nt << 4) + (lane & 15);
        int k = q * 8 + j;
        float v = 0.f;
        if (k < EDGE_IN) {
            const float* w1c = ew1 + (size_t)l * 385 * 128 + (size_t)257 * 128;
            float acc = 0.f;
            for (int c = 0; c < HDIM; ++c) acc += eew[k * 128 + c] * w1c[(size_t)c * 128 + n];
            v = acc;
        }
        split_f16(v, g_hi[gid], g_lo[gid]);
    } else if (gid < T1 + NLAYERS * 128) {
        int r = gid - T1;
        int l = r >> 7;
        int n = r & 127;
        const float* w1c = ew1 + (size_t)l * 385 * 128 + (size_t)257 * 128;
        float acc = eb1[l * 128 + n];
        for (int c = 0; c < HDIM; ++c) acc += eeb[c] * w1c[(size_t)c * 128 + n];
        bias1c[r] = acc;
    }
}

// ============ t_emb ============
__global__ void temb_kernel(const float* t, const float* tw1, const float* tb1,
                            const float* tw2, const float* tb2, float* t_emb) {
    __shared__ float s_a[HDIM];
    int j = threadIdx.x;
    s_a[j] = silu_f(t[0] * tw1[j] + tb1[j]);
    __syncthreads();
    float acc = tb2[j];
    for (int k = 0; k < HDIM; ++k) acc += s_a[k] * tw2[k * HDIM + j];
    t_emb[j] = acc;
}

// ============ h_feat init (fp32 + split fp16 mirror) ============
__global__ void hfeat_kernel(const float* __restrict__ h, const float* __restrict__ new_,
                             const float* __restrict__ neb, const float* __restrict__ t_emb,
                             float* __restrict__ h_feat,
                             ushort_t* __restrict__ hbf_hi, ushort_t* __restrict__ hbf_lo) {
    __shared__ float s_h[NODE_IN];
    int n = blockIdx.x, j = threadIdx.x;
    if (j < NODE_IN) s_h[j] = h[(size_t)n * NODE_IN + j];
    __syncthreads();
    float acc = neb[j] + t_emb[j];
#pragma unroll 8
    for (int i = 0; i < NODE_IN; ++i) acc += s_h[i] * new_[i * HDIM + j];
    h_feat[(size_t)n * HDIM + j] = acc;
    split_f16(acc, hbf_hi[(size_t)n * HDIM + j], hbf_lo[(size_t)n * HDIM + j]);
}

__global__ void xinit_kernel(const float* x, float* x_cur) {
    int idx = blockIdx.x * blockDim.x + threadIdx.x;
    if (idx < N_NODES * 3) x_cur[idx] = x[idx];
}

// ============ MFMA edge kernel: 1 wave = 16 CSR slots, 4 waves/block, fp16x2 ============
// MODE 0: m -> m_buf fp32 (slot order), trans -> tbuf    (no atomics)
// MODE 1: same but m_buf fp16
// MODE 2: legacy atomic agg_h/agg_x fallback
template<int MODE>
__global__ __launch_bounds__(256) void edge_mfma_kernel(
    const int* __restrict__ ei, const float* __restrict__ ea,
    const float* __restrict__ x_cur,
    const ushort_t* __restrict__ hbf_hi, const ushort_t* __restrict__ hbf_lo,
    const ushort_t* __restrict__ wf_hi, const ushort_t* __restrict__ wf_lo,
    const ushort_t* __restrict__ g_hi, const ushort_t* __restrict__ g_lo,
    const float* __restrict__ bias1c,
    const float* __restrict__ ew1,   // d2 row (row 256), fp32
    const float* __restrict__ eb2, const float* __restrict__ cb1, const float* __restrict__ cw2,
    const int* __restrict__ csr_eid,
    void* __restrict__ m_out, float* __restrict__ tbuf,
    int layer, float* __restrict__ agg_h, float* __restrict__ agg_x)
{
    using MT = typename MSel<MODE>::T;
    MT* m_buf = (MT*)m_out;

    __shared__ __align__(16) ushort_t s_acth[4][16 * SACT];
    __shared__ __align__(16) ushort_t s_actl[4][16 * SACT];
    __shared__ float s_d2[4][16], s_dist[4][16], s_diff[4][16][3];
    __shared__ int s_row[4][16];

    const int tid = threadIdx.x;
    const int w = tid >> 6, lane = tid & 63;
    const int lo = lane & 15, q = lane >> 4;
    const int e0 = blockIdx.x * 64 + w * 16;

    const ushort_t* wAh  = wf_hi + (size_t)layer * 4 * 16384;
    const ushort_t* wAl  = wf_lo + (size_t)layer * 4 * 16384;
    const ushort_t* wBh  = wAh + 16384;
    const ushort_t* wBl  = wAl + 16384;
    const ushort_t* wW2h = wAh + 32768;
    const ushort_t* wW2l = wAl + 32768;
    const ushort_t* wC1h = wAh + 49152;
    const ushort_t* wC1l = wAl + 49152;
    const ushort_t* wgh  = g_hi + (size_t)layer * 4096;
    const ushort_t* wgl  = g_lo + (size_t)layer * 4096;
    const float* wd2 = ew1 + (size_t)layer * 385 * 128 + (size_t)256 * 128;
    const float* b1v = bias1c + layer * 128;
    const float* b2v = eb2 + layer * 128;
    const float* cbv = cb1 + layer * 128;
    const float* c2v = cw2 + layer * 128;

    // ---- phase 0: geometry ----
    if (lane < 16) {
        int slot = e0 + lane;
        int e = (MODE < 2) ? csr_eid[slot] : slot;
        int r = ei[e], c = ei[N_EDGES + e];
        s_row[w][lane] = r;
        float dx = x_cur[r * 3 + 0] - x_cur[c * 3 + 0];
        float dy = x_cur[r * 3 + 1] - x_cur[c * 3 + 1];
        float dz = x_cur[r * 3 + 2] - x_cur[c * 3 + 2];
        float d2 = dx * dx + dy * dy + dz * dz;
        s_d2[w][lane] = d2;
        s_dist[w][lane] = sqrtf(d2 + EPSV);
        s_diff[w][lane][0] = dx; s_diff[w][lane][1] = dy; s_diff[w][lane][2] = dz;
    }
    int eidL = (MODE < 2) ? csr_eid[e0 + lo] : (e0 + lo);
    int er = ei[eidL];
    int ec = ei[N_EDGES + eidL];
    __syncthreads();   // B1

    // ---- A fragments: h_row, h_col (hi/lo), ea (split in-register, K 16->32 pad) ----
    s8 aRh[4], aRl[4], aCh[4], aCl[4];
#pragma unroll
    for (int kt = 0; kt < 4; ++kt) {
        size_t ro = (size_t)er * 128 + kt * 32 + q * 8;
        size_t co = (size_t)ec * 128 + kt * 32 + q * 8;
        aRh[kt] = *(const s8*)(hbf_hi + ro);
        aRl[kt] = *(const s8*)(hbf_lo + ro);
        aCh[kt] = *(const s8*)(hbf_hi + co);
        aCl[kt] = *(const s8*)(hbf_lo + co);
    }
    s8 aEAh = {0,0,0,0,0,0,0,0}, aEAl = {0,0,0,0,0,0,0,0};
    if (q < 2) {
        const float* eap = ea + (size_t)eidL * 16 + q * 8;
#pragma unroll
        for (int i = 0; i < 8; ++i) {
            ushort_t hh, ll;
            split_f16(eap[i], hh, ll);
            aEAh[i] = (short)hh; aEAl[i] = (short)ll;
        }
    }

    // ---- GEMM1: y1 = silu(hR@W1a + hC@W1b + ea@G + d2*wd2 + b1') ----
    float d2r[4];
#pragma unroll
    for (int r = 0; r < 4; ++r) d2r[r] = s_d2[w][q * 4 + r];

#pragma unroll
    for (int nt = 0; nt < 8; ++nt) {
        f4 aH = {0.f, 0.f, 0.f, 0.f};
        f4 aL = {0.f, 0.f, 0.f, 0.f};
        {
            s8 bGh = *(const s8*)(wgh + ((size_t)nt * 64 + lane) * 8);
            s8 bGl = *(const s8*)(wgl + ((size_t)nt * 64 + lane) * 8);
            aH = mfma16(aEAh, bGh, aH);
            aL = mfma16(aEAh, bGl, aL);
            aL = mfma16(aEAl, bGh, aL);
        }
#pragma unroll
        for (int kt = 0; kt < 4; ++kt) {
            size_t base = ((size_t)(nt * 4 + kt) * 64 + lane) * 8;
            s8 bh = *(const s8*)(wAh + base);
            s8 bl = *(const s8*)(wAl + base);
            aH = mfma16(aRh[kt], bh, aH);
            aL = mfma16(aRh[kt], bl, aL);
            aL = mfma16(aRl[kt], bh, aL);
            s8 ch = *(const s8*)(wBh + base);
            s8 cl = *(const s8*)(wBl + base);
            aH = mfma16(aCh[kt], ch, aH);
            aL = mfma16(aCh[kt], cl, aL);
            aL = mfma16(aCl[kt], ch, aL);
        }
        float bb = b1v[nt * 16 + lo];
        float wv = wd2[nt * 16 + lo];
#pragma unroll
        for (int r = 0; r < 4; ++r) {
            float v = silu_f(aH[r] + aL[r] * INV4096 + bb + d2r[r] * wv);
            int off = (q * 4 + r) * SACT + nt * 16 + lo;
            split_f16(v, s_acth[w][off], s_actl[w][off]);
        }
    }
    __syncthreads();   // B2

    // ---- GEMM2: m = silu(y1 @ W2 + b2) ----
    s8 aYh[4], aYl[4];
#pragma unroll
    for (int kt = 0; kt < 4; ++kt) {
        aYh[kt] = *(const s8*)&s_acth[w][lo * SACT + kt * 32 + q * 8];
        aYl[kt] = *(const s8*)&s_actl[w][lo * SACT + kt * 32 + q * 8];
    }
    __syncthreads();   // B3

    int rowm[4];
#pragma unroll
    for (int r = 0; r < 4; ++r) rowm[r] = s_row[w][q * 4 + r];

    f4 mv[8];
#pragma unroll
    for (int nt = 0; nt < 8; ++nt) {
        f4 aH = {0.f, 0.f, 0.f, 0.f};
        f4 aL = {0.f, 0.f, 0.f, 0.f};
#pragma unroll
        for (int kt = 0; kt < 4; ++kt) {
            size_t base = ((size_t)(nt * 4 + kt) * 64 + lane) * 8;
            s8 bh = *(const s8*)(wW2h + base);
            s8 bl = *(const s8*)(wW2l + base);
            aH = mfma16(aYh[kt], bh, aH);
            aL = mfma16(aYh[kt], bl, aL);
            aL = mfma16(aYl[kt], bh, aL);
        }
        float bb = b2v[nt * 16 + lo];
#pragma unroll
        for (int r = 0; r < 4; ++r) aH[r] = silu_f(aH[r] + aL[r] * INV4096 + bb);
        mv[nt] = aH;
    }
    // store m (split) for GEMM3 + emit m (coalesced store or atomic fallback)
#pragma unroll
    for (int nt = 0; nt < 8; ++nt) {
#pragma unroll
        for (int r = 0; r < 4; ++r) {
            int off = (q * 4 + r) * SACT + nt * 16 + lo;
            split_f16(mv[nt][r], s_acth[w][off], s_actl[w][off]);
            if (MODE < 2)
                m_buf[(size_t)(e0 + q * 4 + r) * HDIM + nt * 16 + lo] = (MT)mv[nt][r];
            else
                atomicAdd(&agg_h[(size_t)rowm[r] * HDIM + nt * 16 + lo], mv[nt][r]);
        }
    }
    __syncthreads();   // B4

    // ---- GEMM3: c = silu(m @ C1 + cb) ; w = tanh(c . c2) ----
    s8 aMh[4], aMl[4];
#pragma unroll
    for (int kt = 0; kt < 4; ++kt) {
        aMh[kt] = *(const s8*)&s_acth[w][lo * SACT + kt * 32 + q * 8];
        aMl[kt] = *(const s8*)&s_actl[w][lo * SACT + kt * 32 + q * 8];
    }

    float wpart[4] = {0.f, 0.f, 0.f, 0.f};
#pragma unroll
    for (int nt = 0; nt < 8; ++nt) {
        f4 aH = {0.f, 0.f, 0.f, 0.f};
        f4 aL = {0.f, 0.f, 0.f, 0.f};
#pragma unroll
        for (int kt = 0; kt < 4; ++kt) {
            size_t base = ((size_t)(nt * 4 + kt) * 64 + lane) * 8;
            s8 bh = *(const s8*)(wC1h + base);
            s8 bl = *(const s8*)(wC1l + base);
            aH = mfma16(aMh[kt], bh, aH);
            aL = mfma16(aMh[kt], bl, aL);
            aL = mfma16(aMl[kt], bh, aL);
        }
        float bb = cbv[nt * 16 + lo];
        float cc = c2v[nt * 16 + lo];
#pragma unroll
        for (int r = 0; r < 4; ++r)
            wpart[r] += silu_f(aH[r] + aL[r] * INV4096 + bb) * cc;
    }
#pragma unroll
    for (int r = 0; r < 4; ++r) {
#pragma unroll
        for (int mask = 1; mask < 16; mask <<= 1)
            wpart[r] += __shfl_xor(wpart[r], mask, 16);
    }
    if (lo < 3) {
#pragma unroll
        for (int r = 0; r < 4; ++r) {
            int mm = q * 4 + r;
            float wv = tanhf(wpart[r]);
            float val = s_diff[w][mm][lo] / (s_dist[w][mm] + EPSV) * wv;
            if (MODE < 2)
                tbuf[(size_t)(e0 + mm) * 3 + lo] = val;
            else
                atomicAdd(&agg_x[rowm[r] * 3 + lo], val);
        }
    }
}

// ============ node kernel: CSR gather + 2-layer MLP ============
template<int MODE>
__global__ void node_kernel(float* __restrict__ h_feat, float* __restrict__ x_cur,
                            ushort_t* __restrict__ hbf_hi, ushort_t* __restrict__ hbf_lo,
                            const int* __restrict__ row_start,
                            const void* __restrict__ m_out, const float* __restrict__ tbuf,
                            const float* __restrict__ agg_h, const float* __restrict__ agg_x,
                            const float* __restrict__ mask,
                            const float* __restrict__ n1p, const float* __restrict__ nb1p,
                            const float* __restrict__ n2p, const float* __restrict__ nb2p, int layer) {
    using MT = typename MSel<MODE>::T;
    const MT* m_buf = (const MT*)m_out;

    __shared__ float s_cat[2 * HDIM];
    __shared__ float s_u[HDIM];
    __shared__ float s_tp[96];
    int n = blockIdx.x, j = threadIdx.x;
    const size_t w1o = (size_t)layer * 2 * HDIM * HDIM;
    const size_t w2o = (size_t)layer * HDIM * HDIM;
    const size_t bo  = (size_t)layer * HDIM;

    int rs = 0, re = 0;
    if (MODE < 2) { rs = row_start[n]; re = row_start[n + 1]; }

    s_cat[j] = h_feat[(size_t)n * HDIM + j];
    if (MODE < 2) {
        float a0 = 0.f, a1 = 0.f, a2 = 0.f, a3 = 0.f;
        int s = rs;
        for (; s + 4 <= re; s += 4) {
            a0 += (float)m_buf[(size_t)(s + 0) * HDIM + j];
            a1 += (float)m_buf[(size_t)(s + 1) * HDIM + j];
            a2 += (float)m_buf[(size_t)(s + 2) * HDIM + j];
            a3 += (float)m_buf[(size_t)(s + 3) * HDIM + j];
        }
        for (; s < re; ++s) a0 += (float)m_buf[(size_t)s * HDIM + j];
        s_cat[HDIM + j] = (a0 + a1) + (a2 + a3);
        if (j < 96) {
            int comp = j % 3, k = j / 3;
            float ts = 0.f;
            for (int sl = rs + k; sl < re; sl += 32) ts += tbuf[(size_t)sl * 3 + comp];
            s_tp[j] = ts;
        }
    } else {
        s_cat[HDIM + j] = agg_h[(size_t)n * HDIM + j];
    }
    __syncthreads();

    float u = nb1p[bo + j];
    for (int i0 = 0; i0 < 2 * HDIM; i0 += 4) {
        float4 c = *(const float4*)&s_cat[i0];
        u += c.x * n1p[w1o + (size_t)(i0 + 0) * HDIM + j];
        u += c.y * n1p[w1o + (size_t)(i0 + 1) * HDIM + j];
        u += c.z * n1p[w1o + (size_t)(i0 + 2) * HDIM + j];
        u += c.w * n1p[w1o + (size_t)(i0 + 3) * HDIM + j];
    }
    s_u[j] = silu_f(u);
    __syncthreads();
    float acc = nb2p[bo + j];
    for (int i0 = 0; i0 < HDIM; i0 += 4) {
        float4 c = *(const float4*)&s_u[i0];
        acc += c.x * n2p[w2o + (size_t)(i0 + 0) * HDIM + j];
        acc += c.y * n2p[w2o + (size_t)(i0 + 1) * HDIM + j];
        acc += c.z * n2p[w2o + (size_t)(i0 + 2) * HDIM + j];
        acc += c.w * n2p[w2o + (size_t)(i0 + 3) * HDIM + j];
    }
    float nh = s_cat[j] + acc;
    h_feat[(size_t)n * HDIM + j] = nh;
    split_f16(nh, hbf_hi[(size_t)n * HDIM + j], hbf_lo[(size_t)n * HDIM + j]);
    if (j < 3) {
        float ax;
        if (MODE < 2) {
            float ts = 0.f;
            for (int k = 0; k < 32; ++k) ts += s_tp[k * 3 + j];
            ax = ts;
        } else {
            ax = agg_x[n * 3 + j];
        }
        x_cur[n * 3 + j] += ax * mask[n];
    }
}

__global__ void out_kernel(const float* __restrict__ x_cur, const float* __restrict__ x_in,
                           const float* __restrict__ mask, float* __restrict__ out) {
    int idx = blockIdx.x * blockDim.x + threadIdx.x;
    if (idx < N_NODES * 3) {
        int n = idx / 3;
        out[idx] = (x_cur[idx] - x_in[idx]) * mask[n];
    }
}

extern "C" void kernel_launch(void* const* d_in, const int* in_sizes, int n_in,
                              void* d_out, int out_size, void* d_ws, size_t ws_size,
                              hipStream_t stream) {
    const float* h    = (const float*)d_in[0];
    const float* x    = (const float*)d_in[1];
    const int*   ei   = (const int*)d_in[2];
    const float* ea   = (const float*)d_in[3];
    const float* t    = (const float*)d_in[4];
    const float* mask = (const float*)d_in[5];
    const float* tw1  = (const float*)d_in[6];
    const float* tb1  = (const float*)d_in[7];
    const float* tw2  = (const float*)d_in[8];
    const float* tb2  = (const float*)d_in[9];
    const float* new_ = (const float*)d_in[10];
    const float* neb  = (const float*)d_in[11];
    const float* eew  = (const float*)d_in[12];
    const float* eeb  = (const float*)d_in[13];
    const float* ew1  = (const float*)d_in[14];
    const float* eb1  = (const float*)d_in[15];
    const float* ew2  = (const float*)d_in[16];
    const float* eb2  = (const float*)d_in[17];
    const float* cw1  = (const float*)d_in[18];
    const float* cb1  = (const float*)d_in[19];
    const float* cw2  = (const float*)d_in[20];
    const float* nw1  = (const float*)d_in[21];
    const float* nb1  = (const float*)d_in[22];
    const float* nw2  = (const float*)d_in[23];
    const float* nb2  = (const float*)d_in[24];

    // ---- workspace carve-out (256 B aligned) ----
    char* p = (char*)d_ws;
    auto alloc = [&](size_t bytes) -> char* {
        char* r = p;
        p += (bytes + 255) & ~(size_t)255;
        return r;
    };
    float* t_emb    = (float*)alloc(HDIM * 4);
    float* h_feat   = (float*)alloc((size_t)N_NODES * HDIM * 4);
    float* x_cur    = (float*)alloc((size_t)N_NODES * 3 * 4);
    float* agg_h    = (float*)alloc((size_t)N_NODES * HDIM * 4);
    float* agg_x    = (float*)alloc((size_t)N_NODES * 3 * 4);
    float* bias1c   = (float*)alloc(NLAYERS * HDIM * 4);
    ushort_t* hbf_hi = (ushort_t*)alloc((size_t)N_NODES * HDIM * 2);
    ushort_t* hbf_lo = (ushort_t*)alloc((size_t)N_NODES * HDIM * 2);
    ushort_t* wf_hi  = (ushort_t*)alloc((size_t)NLAYERS * 4 * 16384 * 2);
    ushort_t* wf_lo  = (ushort_t*)alloc((size_t)NLAYERS * 4 * 16384 * 2);
    ushort_t* g_hi   = (ushort_t*)alloc((size_t)NLAYERS * 4096 * 2);
    ushort_t* g_lo   = (ushort_t*)alloc((size_t)NLAYERS * 4096 * 2);
    int* deg        = (int*)alloc((size_t)N_NODES * 4);
    int* row_start  = (int*)alloc((size_t)(N_NODES + 1) * 4);
    int* cursor     = (int*)alloc((size_t)N_NODES * 4);
    int* csr_eid    = (int*)alloc((size_t)N_EDGES * 4);
    float* tbuf     = (float*)alloc((size_t)N_EDGES * 3 * 4);
    size_t base_used = (size_t)(p - (char*)d_ws);
    void* m_buf = (void*)p;

    // mode selection on ws_size (host-side, constant across calls -> graph-safe)
    int mode;
    if (base_used + (size_t)N_EDGES * HDIM * 4 <= ws_size)      mode = 0;  // fp32 m_buf
    else if (base_used + (size_t)N_EDGES * HDIM * 2 <= ws_size) mode = 1;  // fp16 m_buf
    else                                                        mode = 2;  // atomic fallback

    repack_weights<<<(NLAYERS * 4 * 16384 + 255) / 256, 256, 0, stream>>>(ew1, ew2, cw1, wf_hi, wf_lo);
    prep_g<<<(NLAYERS * 4096 + NLAYERS * 128 + 255) / 256, 256, 0, stream>>>(eew, eeb, ew1, eb1, g_hi, g_lo, bias1c);
    temb_kernel<<<1, HDIM, 0, stream>>>(t, tw1, tb1, tw2, tb2, t_emb);
    hfeat_kernel<<<N_NODES, HDIM, 0, stream>>>(h, new_, neb, t_emb, h_feat, hbf_hi, hbf_lo);
    xinit_kernel<<<(N_NODES * 3 + 255) / 256, 256, 0, stream>>>(x, x_cur);

    if (mode < 2) {
        hipMemsetAsync(deg, 0, (size_t)N_NODES * 4, stream);
        deg_kernel<<<(N_EDGES + 255) / 256, 256, 0, stream>>>(ei, deg);
        scan_kernel<<<1, 256, 0, stream>>>(deg, row_start, cursor);
        scatter_kernel<<<(N_EDGES + 255) / 256, 256, 0, stream>>>(ei, cursor, csr_eid);
    }

    for (int l = 0; l < NLAYERS; ++l) {
        if (mode == 2) {
            hipMemsetAsync(agg_h, 0, (size_t)N_NODES * HDIM * 4, stream);
            hipMemsetAsync(agg_x, 0, (size_t)N_NODES * 3 * 4, stream);
        }
        if (mode == 0)
            edge_mfma_kernel<0><<<N_EDGES / 64, 256, 0, stream>>>(
                ei, ea, x_cur, hbf_hi, hbf_lo, wf_hi, wf_lo, g_hi, g_lo, bias1c,
                ew1, eb2, cb1, cw2, csr_eid, m_buf, tbuf, l, agg_h, agg_x);
        else if (mode == 1)
            edge_mfma_kernel<1><<<N_EDGES / 64, 256, 0, stream>>>(
                ei, ea, x_cur, hbf_hi, hbf_lo, wf_hi, wf_lo, g_hi, g_lo, bias1c,
                ew1, eb2, cb1, cw2, csr_eid, m_buf, tbuf, l, agg_h, agg_x);
        else
            edge_mfma_kernel<2><<<N_EDGES / 64, 256, 0, stream>>>(
                ei, ea, x_cur, hbf_hi, hbf_lo, wf_hi, wf_lo, g_hi, g_lo, bias1c,
                ew1, eb2, cb1, cw2, csr_eid, m_buf, tbuf, l, agg_h, agg_x);

        if (mode == 0)
            node_kernel<0><<<N_NODES, HDIM, 0, stream>>>(
                h_feat, x_cur, hbf_hi, hbf_lo, row_start, m_buf, tbuf,
                agg_h, agg_x, mask, nw1, nb1, nw2, nb2, l);
        else if (mode == 1)
            node_kernel<1><<<N_NODES, HDIM, 0, stream>>>(
                h_feat, x_cur, hbf_hi, hbf_lo, row_start, m_buf, tbuf,
                agg_h, agg_x, mask, nw1, nb1, nw2, nb2, l);
        else
            node_kernel<2><<<N_NODES, HDIM, 0, stream>>>(
                h_feat, x_cur, hbf_hi, hbf_lo, row_start, m_buf, tbuf,
                agg_h, agg_x, mask, nw1, nb1, nw2, nb2, l);
    }

    out_kernel<<<(N_NODES * 3 + 255) / 256, 256, 0, stream>>>(x_cur, x, mask, (float*)d_out);
}

// Round 7
// 1787.598 us; speedup vs baseline: 3.2493x; 1.1396x over previous
//
#include <hip/hip_runtime.h>
#include <hip/hip_bf16.h>

#define N_NODES 10000
#define N_EDGES 320000
#define HDIM 128
#define NODE_IN 64
#define EDGE_IN 16
#define NLAYERS 4
#define EPSV 1e-8f
#define SACT 136       // LDS activation row stride (fp16 elems)
#define INV4096 2.44140625e-4f

typedef unsigned short ushort_t;
typedef __attribute__((ext_vector_type(8))) short s8;        // 8 fp16 bit-pattern (4 VGPRs)
typedef __attribute__((ext_vector_type(8))) _Float16 h8;
typedef __attribute__((ext_vector_type(4))) float f4;

__device__ __forceinline__ float silu_f(float z) { return z / (1.0f + __expf(-z)); }

__device__ __forceinline__ f4 mfma16(s8 a, s8 b, f4 c) {
    return __builtin_amdgcn_mfma_f32_16x16x32_f16(
        __builtin_bit_cast(h8, a), __builtin_bit_cast(h8, b), c, 0, 0, 0);
}

// fp32 -> fp16 hi + (residual*4096) lo   (rep error ~2^-23 relative)
__device__ __forceinline__ void split_f16(float x, ushort_t& hi, ushort_t& lo) {
    _Float16 h = (_Float16)x;
    float hf = (float)h;
    _Float16 l = (_Float16)((x - hf) * 4096.0f);
    hi = __builtin_bit_cast(ushort_t, h);
    lo = __builtin_bit_cast(ushort_t, l);
}

// ============ CSR build ============
__global__ void deg_kernel(const int* __restrict__ ei, int* __restrict__ deg) {
    int e = blockIdx.x * 256 + threadIdx.x;
    if (e < N_EDGES) atomicAdd(&deg[ei[e]], 1);
}

__global__ void scan_kernel(const int* __restrict__ deg, int* __restrict__ row_start,
                            int* __restrict__ cursor) {
    __shared__ int s_part[256];
    const int CH = 40;   // 256*40 = 10240 >= N_NODES
    int t = threadIdx.x;
    int base = t * CH;
    int sum = 0;
    for (int i = 0; i < CH; ++i) { int n = base + i; if (n < N_NODES) sum += deg[n]; }
    s_part[t] = sum;
    __syncthreads();
    for (int d = 1; d < 256; d <<= 1) {
        int v = (t >= d) ? s_part[t - d] : 0;
        __syncthreads();
        s_part[t] += v;
        __syncthreads();
    }
    int off = s_part[t] - sum;
    for (int i = 0; i < CH; ++i) {
        int n = base + i;
        if (n < N_NODES) { row_start[n] = off; cursor[n] = off; off += deg[n]; }
    }
    if (t == 255) row_start[N_NODES] = s_part[255];
}

__global__ void scatter_kernel(const int* __restrict__ ei, int* __restrict__ cursor,
                               int* __restrict__ csr_eid) {
    int e = blockIdx.x * 256 + threadIdx.x;
    if (e < N_EDGES) {
        int r = ei[e];
        int pos = atomicAdd(&cursor[r], 1);
        csr_eid[pos] = e;
    }
}

// ============ prep 1: repack W1a,W1b,W2,C1 into MFMA B-frag order, split fp16 hi/lo ============
__global__ void repack_weights(const float* __restrict__ ew1, const float* __restrict__ ew2,
                               const float* __restrict__ cw1,
                               ushort_t* __restrict__ wf_hi, ushort_t* __restrict__ wf_lo) {
    int gid = blockIdx.x * 256 + threadIdx.x;
    const int total = NLAYERS * 4 * 16384;
    if (gid >= total) return;
    int l   = gid / (4 * 16384);
    int rem = gid % (4 * 16384);
    int m4  = rem / 16384;
    int idx = rem & 16383;
    int b    = idx >> 9;
    int lane = (idx >> 3) & 63;
    int j    = idx & 7;
    int nt = b >> 2, kt = b & 3;
    int k = kt * 32 + ((lane >> 4) << 3) + j;
    int n = (nt << 4) + (lane & 15);
    float v;
    if (m4 == 0)      v = ew1[(size_t)l * 385 * 128 + (size_t)k * 128 + n];
    else if (m4 == 1) v = ew1[(size_t)l * 385 * 128 + (size_t)(128 + k) * 128 + n];
    else if (m4 == 2) v = ew2[(size_t)l * 16384 + k * 128 + n];
    else              v = cw1[(size_t)l * 16384 + k * 128 + n];
    split_f16(v, wf_hi[gid], wf_lo[gid]);
}

// ============ prep 2: G = eew @ W1c (K padded to 32, frag-packed, split) + bias fold ============
__global__ void prep_g(const float* __restrict__ eew, const float* __restrict__ eeb,
                       const float* __restrict__ ew1, const float* __restrict__ eb1,
                       ushort_t* __restrict__ g_hi, ushort_t* __restrict__ g_lo,
                       float* __restrict__ bias1c) {
    int gid = blockIdx.x * 256 + threadIdx.x;
    const int T1 = NLAYERS * 4096;
    if (gid < T1) {
        int l = gid >> 12;
        int idx = gid & 4095;
        int nt = idx >> 9;
        int lane = (idx >> 3) & 63;
        int j = idx & 7;
        int q = lane >> 4;
        int n = (nt << 4) + (lane & 15);
        int k = q * 8 + j;
        float v = 0.f;
        if (k < EDGE_IN) {
            const float* w1c = ew1 + (size_t)l * 385 * 128 + (size_t)257 * 128;
            float acc = 0.f;
            for (int c = 0; c < HDIM; ++c) acc += eew[k * 128 + c] * w1c[(size_t)c * 128 + n];
            v = acc;
        }
        split_f16(v, g_hi[gid], g_lo[gid]);
    } else if (gid < T1 + NLAYERS * 128) {
        int r = gid - T1;
        int l = r >> 7;
        int n = r & 127;
        const float* w1c = ew1 + (size_t)l * 385 * 128 + (size_t)257 * 128;
        float acc = eb1[l * 128 + n];
        for (int c = 0; c < HDIM; ++c) acc += eeb[c] * w1c[(size_t)c * 128 + n];
        bias1c[r] = acc;
    }
}

// ============ t_emb ============
__global__ void temb_kernel(const float* t, const float* tw1, const float* tb1,
                            const float* tw2, const float* tb2, float* t_emb) {
    __shared__ float s_a[HDIM];
    int j = threadIdx.x;
    s_a[j] = silu_f(t[0] * tw1[j] + tb1[j]);
    __syncthreads();
    float acc = tb2[j];
    for (int k = 0; k < HDIM; ++k) acc += s_a[k] * tw2[k * HDIM + j];
    t_emb[j] = acc;
}

// ============ h_feat init (fp32 + split fp16 mirror) ============
__global__ void hfeat_kernel(const float* __restrict__ h, const float* __restrict__ new_,
                             const float* __restrict__ neb, const float* __restrict__ t_emb,
                             float* __restrict__ h_feat,
                             ushort_t* __restrict__ hbf_hi, ushort_t* __restrict__ hbf_lo) {
    __shared__ float s_h[NODE_IN];
    int n = blockIdx.x, j = threadIdx.x;
    if (j < NODE_IN) s_h[j] = h[(size_t)n * NODE_IN + j];
    __syncthreads();
    float acc = neb[j] + t_emb[j];
#pragma unroll 8
    for (int i = 0; i < NODE_IN; ++i) acc += s_h[i] * new_[i * HDIM + j];
    h_feat[(size_t)n * HDIM + j] = acc;
    split_f16(acc, hbf_hi[(size_t)n * HDIM + j], hbf_lo[(size_t)n * HDIM + j]);
}

__global__ void xinit_kernel(const float* x, float* x_cur) {
    int idx = blockIdx.x * blockDim.x + threadIdx.x;
    if (idx < N_NODES * 3) x_cur[idx] = x[idx];
}

// ============ MFMA edge kernel: 1 wave = 16 CSR slots, segmented-reduce aggregation ============
__global__ __launch_bounds__(256) void edge_mfma_kernel(
    const int* __restrict__ ei, const float* __restrict__ ea,
    const float* __restrict__ x_cur,
    const ushort_t* __restrict__ hbf_hi, const ushort_t* __restrict__ hbf_lo,
    const ushort_t* __restrict__ wf_hi, const ushort_t* __restrict__ wf_lo,
    const ushort_t* __restrict__ g_hi, const ushort_t* __restrict__ g_lo,
    const float* __restrict__ bias1c,
    const float* __restrict__ ew1,   // d2 row (row 256), fp32
    const float* __restrict__ eb2, const float* __restrict__ cb1, const float* __restrict__ cw2,
    const int* __restrict__ csr_eid,
    int layer, float* __restrict__ agg_h, float* __restrict__ agg_x)
{
    __shared__ __align__(16) ushort_t s_acth[4][16 * SACT];
    __shared__ __align__(16) ushort_t s_actl[4][16 * SACT];
    __shared__ float s_d2[4][16], s_dist[4][16], s_diff[4][16][3];
    __shared__ int s_row[4][16];
    __shared__ int s_drows[4][16];
    __shared__ int s_dcnt[4];

    const int tid = threadIdx.x;
    const int w = tid >> 6, lane = tid & 63;
    const int lo = lane & 15, q = lane >> 4;
    const int e0 = blockIdx.x * 64 + w * 16;

    const ushort_t* wAh  = wf_hi + (size_t)layer * 4 * 16384;
    const ushort_t* wAl  = wf_lo + (size_t)layer * 4 * 16384;
    const ushort_t* wBh  = wAh + 16384;
    const ushort_t* wBl  = wAl + 16384;
    const ushort_t* wW2h = wAh + 32768;
    const ushort_t* wW2l = wAl + 32768;
    const ushort_t* wC1h = wAh + 49152;
    const ushort_t* wC1l = wAl + 49152;
    const ushort_t* wgh  = g_hi + (size_t)layer * 4096;
    const ushort_t* wgl  = g_lo + (size_t)layer * 4096;
    const float* wd2 = ew1 + (size_t)layer * 385 * 128 + (size_t)256 * 128;
    const float* b1v = bias1c + layer * 128;
    const float* b2v = eb2 + layer * 128;
    const float* cbv = cb1 + layer * 128;
    const float* c2v = cw2 + layer * 128;

    // ---- phase 0: geometry ----
    if (lane < 16) {
        int slot = e0 + lane;
        int e = csr_eid[slot];
        int r = ei[e], c = ei[N_EDGES + e];
        s_row[w][lane] = r;
        float dx = x_cur[r * 3 + 0] - x_cur[c * 3 + 0];
        float dy = x_cur[r * 3 + 1] - x_cur[c * 3 + 1];
        float dz = x_cur[r * 3 + 2] - x_cur[c * 3 + 2];
        float d2 = dx * dx + dy * dy + dz * dz;
        s_d2[w][lane] = d2;
        s_dist[w][lane] = sqrtf(d2 + EPSV);
        s_diff[w][lane][0] = dx; s_diff[w][lane][1] = dy; s_diff[w][lane][2] = dz;
    }
    int eidL = csr_eid[e0 + lo];
    int er = ei[eidL];
    int ec = ei[N_EDGES + eidL];
    __syncthreads();   // B1

    // wave-local distinct-row list (CSR slots are row-sorted -> ~1.5 distinct rows avg)
    if (lane == 0) {
        int cnt = 0, prev = -1;
        for (int i = 0; i < 16; ++i) {
            int r = s_row[w][i];
            if (r != prev) { s_drows[w][cnt++] = r; prev = r; }
        }
        s_dcnt[w] = cnt;
    }

    // ---- A fragments: h_row, h_col (hi/lo), ea (split in-register, K 16->32 pad) ----
    s8 aRh[4], aRl[4], aCh[4], aCl[4];
#pragma unroll
    for (int kt = 0; kt < 4; ++kt) {
        size_t ro = (size_t)er * 128 + kt * 32 + q * 8;
        size_t co = (size_t)ec * 128 + kt * 32 + q * 8;
        aRh[kt] = *(const s8*)(hbf_hi + ro);
        aRl[kt] = *(const s8*)(hbf_lo + ro);
        aCh[kt] = *(const s8*)(hbf_hi + co);
        aCl[kt] = *(const s8*)(hbf_lo + co);
    }
    s8 aEAh = {0,0,0,0,0,0,0,0}, aEAl = {0,0,0,0,0,0,0,0};
    if (q < 2) {
        const float* eap = ea + (size_t)eidL * 16 + q * 8;
#pragma unroll
        for (int i = 0; i < 8; ++i) {
            ushort_t hh, ll;
            split_f16(eap[i], hh, ll);
            aEAh[i] = (short)hh; aEAl[i] = (short)ll;
        }
    }

    // ---- GEMM1: y1 = silu(hR@W1a + hC@W1b + ea@G + d2*wd2 + b1') ----
    float d2r[4];
#pragma unroll
    for (int r = 0; r < 4; ++r) d2r[r] = s_d2[w][q * 4 + r];

#pragma unroll
    for (int nt = 0; nt < 8; ++nt) {
        f4 aH = {0.f, 0.f, 0.f, 0.f};
        f4 aL = {0.f, 0.f, 0.f, 0.f};
        {
            s8 bGh = *(const s8*)(wgh + ((size_t)nt * 64 + lane) * 8);
            s8 bGl = *(const s8*)(wgl + ((size_t)nt * 64 + lane) * 8);
            aH = mfma16(aEAh, bGh, aH);
            aL = mfma16(aEAh, bGl, aL);
            aL = mfma16(aEAl, bGh, aL);
        }
#pragma unroll
        for (int kt = 0; kt < 4; ++kt) {
            size_t base = ((size_t)(nt * 4 + kt) * 64 + lane) * 8;
            s8 bh = *(const s8*)(wAh + base);
            s8 bl = *(const s8*)(wAl + base);
            aH = mfma16(aRh[kt], bh, aH);
            aL = mfma16(aRh[kt], bl, aL);
            aL = mfma16(aRl[kt], bh, aL);
            s8 ch = *(const s8*)(wBh + base);
            s8 cl = *(const s8*)(wBl + base);
            aH = mfma16(aCh[kt], ch, aH);
            aL = mfma16(aCh[kt], cl, aL);
            aL = mfma16(aCl[kt], ch, aL);
        }
        float bb = b1v[nt * 16 + lo];
        float wv = wd2[nt * 16 + lo];
#pragma unroll
        for (int r = 0; r < 4; ++r) {
            float v = silu_f(aH[r] + aL[r] * INV4096 + bb + d2r[r] * wv);
            int off = (q * 4 + r) * SACT + nt * 16 + lo;
            split_f16(v, s_acth[w][off], s_actl[w][off]);
        }
    }
    __syncthreads();   // B2

    // ---- GEMM2: m = silu(y1 @ W2 + b2) ----
    s8 aYh[4], aYl[4];
#pragma unroll
    for (int kt = 0; kt < 4; ++kt) {
        aYh[kt] = *(const s8*)&s_acth[w][lo * SACT + kt * 32 + q * 8];
        aYl[kt] = *(const s8*)&s_actl[w][lo * SACT + kt * 32 + q * 8];
    }
    __syncthreads();   // B3

    int rowm[4];
#pragma unroll
    for (int r = 0; r < 4; ++r) rowm[r] = s_row[w][q * 4 + r];

    f4 mv[8];
#pragma unroll
    for (int nt = 0; nt < 8; ++nt) {
        f4 aH = {0.f, 0.f, 0.f, 0.f};
        f4 aL = {0.f, 0.f, 0.f, 0.f};
#pragma unroll
        for (int kt = 0; kt < 4; ++kt) {
            size_t base = ((size_t)(nt * 4 + kt) * 64 + lane) * 8;
            s8 bh = *(const s8*)(wW2h + base);
            s8 bl = *(const s8*)(wW2l + base);
            aH = mfma16(aYh[kt], bh, aH);
            aL = mfma16(aYh[kt], bl, aL);
            aL = mfma16(aYl[kt], bh, aL);
        }
        float bb = b2v[nt * 16 + lo];
#pragma unroll
        for (int r = 0; r < 4; ++r) aH[r] = silu_f(aH[r] + aL[r] * INV4096 + bb);
        mv[nt] = aH;
    }
    // store m (split) for GEMM3
#pragma unroll
    for (int nt = 0; nt < 8; ++nt) {
#pragma unroll
        for (int r = 0; r < 4; ++r) {
            int off = (q * 4 + r) * SACT + nt * 16 + lo;
            split_f16(mv[nt][r], s_acth[w][off], s_actl[w][off]);
        }
    }
    // segmented reduce m over the wave's 16 slots -> atomics per distinct row
    {
        int dcnt = s_dcnt[w];
        for (int di = 0; di < dcnt; ++di) {
            int dr = s_drows[w][di];
#pragma unroll
            for (int nt = 0; nt < 8; ++nt) {
                float v = 0.f;
#pragma unroll
                for (int r = 0; r < 4; ++r) v += (rowm[r] == dr) ? mv[nt][r] : 0.f;
                v += __shfl_xor(v, 16, 64);
                v += __shfl_xor(v, 32, 64);
                if (lane < 16) atomicAdd(&agg_h[(size_t)dr * HDIM + nt * 16 + lane], v);
            }
        }
    }
    __syncthreads();   // B4

    // ---- GEMM3: c = silu(m @ C1 + cb) ; w = tanh(c . c2) ----
    s8 aMh[4], aMl[4];
#pragma unroll
    for (int kt = 0; kt < 4; ++kt) {
        aMh[kt] = *(const s8*)&s_acth[w][lo * SACT + kt * 32 + q * 8];
        aMl[kt] = *(const s8*)&s_actl[w][lo * SACT + kt * 32 + q * 8];
    }

    float wpart[4] = {0.f, 0.f, 0.f, 0.f};
#pragma unroll
    for (int nt = 0; nt < 8; ++nt) {
        f4 aH = {0.f, 0.f, 0.f, 0.f};
        f4 aL = {0.f, 0.f, 0.f, 0.f};
#pragma unroll
        for (int kt = 0; kt < 4; ++kt) {
            size_t base = ((size_t)(nt * 4 + kt) * 64 + lane) * 8;
            s8 bh = *(const s8*)(wC1h + base);
            s8 bl = *(const s8*)(wC1l + base);
            aH = mfma16(aMh[kt], bh, aH);
            aL = mfma16(aMh[kt], bl, aL);
            aL = mfma16(aMl[kt], bh, aL);
        }
        float bb = cbv[nt * 16 + lo];
        float cc = c2v[nt * 16 + lo];
#pragma unroll
        for (int r = 0; r < 4; ++r)
            wpart[r] += silu_f(aH[r] + aL[r] * INV4096 + bb) * cc;
    }
#pragma unroll
    for (int r = 0; r < 4; ++r) {
#pragma unroll
        for (int mask = 1; mask < 16; mask <<= 1)
            wpart[r] += __shfl_xor(wpart[r], mask, 16);
    }
    // trans vector + segmented reduce -> agg_x atomics per distinct row
    {
        float val[4];
#pragma unroll
        for (int r = 0; r < 4; ++r) {
            int mm = q * 4 + r;
            val[r] = (lo < 3)
                ? s_diff[w][mm][lo] / (s_dist[w][mm] + EPSV) * tanhf(wpart[r])
                : 0.f;
        }
        int dcnt = s_dcnt[w];
        for (int di = 0; di < dcnt; ++di) {
            int dr = s_drows[w][di];
            float v = 0.f;
#pragma unroll
            for (int r = 0; r < 4; ++r) v += (rowm[r] == dr) ? val[r] : 0.f;
            v += __shfl_xor(v, 16, 64);
            v += __shfl_xor(v, 32, 64);
            if (lane < 3) atomicAdd(&agg_x[dr * 3 + lane], v);
        }
    }
}

// ============ node kernel: h,x update from agg buffers ============
__global__ void node_kernel(float* __restrict__ h_feat, float* __restrict__ x_cur,
                            ushort_t* __restrict__ hbf_hi, ushort_t* __restrict__ hbf_lo,
                            const float* __restrict__ agg_h, const float* __restrict__ agg_x,
                            const float* __restrict__ mask,
                            const float* __restrict__ n1p, const float* __restrict__ nb1p,
                            const float* __restrict__ n2p, const float* __restrict__ nb2p, int layer) {
    __shared__ float s_cat[2 * HDIM];
    __shared__ float s_u[HDIM];
    int n = blockIdx.x, j = threadIdx.x;
    const size_t w1o = (size_t)layer * 2 * HDIM * HDIM;
    const size_t w2o = (size_t)layer * HDIM * HDIM;
    const size_t bo  = (size_t)layer * HDIM;
    s_cat[j] = h_feat[(size_t)n * HDIM + j];
    s_cat[HDIM + j] = agg_h[(size_t)n * HDIM + j];
    __syncthreads();
    float u = nb1p[bo + j];
    for (int i0 = 0; i0 < 2 * HDIM; i0 += 4) {
        float4 c = *(const float4*)&s_cat[i0];
        u += c.x * n1p[w1o + (size_t)(i0 + 0) * HDIM + j];
        u += c.y * n1p[w1o + (size_t)(i0 + 1) * HDIM + j];
        u += c.z * n1p[w1o + (size_t)(i0 + 2) * HDIM + j];
        u += c.w * n1p[w1o + (size_t)(i0 + 3) * HDIM + j];
    }
    s_u[j] = silu_f(u);
    __syncthreads();
    float acc = nb2p[bo + j];
    for (int i0 = 0; i0 < HDIM; i0 += 4) {
        float4 c = *(const float4*)&s_u[i0];
        acc += c.x * n2p[w2o + (size_t)(i0 + 0) * HDIM + j];
        acc += c.y * n2p[w2o + (size_t)(i0 + 1) * HDIM + j];
        acc += c.z * n2p[w2o + (size_t)(i0 + 2) * HDIM + j];
        acc += c.w * n2p[w2o + (size_t)(i0 + 3) * HDIM + j];
    }
    float nh = s_cat[j] + acc;
    h_feat[(size_t)n * HDIM + j] = nh;
    split_f16(nh, hbf_hi[(size_t)n * HDIM + j], hbf_lo[(size_t)n * HDIM + j]);
    if (j < 3) x_cur[n * 3 + j] += agg_x[n * 3 + j] * mask[n];
}

__global__ void out_kernel(const float* __restrict__ x_cur, const float* __restrict__ x_in,
                           const float* __restrict__ mask, float* __restrict__ out) {
    int idx = blockIdx.x * blockDim.x + threadIdx.x;
    if (idx < N_NODES * 3) {
        int n = idx / 3;
        out[idx] = (x_cur[idx] - x_in[idx]) * mask[n];
    }
}

extern "C" void kernel_launch(void* const* d_in, const int* in_sizes, int n_in,
                              void* d_out, int out_size, void* d_ws, size_t ws_size,
                              hipStream_t stream) {
    const float* h    = (const float*)d_in[0];
    const float* x    = (const float*)d_in[1];
    const int*   ei   = (const int*)d_in[2];
    const float* ea   = (const float*)d_in[3];
    const float* t    = (const float*)d_in[4];
    const float* mask = (const float*)d_in[5];
    const float* tw1  = (const float*)d_in[6];
    const float* tb1  = (const float*)d_in[7];
    const float* tw2  = (const float*)d_in[8];
    const float* tb2  = (const float*)d_in[9];
    const float* new_ = (const float*)d_in[10];
    const float* neb  = (const float*)d_in[11];
    const float* eew  = (const float*)d_in[12];
    const float* eeb  = (const float*)d_in[13];
    const float* ew1  = (const float*)d_in[14];
    const float* eb1  = (const float*)d_in[15];
    const float* ew2  = (const float*)d_in[16];
    const float* eb2  = (const float*)d_in[17];
    const float* cw1  = (const float*)d_in[18];
    const float* cb1  = (const float*)d_in[19];
    const float* cw2  = (const float*)d_in[20];
    const float* nw1  = (const float*)d_in[21];
    const float* nb1  = (const float*)d_in[22];
    const float* nw2  = (const float*)d_in[23];
    const float* nb2  = (const float*)d_in[24];

    // ---- workspace carve-out (256 B aligned) ----
    char* p = (char*)d_ws;
    auto alloc = [&](size_t bytes) -> char* {
        char* r = p;
        p += (bytes + 255) & ~(size_t)255;
        return r;
    };
    float* t_emb    = (float*)alloc(HDIM * 4);
    float* h_feat   = (float*)alloc((size_t)N_NODES * HDIM * 4);
    float* x_cur    = (float*)alloc((size_t)N_NODES * 3 * 4);
    float* agg_h    = (float*)alloc((size_t)N_NODES * HDIM * 4);
    float* agg_x    = (float*)alloc((size_t)N_NODES * 3 * 4);
    float* bias1c   = (float*)alloc(NLAYERS * HDIM * 4);
    ushort_t* hbf_hi = (ushort_t*)alloc((size_t)N_NODES * HDIM * 2);
    ushort_t* hbf_lo = (ushort_t*)alloc((size_t)N_NODES * HDIM * 2);
    ushort_t* wf_hi  = (ushort_t*)alloc((size_t)NLAYERS * 4 * 16384 * 2);
    ushort_t* wf_lo  = (ushort_t*)alloc((size_t)NLAYERS * 4 * 16384 * 2);
    ushort_t* g_hi   = (ushort_t*)alloc((size_t)NLAYERS * 4096 * 2);
    ushort_t* g_lo   = (ushort_t*)alloc((size_t)NLAYERS * 4096 * 2);
    int* deg        = (int*)alloc((size_t)N_NODES * 4);
    int* row_start  = (int*)alloc((size_t)(N_NODES + 1) * 4);
    int* cursor     = (int*)alloc((size_t)N_NODES * 4);
    int* csr_eid    = (int*)alloc((size_t)N_EDGES * 4);

    repack_weights<<<(NLAYERS * 4 * 16384 + 255) / 256, 256, 0, stream>>>(ew1, ew2, cw1, wf_hi, wf_lo);
    prep_g<<<(NLAYERS * 4096 + NLAYERS * 128 + 255) / 256, 256, 0, stream>>>(eew, eeb, ew1, eb1, g_hi, g_lo, bias1c);
    temb_kernel<<<1, HDIM, 0, stream>>>(t, tw1, tb1, tw2, tb2, t_emb);
    hfeat_kernel<<<N_NODES, HDIM, 0, stream>>>(h, new_, neb, t_emb, h_feat, hbf_hi, hbf_lo);
    xinit_kernel<<<(N_NODES * 3 + 255) / 256, 256, 0, stream>>>(x, x_cur);

    hipMemsetAsync(deg, 0, (size_t)N_NODES * 4, stream);
    deg_kernel<<<(N_EDGES + 255) / 256, 256, 0, stream>>>(ei, deg);
    scan_kernel<<<1, 256, 0, stream>>>(deg, row_start, cursor);
    scatter_kernel<<<(N_EDGES + 255) / 256, 256, 0, stream>>>(ei, cursor, csr_eid);

    for (int l = 0; l < NLAYERS; ++l) {
        hipMemsetAsync(agg_h, 0, (size_t)N_NODES * HDIM * 4, stream);
        hipMemsetAsync(agg_x, 0, (size_t)N_NODES * 3 * 4, stream);
        edge_mfma_kernel<<<N_EDGES / 64, 256, 0, stream>>>(
            ei, ea, x_cur, hbf_hi, hbf_lo, wf_hi, wf_lo, g_hi, g_lo, bias1c,
            ew1, eb2, cb1, cw2, csr_eid, l, agg_h, agg_x);
        node_kernel<<<N_NODES, HDIM, 0, stream>>>(
            h_feat, x_cur, hbf_hi, hbf_lo, agg_h, agg_x, mask, nw1, nb1, nw2, nb2, l);
    }

    out_kernel<<<(N_NODES * 3 + 255) / 256, 256, 0, stream>>>(x_cur, x, mask, (float*)d_out);
}

// Round 8
// 1392.697 us; speedup vs baseline: 4.1707x; 1.2836x over previous
//
#include <hip/hip_runtime.h>
#include <hip/hip_bf16.h>

#define N_NODES 10000
#define N_EDGES 320000
#define HDIM 128
#define NODE_IN 64
#define EDGE_IN 16
#define NLAYERS 4
#define EPSV 1e-8f
#define SACT 136       // LDS activation row stride (fp16 elems)
#define INV4096 2.44140625e-4f

typedef unsigned short ushort_t;
typedef __attribute__((ext_vector_type(8))) short s8;        // 8 fp16 bit-pattern (4 VGPRs)
typedef __attribute__((ext_vector_type(8))) _Float16 h8;
typedef __attribute__((ext_vector_type(4))) float f4;

__device__ __forceinline__ float silu_f(float z) { return z / (1.0f + __expf(-z)); }

__device__ __forceinline__ f4 mfma16(s8 a, s8 b, f4 c) {
    return __builtin_amdgcn_mfma_f32_16x16x32_f16(
        __builtin_bit_cast(h8, a), __builtin_bit_cast(h8, b), c, 0, 0, 0);
}

// fp32 -> fp16 hi + (residual*4096) lo   (rep error ~2^-23 relative)
__device__ __forceinline__ void split_f16(float x, ushort_t& hi, ushort_t& lo) {
    _Float16 h = (_Float16)x;
    float hf = (float)h;
    _Float16 l = (_Float16)((x - hf) * 4096.0f);
    hi = __builtin_bit_cast(ushort_t, h);
    lo = __builtin_bit_cast(ushort_t, l);
}

// ============ CSR build ============
__global__ void deg_kernel(const int* __restrict__ ei, int* __restrict__ deg) {
    int e = blockIdx.x * 256 + threadIdx.x;
    if (e < N_EDGES) atomicAdd(&deg[ei[e]], 1);
}

__global__ void scan_kernel(const int* __restrict__ deg, int* __restrict__ row_start,
                            int* __restrict__ cursor) {
    __shared__ int s_part[256];
    const int CH = 40;   // 256*40 = 10240 >= N_NODES
    int t = threadIdx.x;
    int base = t * CH;
    int sum = 0;
    for (int i = 0; i < CH; ++i) { int n = base + i; if (n < N_NODES) sum += deg[n]; }
    s_part[t] = sum;
    __syncthreads();
    for (int d = 1; d < 256; d <<= 1) {
        int v = (t >= d) ? s_part[t - d] : 0;
        __syncthreads();
        s_part[t] += v;
        __syncthreads();
    }
    int off = s_part[t] - sum;
    for (int i = 0; i < CH; ++i) {
        int n = base + i;
        if (n < N_NODES) { row_start[n] = off; cursor[n] = off; off += deg[n]; }
    }
    if (t == 255) row_start[N_NODES] = s_part[255];
}

__global__ void scatter_kernel(const int* __restrict__ ei, int* __restrict__ cursor,
                               int* __restrict__ csr_eid) {
    int e = blockIdx.x * 256 + threadIdx.x;
    if (e < N_EDGES) {
        int r = ei[e];
        int pos = atomicAdd(&cursor[r], 1);
        csr_eid[pos] = e;
    }
}

// ============ prep 1: repack W1a,W1b,W2,C1 into MFMA B-frag order, split fp16 hi/lo ============
__global__ void repack_weights(const float* __restrict__ ew1, const float* __restrict__ ew2,
                               const float* __restrict__ cw1,
                               ushort_t* __restrict__ wf_hi, ushort_t* __restrict__ wf_lo) {
    int gid = blockIdx.x * 256 + threadIdx.x;
    const int total = NLAYERS * 4 * 16384;
    if (gid >= total) return;
    int l   = gid / (4 * 16384);
    int rem = gid % (4 * 16384);
    int m4  = rem / 16384;
    int idx = rem & 16383;
    int b    = idx >> 9;
    int lane = (idx >> 3) & 63;
    int j    = idx & 7;
    int nt = b >> 2, kt = b & 3;
    int k = kt * 32 + ((lane >> 4) << 3) + j;
    int n = (nt << 4) + (lane & 15);
    float v;
    if (m4 == 0)      v = ew1[(size_t)l * 385 * 128 + (size_t)k * 128 + n];
    else if (m4 == 1) v = ew1[(size_t)l * 385 * 128 + (size_t)(128 + k) * 128 + n];
    else if (m4 == 2) v = ew2[(size_t)l * 16384 + k * 128 + n];
    else              v = cw1[(size_t)l * 16384 + k * 128 + n];
    split_f16(v, wf_hi[gid], wf_lo[gid]);
}

// ============ prep 2: G = eew @ W1c (K padded to 32, frag-packed, split) + bias fold ============
__global__ void prep_g(const float* __restrict__ eew, const float* __restrict__ eeb,
                       const float* __restrict__ ew1, const float* __restrict__ eb1,
                       ushort_t* __restrict__ g_hi, ushort_t* __restrict__ g_lo,
                       float* __restrict__ bias1c) {
    int gid = blockIdx.x * 256 + threadIdx.x;
    const int T1 = NLAYERS * 4096;
    if (gid < T1) {
        int l = gid >> 12;
        int idx = gid & 4095;
        int nt = idx >> 9;
        int lane = (idx >> 3) & 63;
        int j = idx & 7;
        int q = lane >> 4;
        int n = (nt << 4) + (lane & 15);
        int k = q * 8 + j;
        float v = 0.f;
        if (k < EDGE_IN) {
            const float* w1c = ew1 + (size_t)l * 385 * 128 + (size_t)257 * 128;
            float acc = 0.f;
            for (int c = 0; c < HDIM; ++c) acc += eew[k * 128 + c] * w1c[(size_t)c * 128 + n];
            v = acc;
        }
        split_f16(v, g_hi[gid], g_lo[gid]);
    } else if (gid < T1 + NLAYERS * 128) {
        int r = gid - T1;
        int l = r >> 7;
        int n = r & 127;
        const float* w1c = ew1 + (size_t)l * 385 * 128 + (size_t)257 * 128;
        float acc = eb1[l * 128 + n];
        for (int c = 0; c < HDIM; ++c) acc += eeb[c] * w1c[(size_t)c * 128 + n];
        bias1c[r] = acc;
    }
}

// ============ t_emb ============
__global__ void temb_kernel(const float* t, const float* tw1, const float* tb1,
                            const float* tw2, const float* tb2, float* t_emb) {
    __shared__ float s_a[HDIM];
    int j = threadIdx.x;
    s_a[j] = silu_f(t[0] * tw1[j] + tb1[j]);
    __syncthreads();
    float acc = tb2[j];
    for (int k = 0; k < HDIM; ++k) acc += s_a[k] * tw2[k * HDIM + j];
    t_emb[j] = acc;
}

// ============ h_feat init (fp32 + split fp16 mirror) ============
__global__ void hfeat_kernel(const float* __restrict__ h, const float* __restrict__ new_,
                             const float* __restrict__ neb, const float* __restrict__ t_emb,
                             float* __restrict__ h_feat,
                             ushort_t* __restrict__ hbf_hi, ushort_t* __restrict__ hbf_lo) {
    __shared__ float s_h[NODE_IN];
    int n = blockIdx.x, j = threadIdx.x;
    if (j < NODE_IN) s_h[j] = h[(size_t)n * NODE_IN + j];
    __syncthreads();
    float acc = neb[j] + t_emb[j];
#pragma unroll 8
    for (int i = 0; i < NODE_IN; ++i) acc += s_h[i] * new_[i * HDIM + j];
    h_feat[(size_t)n * HDIM + j] = acc;
    split_f16(acc, hbf_hi[(size_t)n * HDIM + j], hbf_lo[(size_t)n * HDIM + j]);
}

__global__ void xinit_kernel(const float* x, float* x_cur) {
    int idx = blockIdx.x * blockDim.x + threadIdx.x;
    if (idx < N_NODES * 3) x_cur[idx] = x[idx];
}

// ============ MFMA edge kernel: 1 wave = 32 CSR slots (2 M-tiles), 2 waves/block ============
__global__ __launch_bounds__(128, 2) void edge_mfma_kernel(
    const int* __restrict__ ei, const float* __restrict__ ea,
    const float* __restrict__ x_cur,
    const ushort_t* __restrict__ hbf_hi, const ushort_t* __restrict__ hbf_lo,
    const ushort_t* __restrict__ wf_hi, const ushort_t* __restrict__ wf_lo,
    const ushort_t* __restrict__ g_hi, const ushort_t* __restrict__ g_lo,
    const float* __restrict__ bias1c,
    const float* __restrict__ ew1,   // d2 row (row 256), fp32
    const float* __restrict__ eb2, const float* __restrict__ cb1, const float* __restrict__ cw2,
    const int* __restrict__ csr_eid,
    int layer, float* __restrict__ agg_h, float* __restrict__ agg_x)
{
    __shared__ __align__(16) ushort_t s_acth[2][32 * SACT];
    __shared__ __align__(16) ushort_t s_actl[2][32 * SACT];
    __shared__ float s_d2[2][32], s_dist[2][32], s_diff[2][32][3];
    __shared__ int s_row[2][32];
    __shared__ int s_drows[2][32];
    __shared__ int s_dcnt[2];

    const int tid = threadIdx.x;
    const int w = tid >> 6, lane = tid & 63;
    const int lo = lane & 15, q = lane >> 4;
    const int e0 = blockIdx.x * 64 + w * 32;

    const ushort_t* wAh  = wf_hi + (size_t)layer * 4 * 16384;
    const ushort_t* wAl  = wf_lo + (size_t)layer * 4 * 16384;
    const ushort_t* wBh  = wAh + 16384;
    const ushort_t* wBl  = wAl + 16384;
    const ushort_t* wW2h = wAh + 32768;
    const ushort_t* wW2l = wAl + 32768;
    const ushort_t* wC1h = wAh + 49152;
    const ushort_t* wC1l = wAl + 49152;
    const ushort_t* wgh  = g_hi + (size_t)layer * 4096;
    const ushort_t* wgl  = g_lo + (size_t)layer * 4096;
    const float* wd2 = ew1 + (size_t)layer * 385 * 128 + (size_t)256 * 128;
    const float* b1v = bias1c + layer * 128;
    const float* b2v = eb2 + layer * 128;
    const float* cbv = cb1 + layer * 128;
    const float* c2v = cw2 + layer * 128;

    // ---- phase 0: geometry for 32 slots ----
    if (lane < 32) {
        int slot = e0 + lane;
        int e = csr_eid[slot];
        int r = ei[e], c = ei[N_EDGES + e];
        s_row[w][lane] = r;
        float dx = x_cur[r * 3 + 0] - x_cur[c * 3 + 0];
        float dy = x_cur[r * 3 + 1] - x_cur[c * 3 + 1];
        float dz = x_cur[r * 3 + 2] - x_cur[c * 3 + 2];
        float d2 = dx * dx + dy * dy + dz * dz;
        s_d2[w][lane] = d2;
        s_dist[w][lane] = sqrtf(d2 + EPSV);
        s_diff[w][lane][0] = dx; s_diff[w][lane][1] = dy; s_diff[w][lane][2] = dz;
    }
    int eidT[2], erT[2], ecT[2];
#pragma unroll
    for (int t = 0; t < 2; ++t) {
        eidT[t] = csr_eid[e0 + t * 16 + lo];
        erT[t] = ei[eidT[t]];
        ecT[t] = ei[N_EDGES + eidT[t]];
    }
    __syncthreads();   // B1

    // wave-local distinct-row list (CSR slots row-sorted -> ~2 distinct rows / 32 slots)
    if (lane == 0) {
        int cnt = 0, prev = -1;
        for (int i = 0; i < 32; ++i) {
            int r = s_row[w][i];
            if (r != prev) { s_drows[w][cnt++] = r; prev = r; }
        }
        s_dcnt[w] = cnt;
    }

    // ---- A fragments for both tiles ----
    s8 aRh[2][4], aRl[2][4], aCh[2][4], aCl[2][4];
#pragma unroll
    for (int t = 0; t < 2; ++t)
#pragma unroll
        for (int kt = 0; kt < 4; ++kt) {
            size_t ro = (size_t)erT[t] * 128 + kt * 32 + q * 8;
            size_t co = (size_t)ecT[t] * 128 + kt * 32 + q * 8;
            aRh[t][kt] = *(const s8*)(hbf_hi + ro);
            aRl[t][kt] = *(const s8*)(hbf_lo + ro);
            aCh[t][kt] = *(const s8*)(hbf_hi + co);
            aCl[t][kt] = *(const s8*)(hbf_lo + co);
        }
    s8 aEAh[2], aEAl[2];
#pragma unroll
    for (int t = 0; t < 2; ++t) {
        aEAh[t] = (s8){0,0,0,0,0,0,0,0};
        aEAl[t] = (s8){0,0,0,0,0,0,0,0};
        if (q < 2) {
            const float* eap = ea + (size_t)eidT[t] * 16 + q * 8;
#pragma unroll
            for (int i = 0; i < 8; ++i) {
                ushort_t hh, ll;
                split_f16(eap[i], hh, ll);
                aEAh[t][i] = (short)hh; aEAl[t][i] = (short)ll;
            }
        }
    }

    // ---- GEMM1: y1 = silu(hR@W1a + hC@W1b + ea@G + d2*wd2 + b1') ----
    float d2r[2][4];
#pragma unroll
    for (int t = 0; t < 2; ++t)
#pragma unroll
        for (int r = 0; r < 4; ++r) d2r[t][r] = s_d2[w][t * 16 + q * 4 + r];

#pragma unroll
    for (int nt = 0; nt < 8; ++nt) {
        f4 aH[2], aL[2];
#pragma unroll
        for (int t = 0; t < 2; ++t) { aH[t] = (f4){0.f,0.f,0.f,0.f}; aL[t] = (f4){0.f,0.f,0.f,0.f}; }
        {
            s8 bGh = *(const s8*)(wgh + ((size_t)nt * 64 + lane) * 8);
            s8 bGl = *(const s8*)(wgl + ((size_t)nt * 64 + lane) * 8);
#pragma unroll
            for (int t = 0; t < 2; ++t) {
                aH[t] = mfma16(aEAh[t], bGh, aH[t]);
                aL[t] = mfma16(aEAh[t], bGl, aL[t]);
                aL[t] = mfma16(aEAl[t], bGh, aL[t]);
            }
        }
#pragma unroll
        for (int kt = 0; kt < 4; ++kt) {
            size_t base = ((size_t)(nt * 4 + kt) * 64 + lane) * 8;
            s8 bh = *(const s8*)(wAh + base);
            s8 bl = *(const s8*)(wAl + base);
            s8 ch = *(const s8*)(wBh + base);
            s8 cl = *(const s8*)(wBl + base);
#pragma unroll
            for (int t = 0; t < 2; ++t) {
                aH[t] = mfma16(aRh[t][kt], bh, aH[t]);
                aL[t] = mfma16(aRh[t][kt], bl, aL[t]);
                aL[t] = mfma16(aRl[t][kt], bh, aL[t]);
                aH[t] = mfma16(aCh[t][kt], ch, aH[t]);
                aL[t] = mfma16(aCh[t][kt], cl, aL[t]);
                aL[t] = mfma16(aCl[t][kt], ch, aL[t]);
            }
        }
        float bb = b1v[nt * 16 + lo];
        float wv = wd2[nt * 16 + lo];
#pragma unroll
        for (int t = 0; t < 2; ++t)
#pragma unroll
            for (int r = 0; r < 4; ++r) {
                float v = silu_f(aH[t][r] + aL[t][r] * INV4096 + bb + d2r[t][r] * wv);
                int off = (t * 16 + q * 4 + r) * SACT + nt * 16 + lo;
                split_f16(v, s_acth[w][off], s_actl[w][off]);
            }
    }
    __syncthreads();   // B2

    // ---- GEMM2: m = silu(y1 @ W2 + b2) ----
    s8 aYh[2][4], aYl[2][4];
#pragma unroll
    for (int t = 0; t < 2; ++t)
#pragma unroll
        for (int kt = 0; kt < 4; ++kt) {
            int off = (t * 16 + lo) * SACT + kt * 32 + q * 8;
            aYh[t][kt] = *(const s8*)&s_acth[w][off];
            aYl[t][kt] = *(const s8*)&s_actl[w][off];
        }
    __syncthreads();   // B3

    int rowm[2][4];
#pragma unroll
    for (int t = 0; t < 2; ++t)
#pragma unroll
        for (int r = 0; r < 4; ++r) rowm[t][r] = s_row[w][t * 16 + q * 4 + r];

    f4 mv[2][8];
#pragma unroll
    for (int nt = 0; nt < 8; ++nt) {
        f4 aH[2], aL[2];
#pragma unroll
        for (int t = 0; t < 2; ++t) { aH[t] = (f4){0.f,0.f,0.f,0.f}; aL[t] = (f4){0.f,0.f,0.f,0.f}; }
#pragma unroll
        for (int kt = 0; kt < 4; ++kt) {
            size_t base = ((size_t)(nt * 4 + kt) * 64 + lane) * 8;
            s8 bh = *(const s8*)(wW2h + base);
            s8 bl = *(const s8*)(wW2l + base);
#pragma unroll
            for (int t = 0; t < 2; ++t) {
                aH[t] = mfma16(aYh[t][kt], bh, aH[t]);
                aL[t] = mfma16(aYh[t][kt], bl, aL[t]);
                aL[t] = mfma16(aYl[t][kt], bh, aL[t]);
            }
        }
        float bb = b2v[nt * 16 + lo];
#pragma unroll
        for (int t = 0; t < 2; ++t) {
#pragma unroll
            for (int r = 0; r < 4; ++r) aH[t][r] = silu_f(aH[t][r] + aL[t][r] * INV4096 + bb);
            mv[t][nt] = aH[t];
        }
    }
    // store m (split) for GEMM3
#pragma unroll
    for (int nt = 0; nt < 8; ++nt)
#pragma unroll
        for (int t = 0; t < 2; ++t)
#pragma unroll
            for (int r = 0; r < 4; ++r) {
                int off = (t * 16 + q * 4 + r) * SACT + nt * 16 + lo;
                split_f16(mv[t][nt][r], s_acth[w][off], s_actl[w][off]);
            }
    // segmented reduce m over the wave's 32 slots -> atomics per distinct row
    {
        int dcnt = s_dcnt[w];
        for (int di = 0; di < dcnt; ++di) {
            int dr = s_drows[w][di];
#pragma unroll
            for (int nt = 0; nt < 8; ++nt) {
                float v = 0.f;
#pragma unroll
                for (int t = 0; t < 2; ++t)
#pragma unroll
                    for (int r = 0; r < 4; ++r) v += (rowm[t][r] == dr) ? mv[t][nt][r] : 0.f;
                v += __shfl_xor(v, 16, 64);
                v += __shfl_xor(v, 32, 64);
                if (lane < 16) atomicAdd(&agg_h[(size_t)dr * HDIM + nt * 16 + lane], v);
            }
        }
    }
    __syncthreads();   // B4

    // ---- GEMM3: c = silu(m @ C1 + cb) ; w = tanh(c . c2) ----
    s8 aMh[2][4], aMl[2][4];
#pragma unroll
    for (int t = 0; t < 2; ++t)
#pragma unroll
        for (int kt = 0; kt < 4; ++kt) {
            int off = (t * 16 + lo) * SACT + kt * 32 + q * 8;
            aMh[t][kt] = *(const s8*)&s_acth[w][off];
            aMl[t][kt] = *(const s8*)&s_actl[w][off];
        }

    float wpart[2][4] = {{0.f,0.f,0.f,0.f},{0.f,0.f,0.f,0.f}};
#pragma unroll
    for (int nt = 0; nt < 8; ++nt) {
        f4 aH[2], aL[2];
#pragma unroll
        for (int t = 0; t < 2; ++t) { aH[t] = (f4){0.f,0.f,0.f,0.f}; aL[t] = (f4){0.f,0.f,0.f,0.f}; }
#pragma unroll
        for (int kt = 0; kt < 4; ++kt) {
            size_t base = ((size_t)(nt * 4 + kt) * 64 + lane) * 8;
            s8 bh = *(const s8*)(wC1h + base);
            s8 bl = *(const s8*)(wC1l + base);
#pragma unroll
            for (int t = 0; t < 2; ++t) {
                aH[t] = mfma16(aMh[t][kt], bh, aH[t]);
                aL[t] = mfma16(aMh[t][kt], bl, aL[t]);
                aL[t] = mfma16(aMl[t][kt], bh, aL[t]);
            }
        }
        float bb = cbv[nt * 16 + lo];
        float cc = c2v[nt * 16 + lo];
#pragma unroll
        for (int t = 0; t < 2; ++t)
#pragma unroll
            for (int r = 0; r < 4; ++r)
                wpart[t][r] += silu_f(aH[t][r] + aL[t][r] * INV4096 + bb) * cc;
    }
#pragma unroll
    for (int t = 0; t < 2; ++t)
#pragma unroll
        for (int r = 0; r < 4; ++r) {
#pragma unroll
            for (int mask = 1; mask < 16; mask <<= 1)
                wpart[t][r] += __shfl_xor(wpart[t][r], mask, 16);
        }
    // trans vector + segmented reduce -> agg_x atomics per distinct row
    {
        float val[2][4];
#pragma unroll
        for (int t = 0; t < 2; ++t)
#pragma unroll
            for (int r = 0; r < 4; ++r) {
                int mm = t * 16 + q * 4 + r;
                val[t][r] = (lo < 3)
                    ? s_diff[w][mm][lo] / (s_dist[w][mm] + EPSV) * tanhf(wpart[t][r])
                    : 0.f;
            }
        int dcnt = s_dcnt[w];
        for (int di = 0; di < dcnt; ++di) {
            int dr = s_drows[w][di];
            float v = 0.f;
#pragma unroll
            for (int t = 0; t < 2; ++t)
#pragma unroll
                for (int r = 0; r < 4; ++r) v += (rowm[t][r] == dr) ? val[t][r] : 0.f;
            v += __shfl_xor(v, 16, 64);
            v += __shfl_xor(v, 32, 64);
            if (lane < 3) atomicAdd(&agg_x[dr * 3 + lane], v);
        }
    }
}

// ============ node kernel: 8 nodes/block, weights amortized ============
__global__ __launch_bounds__(128) void node_kernel(
    float* __restrict__ h_feat, float* __restrict__ x_cur,
    ushort_t* __restrict__ hbf_hi, ushort_t* __restrict__ hbf_lo,
    const float* __restrict__ agg_h, const float* __restrict__ agg_x,
    const float* __restrict__ mask,
    const float* __restrict__ n1p, const float* __restrict__ nb1p,
    const float* __restrict__ n2p, const float* __restrict__ nb2p, int layer) {
    __shared__ float s_cat[8][2 * HDIM];
    __shared__ float s_u[8][HDIM];
    int nb = blockIdx.x * 8, j = threadIdx.x;
    const size_t w1o = (size_t)layer * 2 * HDIM * HDIM;
    const size_t w2o = (size_t)layer * HDIM * HDIM;
    const size_t bo  = (size_t)layer * HDIM;

#pragma unroll
    for (int e = 0; e < 8; ++e) {
        s_cat[e][j] = h_feat[(size_t)(nb + e) * HDIM + j];
        s_cat[e][HDIM + j] = agg_h[(size_t)(nb + e) * HDIM + j];
    }
    __syncthreads();

    float u[8];
    float b1 = nb1p[bo + j];
#pragma unroll
    for (int e = 0; e < 8; ++e) u[e] = b1;
    for (int i0 = 0; i0 < 2 * HDIM; i0 += 2) {
        float w0 = n1p[w1o + (size_t)i0 * HDIM + j];
        float w1 = n1p[w1o + (size_t)(i0 + 1) * HDIM + j];
#pragma unroll
        for (int e = 0; e < 8; ++e)
            u[e] += s_cat[e][i0] * w0 + s_cat[e][i0 + 1] * w1;
    }
#pragma unroll
    for (int e = 0; e < 8; ++e) s_u[e][j] = silu_f(u[e]);
    __syncthreads();

    float acc[8];
    float b2 = nb2p[bo + j];
#pragma unroll
    for (int e = 0; e < 8; ++e) acc[e] = b2;
    for (int i0 = 0; i0 < HDIM; i0 += 2) {
        float w0 = n2p[w2o + (size_t)i0 * HDIM + j];
        float w1 = n2p[w2o + (size_t)(i0 + 1) * HDIM + j];
#pragma unroll
        for (int e = 0; e < 8; ++e)
            acc[e] += s_u[e][i0] * w0 + s_u[e][i0 + 1] * w1;
    }
#pragma unroll
    for (int e = 0; e < 8; ++e) {
        float nh = s_cat[e][j] + acc[e];
        h_feat[(size_t)(nb + e) * HDIM + j] = nh;
        split_f16(nh, hbf_hi[(size_t)(nb + e) * HDIM + j], hbf_lo[(size_t)(nb + e) * HDIM + j]);
    }
    if (j < 24) {
        int e = j / 3, c = j - e * 3;
        x_cur[(nb + e) * 3 + c] += agg_x[(nb + e) * 3 + c] * mask[nb + e];
    }
}

__global__ void out_kernel(const float* __restrict__ x_cur, const float* __restrict__ x_in,
                           const float* __restrict__ mask, float* __restrict__ out) {
    int idx = blockIdx.x * blockDim.x + threadIdx.x;
    if (idx < N_NODES * 3) {
        int n = idx / 3;
        out[idx] = (x_cur[idx] - x_in[idx]) * mask[n];
    }
}

extern "C" void kernel_launch(void* const* d_in, const int* in_sizes, int n_in,
                              void* d_out, int out_size, void* d_ws, size_t ws_size,
                              hipStream_t stream) {
    const float* h    = (const float*)d_in[0];
    const float* x    = (const float*)d_in[1];
    const int*   ei   = (const int*)d_in[2];
    const float* ea   = (const float*)d_in[3];
    const float* t    = (const float*)d_in[4];
    const float* mask = (const float*)d_in[5];
    const float* tw1  = (const float*)d_in[6];
    const float* tb1  = (const float*)d_in[7];
    const float* tw2  = (const float*)d_in[8];
    const float* tb2  = (const float*)d_in[9];
    const float* new_ = (const float*)d_in[10];
    const float* neb  = (const float*)d_in[11];
    const float* eew  = (const float*)d_in[12];
    const float* eeb  = (const float*)d_in[13];
    const float* ew1  = (const float*)d_in[14];
    const float* eb1  = (const float*)d_in[15];
    const float* ew2  = (const float*)d_in[16];
    const float* eb2  = (const float*)d_in[17];
    const float* cw1  = (const float*)d_in[18];
    const float* cb1  = (const float*)d_in[19];
    const float* cw2  = (const float*)d_in[20];
    const float* nw1  = (const float*)d_in[21];
    const float* nb1  = (const float*)d_in[22];
    const float* nw2  = (const float*)d_in[23];
    const float* nb2  = (const float*)d_in[24];

    // ---- workspace carve-out (256 B aligned) ----
    char* p = (char*)d_ws;
    auto alloc = [&](size_t bytes) -> char* {
        char* r = p;
        p += (bytes + 255) & ~(size_t)255;
        return r;
    };
    float* t_emb    = (float*)alloc(HDIM * 4);
    float* h_feat   = (float*)alloc((size_t)N_NODES * HDIM * 4);
    float* x_cur    = (float*)alloc((size_t)N_NODES * 3 * 4);
    float* agg_h    = (float*)alloc((size_t)N_NODES * HDIM * 4);
    float* agg_x    = (float*)alloc((size_t)N_NODES * 3 * 4);
    float* bias1c   = (float*)alloc(NLAYERS * HDIM * 4);
    ushort_t* hbf_hi = (ushort_t*)alloc((size_t)N_NODES * HDIM * 2);
    ushort_t* hbf_lo = (ushort_t*)alloc((size_t)N_NODES * HDIM * 2);
    ushort_t* wf_hi  = (ushort_t*)alloc((size_t)NLAYERS * 4 * 16384 * 2);
    ushort_t* wf_lo  = (ushort_t*)alloc((size_t)NLAYERS * 4 * 16384 * 2);
    ushort_t* g_hi   = (ushort_t*)alloc((size_t)NLAYERS * 4096 * 2);
    ushort_t* g_lo   = (ushort_t*)alloc((size_t)NLAYERS * 4096 * 2);
    int* deg        = (int*)alloc((size_t)N_NODES * 4);
    int* row_start  = (int*)alloc((size_t)(N_NODES + 1) * 4);
    int* cursor     = (int*)alloc((size_t)N_NODES * 4);
    int* csr_eid    = (int*)alloc((size_t)N_EDGES * 4);

    repack_weights<<<(NLAYERS * 4 * 16384 + 255) / 256, 256, 0, stream>>>(ew1, ew2, cw1, wf_hi, wf_lo);
    prep_g<<<(NLAYERS * 4096 + NLAYERS * 128 + 255) / 256, 256, 0, stream>>>(eew, eeb, ew1, eb1, g_hi, g_lo, bias1c);
    temb_kernel<<<1, HDIM, 0, stream>>>(t, tw1, tb1, tw2, tb2, t_emb);
    hfeat_kernel<<<N_NODES, HDIM, 0, stream>>>(h, new_, neb, t_emb, h_feat, hbf_hi, hbf_lo);
    xinit_kernel<<<(N_NODES * 3 + 255) / 256, 256, 0, stream>>>(x, x_cur);

    hipMemsetAsync(deg, 0, (size_t)N_NODES * 4, stream);
    deg_kernel<<<(N_EDGES + 255) / 256, 256, 0, stream>>>(ei, deg);
    scan_kernel<<<1, 256, 0, stream>>>(deg, row_start, cursor);
    scatter_kernel<<<(N_EDGES + 255) / 256, 256, 0, stream>>>(ei, cursor, csr_eid);

    for (int l = 0; l < NLAYERS; ++l) {
        hipMemsetAsync(agg_h, 0, (size_t)N_NODES * HDIM * 4, stream);
        hipMemsetAsync(agg_x, 0, (size_t)N_NODES * 3 * 4, stream);
        edge_mfma_kernel<<<N_EDGES / 64, 128, 0, stream>>>(
            ei, ea, x_cur, hbf_hi, hbf_lo, wf_hi, wf_lo, g_hi, g_lo, bias1c,
            ew1, eb2, cb1, cw2, csr_eid, l, agg_h, agg_x);
        node_kernel<<<N_NODES / 8, 128, 0, stream>>>(
            h_feat, x_cur, hbf_hi, hbf_lo, agg_h, agg_x, mask, nw1, nb1, nw2, nb2, l);
    }

    out_kernel<<<(N_NODES * 3 + 255) / 256, 256, 0, stream>>>(x_cur, x, mask, (float*)d_out);
}

// Round 9
// 1345.273 us; speedup vs baseline: 4.3177x; 1.0353x over previous
//
#include <hip/hip_runtime.h>
#include <hip/hip_bf16.h>

#define N_NODES 10000
#define N_EDGES 320000
#define HDIM 128
#define NODE_IN 64
#define EDGE_IN 16
#define NLAYERS 4
#define EPSV 1e-8f
#define SACT 136       // LDS activation row stride (fp16 elems)
#define INV4096 2.44140625e-4f

typedef unsigned short ushort_t;
typedef __attribute__((ext_vector_type(8))) short s8;        // 8 fp16 bit-pattern (4 VGPRs)
typedef __attribute__((ext_vector_type(8))) _Float16 h8;
typedef __attribute__((ext_vector_type(4))) float f4;

__device__ __forceinline__ float silu_f(float z) { return z / (1.0f + __expf(-z)); }

__device__ __forceinline__ f4 mfma16(s8 a, s8 b, f4 c) {
    return __builtin_amdgcn_mfma_f32_16x16x32_f16(
        __builtin_bit_cast(h8, a), __builtin_bit_cast(h8, b), c, 0, 0, 0);
}

// fp32 -> fp16 hi + (residual*4096) lo   (rep error ~2^-23 relative)
__device__ __forceinline__ void split_f16(float x, ushort_t& hi, ushort_t& lo) {
    _Float16 h = (_Float16)x;
    float hf = (float)h;
    _Float16 l = (_Float16)((x - hf) * 4096.0f);
    hi = __builtin_bit_cast(ushort_t, h);
    lo = __builtin_bit_cast(ushort_t, l);
}

// ============ CSR build ============
__global__ void deg_kernel(const int* __restrict__ ei, int* __restrict__ deg) {
    int e = blockIdx.x * 256 + threadIdx.x;
    if (e < N_EDGES) atomicAdd(&deg[ei[e]], 1);
}

__global__ void scan_kernel(const int* __restrict__ deg, int* __restrict__ row_start,
                            int* __restrict__ cursor) {
    __shared__ int s_part[256];
    const int CH = 40;   // 256*40 = 10240 >= N_NODES
    int t = threadIdx.x;
    int base = t * CH;
    int sum = 0;
    for (int i = 0; i < CH; ++i) { int n = base + i; if (n < N_NODES) sum += deg[n]; }
    s_part[t] = sum;
    __syncthreads();
    for (int d = 1; d < 256; d <<= 1) {
        int v = (t >= d) ? s_part[t - d] : 0;
        __syncthreads();
        s_part[t] += v;
        __syncthreads();
    }
    int off = s_part[t] - sum;
    for (int i = 0; i < CH; ++i) {
        int n = base + i;
        if (n < N_NODES) { row_start[n] = off; cursor[n] = off; off += deg[n]; }
    }
    if (t == 255) row_start[N_NODES] = s_part[255];
}

__global__ void scatter_kernel(const int* __restrict__ ei, int* __restrict__ cursor,
                               int* __restrict__ csr_eid) {
    int e = blockIdx.x * 256 + threadIdx.x;
    if (e < N_EDGES) {
        int r = ei[e];
        int pos = atomicAdd(&cursor[r], 1);
        csr_eid[pos] = e;
    }
}

// ============ prep 1: repack W1a,W1b,W2,C1 into MFMA B-frag order, split fp16 hi/lo ============
__global__ void repack_weights(const float* __restrict__ ew1, const float* __restrict__ ew2,
                               const float* __restrict__ cw1,
                               ushort_t* __restrict__ wf_hi, ushort_t* __restrict__ wf_lo) {
    int gid = blockIdx.x * 256 + threadIdx.x;
    const int total = NLAYERS * 4 * 16384;
    if (gid >= total) return;
    int l   = gid / (4 * 16384);
    int rem = gid % (4 * 16384);
    int m4  = rem / 16384;
    int idx = rem & 16383;
    int b    = idx >> 9;
    int lane = (idx >> 3) & 63;
    int j    = idx & 7;
    int nt = b >> 2, kt = b & 3;
    int k = kt * 32 + ((lane >> 4) << 3) + j;
    int n = (nt << 4) + (lane & 15);
    float v;
    if (m4 == 0)      v = ew1[(size_t)l * 385 * 128 + (size_t)k * 128 + n];
    else if (m4 == 1) v = ew1[(size_t)l * 385 * 128 + (size_t)(128 + k) * 128 + n];
    else if (m4 == 2) v = ew2[(size_t)l * 16384 + k * 128 + n];
    else              v = cw1[(size_t)l * 16384 + k * 128 + n];
    split_f16(v, wf_hi[gid], wf_lo[gid]);
}

// ============ prep 2: G = eew @ W1c (K rows 0-15) + d2 weight row at k=16; frag-packed, split ============
__global__ void prep_g(const float* __restrict__ eew, const float* __restrict__ eeb,
                       const float* __restrict__ ew1, const float* __restrict__ eb1,
                       ushort_t* __restrict__ g_hi, ushort_t* __restrict__ g_lo,
                       float* __restrict__ bias1c) {
    int gid = blockIdx.x * 256 + threadIdx.x;
    const int T1 = NLAYERS * 4096;
    if (gid < T1) {
        int l = gid >> 12;
        int idx = gid & 4095;
        int nt = idx >> 9;
        int lane = (idx >> 3) & 63;
        int j = idx & 7;
        int q = lane >> 4;
        int n = (nt << 4) + (lane & 15);
        int k = q * 8 + j;
        float v = 0.f;
        if (k < EDGE_IN) {
            const float* w1c = ew1 + (size_t)l * 385 * 128 + (size_t)257 * 128;
            float acc = 0.f;
            for (int c = 0; c < HDIM; ++c) acc += eew[k * 128 + c] * w1c[(size_t)c * 128 + n];
            v = acc;
        } else if (k == EDGE_IN) {
            v = ew1[(size_t)l * 385 * 128 + (size_t)256 * 128 + n];   // d2 weight row
        }
        split_f16(v, g_hi[gid], g_lo[gid]);
    } else if (gid < T1 + NLAYERS * 128) {
        int r = gid - T1;
        int l = r >> 7;
        int n = r & 127;
        const float* w1c = ew1 + (size_t)l * 385 * 128 + (size_t)257 * 128;
        float acc = eb1[l * 128 + n];
        for (int c = 0; c < HDIM; ++c) acc += eeb[c] * w1c[(size_t)c * 128 + n];
        bias1c[r] = acc;
    }
}

// ============ t_emb ============
__global__ void temb_kernel(const float* t, const float* tw1, const float* tb1,
                            const float* tw2, const float* tb2, float* t_emb) {
    __shared__ float s_a[HDIM];
    int j = threadIdx.x;
    s_a[j] = silu_f(t[0] * tw1[j] + tb1[j]);
    __syncthreads();
    float acc = tb2[j];
    for (int k = 0; k < HDIM; ++k) acc += s_a[k] * tw2[k * HDIM + j];
    t_emb[j] = acc;
}

// ============ h_feat init (fp32 + split fp16 mirror) ============
__global__ void hfeat_kernel(const float* __restrict__ h, const float* __restrict__ new_,
                             const float* __restrict__ neb, const float* __restrict__ t_emb,
                             float* __restrict__ h_feat,
                             ushort_t* __restrict__ hbf_hi, ushort_t* __restrict__ hbf_lo) {
    __shared__ float s_h[NODE_IN];
    int n = blockIdx.x, j = threadIdx.x;
    if (j < NODE_IN) s_h[j] = h[(size_t)n * NODE_IN + j];
    __syncthreads();
    float acc = neb[j] + t_emb[j];
#pragma unroll 8
    for (int i = 0; i < NODE_IN; ++i) acc += s_h[i] * new_[i * HDIM + j];
    h_feat[(size_t)n * HDIM + j] = acc;
    split_f16(acc, hbf_hi[(size_t)n * HDIM + j], hbf_lo[(size_t)n * HDIM + j]);
}

__global__ void xinit_kernel(const float* x, float* x_cur) {
    int idx = blockIdx.x * blockDim.x + threadIdx.x;
    if (idx < N_NODES * 3) x_cur[idx] = x[idx];
}

// ============ MFMA edge kernel: 1 block = 1 wave = 32 CSR slots (2 M-tiles) ============
__global__ __launch_bounds__(64, 2) void edge_mfma_kernel(
    const int* __restrict__ ei, const float* __restrict__ ea,
    const float* __restrict__ x_cur,
    const ushort_t* __restrict__ hbf_hi, const ushort_t* __restrict__ hbf_lo,
    const ushort_t* __restrict__ wf_hi, const ushort_t* __restrict__ wf_lo,
    const ushort_t* __restrict__ g_hi, const ushort_t* __restrict__ g_lo,
    const float* __restrict__ bias1c,
    const float* __restrict__ eb2, const float* __restrict__ cb1, const float* __restrict__ cw2,
    const int* __restrict__ csr_eid,
    int layer, float* __restrict__ agg_h, float* __restrict__ agg_x)
{
    __shared__ __align__(16) ushort_t s_acth[32 * SACT];
    __shared__ __align__(16) ushort_t s_actl[32 * SACT];
    __shared__ float s_d2[32], s_dist[32], s_diff[32][3];
    __shared__ int s_row[32];
    __shared__ int s_drows[32];
    __shared__ int s_dcnt[1];

    const int lane = threadIdx.x;
    const int lo = lane & 15, q = lane >> 4;
    const int e0 = blockIdx.x * 32;

    const ushort_t* wAh  = wf_hi + (size_t)layer * 4 * 16384;
    const ushort_t* wAl  = wf_lo + (size_t)layer * 4 * 16384;
    const ushort_t* wBh  = wAh + 16384;
    const ushort_t* wBl  = wAl + 16384;
    const ushort_t* wW2h = wAh + 32768;
    const ushort_t* wW2l = wAl + 32768;
    const ushort_t* wC1h = wAh + 49152;
    const ushort_t* wgh  = g_hi + (size_t)layer * 4096;
    const ushort_t* wgl  = g_lo + (size_t)layer * 4096;
    const float* b1v = bias1c + layer * 128;
    const float* b2v = eb2 + layer * 128;
    const float* cbv = cb1 + layer * 128;
    const float* c2v = cw2 + layer * 128;

    // ---- phase 0: geometry for 32 slots ----
    if (lane < 32) {
        int slot = e0 + lane;
        int e = csr_eid[slot];
        int r = ei[e], c = ei[N_EDGES + e];
        s_row[lane] = r;
        float dx = x_cur[r * 3 + 0] - x_cur[c * 3 + 0];
        float dy = x_cur[r * 3 + 1] - x_cur[c * 3 + 1];
        float dz = x_cur[r * 3 + 2] - x_cur[c * 3 + 2];
        float d2 = dx * dx + dy * dy + dz * dz;
        s_d2[lane] = d2;
        s_dist[lane] = sqrtf(d2 + EPSV);
        s_diff[lane][0] = dx; s_diff[lane][1] = dy; s_diff[lane][2] = dz;
    }
    int eidT[2], erT[2], ecT[2];
#pragma unroll
    for (int t = 0; t < 2; ++t) {
        eidT[t] = csr_eid[e0 + t * 16 + lo];
        erT[t] = ei[eidT[t]];
        ecT[t] = ei[N_EDGES + eidT[t]];
    }
    __syncthreads();   // B1 (single-wave: ~free)

    // wave-local distinct-row list (CSR slots row-sorted -> ~2 distinct rows / 32 slots)
    if (lane == 0) {
        int cnt = 0, prev = -1;
        for (int i = 0; i < 32; ++i) {
            int r = s_row[i];
            if (r != prev) { s_drows[cnt++] = r; prev = r; }
        }
        s_dcnt[0] = cnt;
    }

    // ---- A fragments for both tiles ----
    s8 aRh[2][4], aRl[2][4], aCh[2][4], aCl[2][4];
#pragma unroll
    for (int t = 0; t < 2; ++t)
#pragma unroll
        for (int kt = 0; kt < 4; ++kt) {
            size_t ro = (size_t)erT[t] * 128 + kt * 32 + q * 8;
            size_t co = (size_t)ecT[t] * 128 + kt * 32 + q * 8;
            aRh[t][kt] = *(const s8*)(hbf_hi + ro);
            aRl[t][kt] = *(const s8*)(hbf_lo + ro);
            aCh[t][kt] = *(const s8*)(hbf_hi + co);
            aCl[t][kt] = *(const s8*)(hbf_lo + co);
        }
    // ea (k=0..15) + d2 (k=16, lanes q==2 slot j=0)
    s8 aEAh[2], aEAl[2];
#pragma unroll
    for (int t = 0; t < 2; ++t) {
        aEAh[t] = (s8){0,0,0,0,0,0,0,0};
        aEAl[t] = (s8){0,0,0,0,0,0,0,0};
        if (q < 2) {
            const float* eap = ea + (size_t)eidT[t] * 16 + q * 8;
#pragma unroll
            for (int i = 0; i < 8; ++i) {
                ushort_t hh, ll;
                split_f16(eap[i], hh, ll);
                aEAh[t][i] = (short)hh; aEAl[t][i] = (short)ll;
            }
        } else if (q == 2) {
            ushort_t hh, ll;
            split_f16(s_d2[t * 16 + lo], hh, ll);
            aEAh[t][0] = (short)hh; aEAl[t][0] = (short)ll;
        }
    }

    // ---- GEMM1: y1 = silu(hR@W1a + hC@W1b + [ea|d2]@G + b1') ----
#pragma unroll
    for (int nt = 0; nt < 8; ++nt) {
        f4 aH[2], aL[2];
#pragma unroll
        for (int t = 0; t < 2; ++t) { aH[t] = (f4){0.f,0.f,0.f,0.f}; aL[t] = (f4){0.f,0.f,0.f,0.f}; }
        {
            s8 bGh = *(const s8*)(wgh + ((size_t)nt * 64 + lane) * 8);
            s8 bGl = *(const s8*)(wgl + ((size_t)nt * 64 + lane) * 8);
#pragma unroll
            for (int t = 0; t < 2; ++t) {
                aH[t] = mfma16(aEAh[t], bGh, aH[t]);
                aL[t] = mfma16(aEAh[t], bGl, aL[t]);
                aL[t] = mfma16(aEAl[t], bGh, aL[t]);
            }
        }
#pragma unroll
        for (int kt = 0; kt < 4; ++kt) {
            size_t base = ((size_t)(nt * 4 + kt) * 64 + lane) * 8;
            s8 bh = *(const s8*)(wAh + base);
            s8 bl = *(const s8*)(wAl + base);
            s8 ch = *(const s8*)(wBh + base);
            s8 cl = *(const s8*)(wBl + base);
#pragma unroll
            for (int t = 0; t < 2; ++t) {
                aH[t] = mfma16(aRh[t][kt], bh, aH[t]);
                aL[t] = mfma16(aRh[t][kt], bl, aL[t]);
                aL[t] = mfma16(aRl[t][kt], bh, aL[t]);
                aH[t] = mfma16(aCh[t][kt], ch, aH[t]);
                aL[t] = mfma16(aCh[t][kt], cl, aL[t]);
                aL[t] = mfma16(aCl[t][kt], ch, aL[t]);
            }
        }
        float bb = b1v[nt * 16 + lo];
#pragma unroll
        for (int t = 0; t < 2; ++t)
#pragma unroll
            for (int r = 0; r < 4; ++r) {
                float v = silu_f(aH[t][r] + aL[t][r] * INV4096 + bb);
                int off = (t * 16 + q * 4 + r) * SACT + nt * 16 + lo;
                split_f16(v, s_acth[off], s_actl[off]);
            }
    }
    __syncthreads();   // B2

    // ---- GEMM2: m = silu(y1 @ W2 + b2) ----
    s8 aYh[2][4], aYl[2][4];
#pragma unroll
    for (int t = 0; t < 2; ++t)
#pragma unroll
        for (int kt = 0; kt < 4; ++kt) {
            int off = (t * 16 + lo) * SACT + kt * 32 + q * 8;
            aYh[t][kt] = *(const s8*)&s_acth[off];
            aYl[t][kt] = *(const s8*)&s_actl[off];
        }
    __syncthreads();   // B3

    int rowm[2][4];
#pragma unroll
    for (int t = 0; t < 2; ++t)
#pragma unroll
        for (int r = 0; r < 4; ++r) rowm[t][r] = s_row[t * 16 + q * 4 + r];

    f4 mv[2][8];
#pragma unroll
    for (int nt = 0; nt < 8; ++nt) {
        f4 aH[2], aL[2];
#pragma unroll
        for (int t = 0; t < 2; ++t) { aH[t] = (f4){0.f,0.f,0.f,0.f}; aL[t] = (f4){0.f,0.f,0.f,0.f}; }
#pragma unroll
        for (int kt = 0; kt < 4; ++kt) {
            size_t base = ((size_t)(nt * 4 + kt) * 64 + lane) * 8;
            s8 bh = *(const s8*)(wW2h + base);
            s8 bl = *(const s8*)(wW2l + base);
#pragma unroll
            for (int t = 0; t < 2; ++t) {
                aH[t] = mfma16(aYh[t][kt], bh, aH[t]);
                aL[t] = mfma16(aYh[t][kt], bl, aL[t]);
                aL[t] = mfma16(aYl[t][kt], bh, aL[t]);
            }
        }
        float bb = b2v[nt * 16 + lo];
#pragma unroll
        for (int t = 0; t < 2; ++t) {
#pragma unroll
            for (int r = 0; r < 4; ++r) aH[t][r] = silu_f(aH[t][r] + aL[t][r] * INV4096 + bb);
            mv[t][nt] = aH[t];
        }
    }
    // store m (hi only -- GEMM3 runs hi-only) for GEMM3 A-frags
#pragma unroll
    for (int nt = 0; nt < 8; ++nt)
#pragma unroll
        for (int t = 0; t < 2; ++t)
#pragma unroll
            for (int r = 0; r < 4; ++r) {
                int off = (t * 16 + q * 4 + r) * SACT + nt * 16 + lo;
                _Float16 hh = (_Float16)mv[t][nt][r];
                s_acth[off] = __builtin_bit_cast(ushort_t, hh);
            }
    // segmented reduce m over the wave's 32 slots -> atomics per distinct row
    {
        int dcnt = s_dcnt[0];
        for (int di = 0; di < dcnt; ++di) {
            int dr = s_drows[di];
#pragma unroll
            for (int nt = 0; nt < 8; ++nt) {
                float v = 0.f;
#pragma unroll
                for (int t = 0; t < 2; ++t)
#pragma unroll
                    for (int r = 0; r < 4; ++r) v += (rowm[t][r] == dr) ? mv[t][nt][r] : 0.f;
                v += __shfl_xor(v, 16, 64);
                v += __shfl_xor(v, 32, 64);
                if (lane < 16) atomicAdd(&agg_h[(size_t)dr * HDIM + nt * 16 + lane], v);
            }
        }
    }
    __syncthreads();   // B4

    // ---- GEMM3 (hi-only): c = silu(m @ C1 + cb) ; w = tanh(c . c2) ----
    s8 aMh[2][4];
#pragma unroll
    for (int t = 0; t < 2; ++t)
#pragma unroll
        for (int kt = 0; kt < 4; ++kt) {
            int off = (t * 16 + lo) * SACT + kt * 32 + q * 8;
            aMh[t][kt] = *(const s8*)&s_acth[off];
        }

    float wpart[2][4] = {{0.f,0.f,0.f,0.f},{0.f,0.f,0.f,0.f}};
#pragma unroll
    for (int nt = 0; nt < 8; ++nt) {
        f4 aH[2];
#pragma unroll
        for (int t = 0; t < 2; ++t) aH[t] = (f4){0.f,0.f,0.f,0.f};
#pragma unroll
        for (int kt = 0; kt < 4; ++kt) {
            size_t base = ((size_t)(nt * 4 + kt) * 64 + lane) * 8;
            s8 bh = *(const s8*)(wC1h + base);
#pragma unroll
            for (int t = 0; t < 2; ++t)
                aH[t] = mfma16(aMh[t][kt], bh, aH[t]);
        }
        float bb = cbv[nt * 16 + lo];
        float cc = c2v[nt * 16 + lo];
#pragma unroll
        for (int t = 0; t < 2; ++t)
#pragma unroll
            for (int r = 0; r < 4; ++r)
                wpart[t][r] += silu_f(aH[t][r] + bb) * cc;
    }
#pragma unroll
    for (int t = 0; t < 2; ++t)
#pragma unroll
        for (int r = 0; r < 4; ++r) {
#pragma unroll
            for (int mask = 1; mask < 16; mask <<= 1)
                wpart[t][r] += __shfl_xor(wpart[t][r], mask, 16);
        }
    // trans vector + segmented reduce -> agg_x atomics per distinct row
    {
        float val[2][4];
#pragma unroll
        for (int t = 0; t < 2; ++t)
#pragma unroll
            for (int r = 0; r < 4; ++r) {
                int mm = t * 16 + q * 4 + r;
                val[t][r] = (lo < 3)
                    ? s_diff[mm][lo] / (s_dist[mm] + EPSV) * tanhf(wpart[t][r])
                    : 0.f;
            }
        int dcnt = s_dcnt[0];
        for (int di = 0; di < dcnt; ++di) {
            int dr = s_drows[di];
            float v = 0.f;
#pragma unroll
            for (int t = 0; t < 2; ++t)
#pragma unroll
                for (int r = 0; r < 4; ++r) v += (rowm[t][r] == dr) ? val[t][r] : 0.f;
            v += __shfl_xor(v, 16, 64);
            v += __shfl_xor(v, 32, 64);
            if (lane < 3) atomicAdd(&agg_x[dr * 3 + lane], v);
        }
    }
}

// ============ node kernel: 8 nodes/block, weights amortized ============
__global__ __launch_bounds__(128) void node_kernel(
    float* __restrict__ h_feat, float* __restrict__ x_cur,
    ushort_t* __restrict__ hbf_hi, ushort_t* __restrict__ hbf_lo,
    const float* __restrict__ agg_h, const float* __restrict__ agg_x,
    const float* __restrict__ mask,
    const float* __restrict__ n1p, const float* __restrict__ nb1p,
    const float* __restrict__ n2p, const float* __restrict__ nb2p, int layer) {
    __shared__ float s_cat[8][2 * HDIM];
    __shared__ float s_u[8][HDIM];
    int nb = blockIdx.x * 8, j = threadIdx.x;
    const size_t w1o = (size_t)layer * 2 * HDIM * HDIM;
    const size_t w2o = (size_t)layer * HDIM * HDIM;
    const size_t bo  = (size_t)layer * HDIM;

#pragma unroll
    for (int e = 0; e < 8; ++e) {
        s_cat[e][j] = h_feat[(size_t)(nb + e) * HDIM + j];
        s_cat[e][HDIM + j] = agg_h[(size_t)(nb + e) * HDIM + j];
    }
    __syncthreads();

    float u[8];
    float b1 = nb1p[bo + j];
#pragma unroll
    for (int e = 0; e < 8; ++e) u[e] = b1;
    for (int i0 = 0; i0 < 2 * HDIM; i0 += 2) {
        float w0 = n1p[w1o + (size_t)i0 * HDIM + j];
        float w1 = n1p[w1o + (size_t)(i0 + 1) * HDIM + j];
#pragma unroll
        for (int e = 0; e < 8; ++e)
            u[e] += s_cat[e][i0] * w0 + s_cat[e][i0 + 1] * w1;
    }
#pragma unroll
    for (int e = 0; e < 8; ++e) s_u[e][j] = silu_f(u[e]);
    __syncthreads();

    float acc[8];
    float b2 = nb2p[bo + j];
#pragma unroll
    for (int e = 0; e < 8; ++e) acc[e] = b2;
    for (int i0 = 0; i0 < HDIM; i0 += 2) {
        float w0 = n2p[w2o + (size_t)i0 * HDIM + j];
        float w1 = n2p[w2o + (size_t)(i0 + 1) * HDIM + j];
#pragma unroll
        for (int e = 0; e < 8; ++e)
            acc[e] += s_u[e][i0] * w0 + s_u[e][i0 + 1] * w1;
    }
#pragma unroll
    for (int e = 0; e < 8; ++e) {
        float nh = s_cat[e][j] + acc[e];
        h_feat[(size_t)(nb + e) * HDIM + j] = nh;
        split_f16(nh, hbf_hi[(size_t)(nb + e) * HDIM + j], hbf_lo[(size_t)(nb + e) * HDIM + j]);
    }
    if (j < 24) {
        int e = j / 3, c = j - e * 3;
        x_cur[(nb + e) * 3 + c] += agg_x[(nb + e) * 3 + c] * mask[nb + e];
    }
}

__global__ void out_kernel(const float* __restrict__ x_cur, const float* __restrict__ x_in,
                           const float* __restrict__ mask, float* __restrict__ out) {
    int idx = blockIdx.x * blockDim.x + threadIdx.x;
    if (idx < N_NODES * 3) {
        int n = idx / 3;
        out[idx] = (x_cur[idx] - x_in[idx]) * mask[n];
    }
}

extern "C" void kernel_launch(void* const* d_in, const int* in_sizes, int n_in,
                              void* d_out, int out_size, void* d_ws, size_t ws_size,
                              hipStream_t stream) {
    const float* h    = (const float*)d_in[0];
    const float* x    = (const float*)d_in[1];
    const int*   ei   = (const int*)d_in[2];
    const float* ea   = (const float*)d_in[3];
    const float* t    = (const float*)d_in[4];
    const float* mask = (const float*)d_in[5];
    const float* tw1  = (const float*)d_in[6];
    const float* tb1  = (const float*)d_in[7];
    const float* tw2  = (const float*)d_in[8];
    const float* tb2  = (const float*)d_in[9];
    const float* new_ = (const float*)d_in[10];
    const float* neb  = (const float*)d_in[11];
    const float* eew  = (const float*)d_in[12];
    const float* eeb  = (const float*)d_in[13];
    const float* ew1  = (const float*)d_in[14];
    const float* eb1  = (const float*)d_in[15];
    const float* ew2  = (const float*)d_in[16];
    const float* eb2  = (const float*)d_in[17];
    const float* cw1  = (const float*)d_in[18];
    const float* cb1  = (const float*)d_in[19];
    const float* cw2  = (const float*)d_in[20];
    const float* nw1  = (const float*)d_in[21];
    const float* nb1  = (const float*)d_in[22];
    const float* nw2  = (const float*)d_in[23];
    const float* nb2  = (const float*)d_in[24];

    // ---- workspace carve-out (256 B aligned) ----
    char* p = (char*)d_ws;
    auto alloc = [&](size_t bytes) -> char* {
        char* r = p;
        p += (bytes + 255) & ~(size_t)255;
        return r;
    };
    float* t_emb    = (float*)alloc(HDIM * 4);
    float* h_feat   = (float*)alloc((size_t)N_NODES * HDIM * 4);
    float* x_cur    = (float*)alloc((size_t)N_NODES * 3 * 4);
    float* agg_h    = (float*)alloc((size_t)N_NODES * HDIM * 4);
    float* agg_x    = (float*)alloc((size_t)N_NODES * 3 * 4);
    float* bias1c   = (float*)alloc(NLAYERS * HDIM * 4);
    ushort_t* hbf_hi = (ushort_t*)alloc((size_t)N_NODES * HDIM * 2);
    ushort_t* hbf_lo = (ushort_t*)alloc((size_t)N_NODES * HDIM * 2);
    ushort_t* wf_hi  = (ushort_t*)alloc((size_t)NLAYERS * 4 * 16384 * 2);
    ushort_t* wf_lo  = (ushort_t*)alloc((size_t)NLAYERS * 4 * 16384 * 2);
    ushort_t* g_hi   = (ushort_t*)alloc((size_t)NLAYERS * 4096 * 2);
    ushort_t* g_lo   = (ushort_t*)alloc((size_t)NLAYERS * 4096 * 2);
    int* deg        = (int*)alloc((size_t)N_NODES * 4);
    int* row_start  = (int*)alloc((size_t)(N_NODES + 1) * 4);
    int* cursor     = (int*)alloc((size_t)N_NODES * 4);
    int* csr_eid    = (int*)alloc((size_t)N_EDGES * 4);

    repack_weights<<<(NLAYERS * 4 * 16384 + 255) / 256, 256, 0, stream>>>(ew1, ew2, cw1, wf_hi, wf_lo);
    prep_g<<<(NLAYERS * 4096 + NLAYERS * 128 + 255) / 256, 256, 0, stream>>>(eew, eeb, ew1, eb1, g_hi, g_lo, bias1c);
    temb_kernel<<<1, HDIM, 0, stream>>>(t, tw1, tb1, tw2, tb2, t_emb);
    hfeat_kernel<<<N_NODES, HDIM, 0, stream>>>(h, new_, neb, t_emb, h_feat, hbf_hi, hbf_lo);
    xinit_kernel<<<(N_NODES * 3 + 255) / 256, 256, 0, stream>>>(x, x_cur);

    hipMemsetAsync(deg, 0, (size_t)N_NODES * 4, stream);
    deg_kernel<<<(N_EDGES + 255) / 256, 256, 0, stream>>>(ei, deg);
    scan_kernel<<<1, 256, 0, stream>>>(deg, row_start, cursor);
    scatter_kernel<<<(N_EDGES + 255) / 256, 256, 0, stream>>>(ei, cursor, csr_eid);

    for (int l = 0; l < NLAYERS; ++l) {
        hipMemsetAsync(agg_h, 0, (size_t)N_NODES * HDIM * 4, stream);
        hipMemsetAsync(agg_x, 0, (size_t)N_NODES * 3 * 4, stream);
        edge_mfma_kernel<<<N_EDGES / 32, 64, 0, stream>>>(
            ei, ea, x_cur, hbf_hi, hbf_lo, wf_hi, wf_lo, g_hi, g_lo, bias1c,
            eb2, cb1, cw2, csr_eid, l, agg_h, agg_x);
        node_kernel<<<N_NODES / 8, 128, 0, stream>>>(
            h_feat, x_cur, hbf_hi, hbf_lo, agg_h, agg_x, mask, nw1, nb1, nw2, nb2, l);
    }

    out_kernel<<<(N_NODES * 3 + 255) / 256, 256, 0, stream>>>(x_cur, x, mask, (float*)d_out);
}

// Round 10
// 1335.478 us; speedup vs baseline: 4.3494x; 1.0073x over previous
//
#include <hip/hip_runtime.h>
#include <hip/hip_bf16.h>

#define N_NODES 10000
#define N_EDGES 320000
#define HDIM 128
#define NODE_IN 64
#define EDGE_IN 16
#define NLAYERS 4
#define EPSV 1e-8f
#define SACT 136       // LDS activation row stride (elems)
#define INV4096 2.44140625e-4f

typedef unsigned short ushort_t;
typedef unsigned char uchar_t;
typedef __attribute__((ext_vector_type(8))) short s8;        // 8 fp16 bit-pattern (4 VGPRs)
typedef __attribute__((ext_vector_type(8))) _Float16 h8;
typedef __attribute__((ext_vector_type(4))) float f4;

__device__ __forceinline__ float silu_f(float z) { return z / (1.0f + __expf(-z)); }

__device__ __forceinline__ f4 mfma16(s8 a, s8 b, f4 c) {
    return __builtin_amdgcn_mfma_f32_16x16x32_f16(
        __builtin_bit_cast(h8, a), __builtin_bit_cast(h8, b), c, 0, 0, 0);
}

// fp32 -> fp16 hi + (residual*4096) lo   (rep error ~2^-23 relative)
__device__ __forceinline__ void split_f16(float x, ushort_t& hi, ushort_t& lo) {
    _Float16 h = (_Float16)x;
    float hf = (float)h;
    _Float16 l = (_Float16)((x - hf) * 4096.0f);
    hi = __builtin_bit_cast(ushort_t, h);
    lo = __builtin_bit_cast(ushort_t, l);
}

// expand 8 truncated-fp16 bytes (fp8-e5m2 == top byte of fp16) -> 8 fp16
__device__ __forceinline__ s8 expand_fp8lo(uint2 dw) {
    unsigned o0 = ((dw.x << 8) & 0x0000FF00u) | ((dw.x << 16) & 0xFF000000u);
    unsigned o1 = ((dw.x >> 8) & 0x0000FF00u) | (dw.x & 0xFF000000u);
    unsigned o2 = ((dw.y << 8) & 0x0000FF00u) | ((dw.y << 16) & 0xFF000000u);
    unsigned o3 = ((dw.y >> 8) & 0x0000FF00u) | (dw.y & 0xFF000000u);
    uint4 u; u.x = o0; u.y = o1; u.z = o2; u.w = o3;
    return __builtin_bit_cast(s8, u);
}

// ============ CSR build ============
__global__ void deg_kernel(const int* __restrict__ ei, int* __restrict__ deg) {
    int e = blockIdx.x * 256 + threadIdx.x;
    if (e < N_EDGES) atomicAdd(&deg[ei[e]], 1);
}

__global__ void scan_kernel(const int* __restrict__ deg, int* __restrict__ row_start,
                            int* __restrict__ cursor) {
    __shared__ int s_part[256];
    const int CH = 40;   // 256*40 = 10240 >= N_NODES
    int t = threadIdx.x;
    int base = t * CH;
    int sum = 0;
    for (int i = 0; i < CH; ++i) { int n = base + i; if (n < N_NODES) sum += deg[n]; }
    s_part[t] = sum;
    __syncthreads();
    for (int d = 1; d < 256; d <<= 1) {
        int v = (t >= d) ? s_part[t - d] : 0;
        __syncthreads();
        s_part[t] += v;
        __syncthreads();
    }
    int off = s_part[t] - sum;
    for (int i = 0; i < CH; ++i) {
        int n = base + i;
        if (n < N_NODES) { row_start[n] = off; cursor[n] = off; off += deg[n]; }
    }
    if (t == 255) row_start[N_NODES] = s_part[255];
}

__global__ void scatter_kernel(const int* __restrict__ ei, int* __restrict__ cursor,
                               int* __restrict__ csr_eid) {
    int e = blockIdx.x * 256 + threadIdx.x;
    if (e < N_EDGES) {
        int r = ei[e];
        int pos = atomicAdd(&cursor[r], 1);
        csr_eid[pos] = e;
    }
}

// ============ prep 1: repack W1a,W1b,W2,C1 into MFMA B-frag order, split fp16 hi/lo ============
__global__ void repack_weights(const float* __restrict__ ew1, const float* __restrict__ ew2,
                               const float* __restrict__ cw1,
                               ushort_t* __restrict__ wf_hi, ushort_t* __restrict__ wf_lo) {
    int gid = blockIdx.x * 256 + threadIdx.x;
    const int total = NLAYERS * 4 * 16384;
    if (gid >= total) return;
    int l   = gid / (4 * 16384);
    int rem = gid % (4 * 16384);
    int m4  = rem / 16384;
    int idx = rem & 16383;
    int b    = idx >> 9;
    int lane = (idx >> 3) & 63;
    int j    = idx & 7;
    int nt = b >> 2, kt = b & 3;
    int k = kt * 32 + ((lane >> 4) << 3) + j;
    int n = (nt << 4) + (lane & 15);
    float v;
    if (m4 == 0)      v = ew1[(size_t)l * 385 * 128 + (size_t)k * 128 + n];
    else if (m4 == 1) v = ew1[(size_t)l * 385 * 128 + (size_t)(128 + k) * 128 + n];
    else if (m4 == 2) v = ew2[(size_t)l * 16384 + k * 128 + n];
    else              v = cw1[(size_t)l * 16384 + k * 128 + n];
    split_f16(v, wf_hi[gid], wf_lo[gid]);
}

// ============ prep 2: G = eew @ W1c (K rows 0-15) + d2 weight row at k=16; frag-packed, split ============
__global__ void prep_g(const float* __restrict__ eew, const float* __restrict__ eeb,
                       const float* __restrict__ ew1, const float* __restrict__ eb1,
                       ushort_t* __restrict__ g_hi, ushort_t* __restrict__ g_lo,
                       float* __restrict__ bias1c) {
    int gid = blockIdx.x * 256 + threadIdx.x;
    const int T1 = NLAYERS * 4096;
    if (gid < T1) {
        int l = gid >> 12;
        int idx = gid & 4095;
        int nt = idx >> 9;
        int lane = (idx >> 3) & 63;
        int j = idx & 7;
        int q = lane >> 4;
        int n = (nt << 4) + (lane & 15);
        int k = q * 8 + j;
        float v = 0.f;
        if (k < EDGE_IN) {
            const float* w1c = ew1 + (size_t)l * 385 * 128 + (size_t)257 * 128;
            float acc = 0.f;
            for (int c = 0; c < HDIM; ++c) acc += eew[k * 128 + c] * w1c[(size_t)c * 128 + n];
            v = acc;
        } else if (k == EDGE_IN) {
            v = ew1[(size_t)l * 385 * 128 + (size_t)256 * 128 + n];   // d2 weight row
        }
        split_f16(v, g_hi[gid], g_lo[gid]);
    } else if (gid < T1 + NLAYERS * 128) {
        int r = gid - T1;
        int l = r >> 7;
        int n = r & 127;
        const float* w1c = ew1 + (size_t)l * 385 * 128 + (size_t)257 * 128;
        float acc = eb1[l * 128 + n];
        for (int c = 0; c < HDIM; ++c) acc += eeb[c] * w1c[(size_t)c * 128 + n];
        bias1c[r] = acc;
    }
}

// ============ t_emb ============
__global__ void temb_kernel(const float* t, const float* tw1, const float* tb1,
                            const float* tw2, const float* tb2, float* t_emb) {
    __shared__ float s_a[HDIM];
    int j = threadIdx.x;
    s_a[j] = silu_f(t[0] * tw1[j] + tb1[j]);
    __syncthreads();
    float acc = tb2[j];
    for (int k = 0; k < HDIM; ++k) acc += s_a[k] * tw2[k * HDIM + j];
    t_emb[j] = acc;
}

// ============ h_feat init (fp32 + split fp16 mirror) ============
__global__ void hfeat_kernel(const float* __restrict__ h, const float* __restrict__ new_,
                             const float* __restrict__ neb, const float* __restrict__ t_emb,
                             float* __restrict__ h_feat,
                             ushort_t* __restrict__ hbf_hi, ushort_t* __restrict__ hbf_lo) {
    __shared__ float s_h[NODE_IN];
    int n = blockIdx.x, j = threadIdx.x;
    if (j < NODE_IN) s_h[j] = h[(size_t)n * NODE_IN + j];
    __syncthreads();
    float acc = neb[j] + t_emb[j];
#pragma unroll 8
    for (int i = 0; i < NODE_IN; ++i) acc += s_h[i] * new_[i * HDIM + j];
    h_feat[(size_t)n * HDIM + j] = acc;
    split_f16(acc, hbf_hi[(size_t)n * HDIM + j], hbf_lo[(size_t)n * HDIM + j]);
}

__global__ void xinit_kernel(const float* x, float* x_cur) {
    int idx = blockIdx.x * blockDim.x + threadIdx.x;
    if (idx < N_NODES * 3) x_cur[idx] = x[idx];
}

// ============ MFMA edge kernel: 1 block = 1 wave = 32 CSR slots (2 M-tiles) ============
// y1 staging: hi fp16 in LDS + lo as fp8(e5m2 = fp16 top byte) -> ~14 KB LDS -> 11 blocks/CU
__global__ __launch_bounds__(64, 2) void edge_mfma_kernel(
    const int* __restrict__ ei, const float* __restrict__ ea,
    const float* __restrict__ x_cur,
    const ushort_t* __restrict__ hbf_hi, const ushort_t* __restrict__ hbf_lo,
    const ushort_t* __restrict__ wf_hi, const ushort_t* __restrict__ wf_lo,
    const ushort_t* __restrict__ g_hi, const ushort_t* __restrict__ g_lo,
    const float* __restrict__ bias1c,
    const float* __restrict__ eb2, const float* __restrict__ cb1, const float* __restrict__ cw2,
    const int* __restrict__ csr_eid,
    int layer, float* __restrict__ agg_h, float* __restrict__ agg_x)
{
    __shared__ __align__(16) ushort_t s_acth[32 * SACT];
    __shared__ __align__(16) uchar_t  s_actl8[32 * SACT];
    __shared__ float s_d2[32], s_dist[32], s_diff[32][3];
    __shared__ int s_row[32];
    __shared__ int s_drows[32];
    __shared__ int s_dcnt[1];

    const int lane = threadIdx.x;
    const int lo = lane & 15, q = lane >> 4;
    const int e0 = blockIdx.x * 32;

    const ushort_t* wAh  = wf_hi + (size_t)layer * 4 * 16384;
    const ushort_t* wAl  = wf_lo + (size_t)layer * 4 * 16384;
    const ushort_t* wBh  = wAh + 16384;
    const ushort_t* wBl  = wAl + 16384;
    const ushort_t* wW2h = wAh + 32768;
    const ushort_t* wW2l = wAl + 32768;
    const ushort_t* wC1h = wAh + 49152;
    const ushort_t* wgh  = g_hi + (size_t)layer * 4096;
    const ushort_t* wgl  = g_lo + (size_t)layer * 4096;
    const float* b1v = bias1c + layer * 128;
    const float* b2v = eb2 + layer * 128;
    const float* cbv = cb1 + layer * 128;
    const float* c2v = cw2 + layer * 128;

    // ---- phase 0: geometry for 32 slots ----
    if (lane < 32) {
        int slot = e0 + lane;
        int e = csr_eid[slot];
        int r = ei[e], c = ei[N_EDGES + e];
        s_row[lane] = r;
        float dx = x_cur[r * 3 + 0] - x_cur[c * 3 + 0];
        float dy = x_cur[r * 3 + 1] - x_cur[c * 3 + 1];
        float dz = x_cur[r * 3 + 2] - x_cur[c * 3 + 2];
        float d2 = dx * dx + dy * dy + dz * dz;
        s_d2[lane] = d2;
        s_dist[lane] = sqrtf(d2 + EPSV);
        s_diff[lane][0] = dx; s_diff[lane][1] = dy; s_diff[lane][2] = dz;
    }
    int eidT[2], erT[2], ecT[2];
#pragma unroll
    for (int t = 0; t < 2; ++t) {
        eidT[t] = csr_eid[e0 + t * 16 + lo];
        erT[t] = ei[eidT[t]];
        ecT[t] = ei[N_EDGES + eidT[t]];
    }
    __syncthreads();   // B1 (single-wave: ~free)

    // wave-local distinct-row list (CSR slots row-sorted -> ~2 distinct rows / 32 slots)
    if (lane == 0) {
        int cnt = 0, prev = -1;
        for (int i = 0; i < 32; ++i) {
            int r = s_row[i];
            if (r != prev) { s_drows[cnt++] = r; prev = r; }
        }
        s_dcnt[0] = cnt;
    }

    // ---- A fragments for both tiles ----
    s8 aRh[2][4], aRl[2][4], aCh[2][4], aCl[2][4];
#pragma unroll
    for (int t = 0; t < 2; ++t)
#pragma unroll
        for (int kt = 0; kt < 4; ++kt) {
            size_t ro = (size_t)erT[t] * 128 + kt * 32 + q * 8;
            size_t co = (size_t)ecT[t] * 128 + kt * 32 + q * 8;
            aRh[t][kt] = *(const s8*)(hbf_hi + ro);
            aRl[t][kt] = *(const s8*)(hbf_lo + ro);
            aCh[t][kt] = *(const s8*)(hbf_hi + co);
            aCl[t][kt] = *(const s8*)(hbf_lo + co);
        }
    // ea (k=0..15) + d2 (k=16, lanes q==2 slot j=0)
    s8 aEAh[2], aEAl[2];
#pragma unroll
    for (int t = 0; t < 2; ++t) {
        aEAh[t] = (s8){0,0,0,0,0,0,0,0};
        aEAl[t] = (s8){0,0,0,0,0,0,0,0};
        if (q < 2) {
            const float* eap = ea + (size_t)eidT[t] * 16 + q * 8;
#pragma unroll
            for (int i = 0; i < 8; ++i) {
                ushort_t hh, ll;
                split_f16(eap[i], hh, ll);
                aEAh[t][i] = (short)hh; aEAl[t][i] = (short)ll;
            }
        } else if (q == 2) {
            ushort_t hh, ll;
            split_f16(s_d2[t * 16 + lo], hh, ll);
            aEAh[t][0] = (short)hh; aEAl[t][0] = (short)ll;
        }
    }

    // ---- GEMM1: y1 = silu(hR@W1a + hC@W1b + [ea|d2]@G + b1') ----
#pragma unroll
    for (int nt = 0; nt < 8; ++nt) {
        f4 aH[2], aL[2];
#pragma unroll
        for (int t = 0; t < 2; ++t) { aH[t] = (f4){0.f,0.f,0.f,0.f}; aL[t] = (f4){0.f,0.f,0.f,0.f}; }
        {
            s8 bGh = *(const s8*)(wgh + ((size_t)nt * 64 + lane) * 8);
            s8 bGl = *(const s8*)(wgl + ((size_t)nt * 64 + lane) * 8);
#pragma unroll
            for (int t = 0; t < 2; ++t) {
                aH[t] = mfma16(aEAh[t], bGh, aH[t]);
                aL[t] = mfma16(aEAh[t], bGl, aL[t]);
                aL[t] = mfma16(aEAl[t], bGh, aL[t]);
            }
        }
#pragma unroll
        for (int kt = 0; kt < 4; ++kt) {
            size_t base = ((size_t)(nt * 4 + kt) * 64 + lane) * 8;
            s8 bh = *(const s8*)(wAh + base);
            s8 bl = *(const s8*)(wAl + base);
            s8 ch = *(const s8*)(wBh + base);
            s8 cl = *(const s8*)(wBl + base);
#pragma unroll
            for (int t = 0; t < 2; ++t) {
                aH[t] = mfma16(aRh[t][kt], bh, aH[t]);
                aL[t] = mfma16(aRh[t][kt], bl, aL[t]);
                aL[t] = mfma16(aRl[t][kt], bh, aL[t]);
                aH[t] = mfma16(aCh[t][kt], ch, aH[t]);
                aL[t] = mfma16(aCh[t][kt], cl, aL[t]);
                aL[t] = mfma16(aCl[t][kt], ch, aL[t]);
            }
        }
        float bb = b1v[nt * 16 + lo];
#pragma unroll
        for (int t = 0; t < 2; ++t)
#pragma unroll
            for (int r = 0; r < 4; ++r) {
                float v = silu_f(aH[t][r] + aL[t][r] * INV4096 + bb);
                int off = (t * 16 + q * 4 + r) * SACT + nt * 16 + lo;
                ushort_t hh, ll;
                split_f16(v, hh, ll);
                s_acth[off] = hh;
                s_actl8[off] = (uchar_t)(ll >> 8);   // fp8-e5m2 = top byte of fp16
            }
    }
    __syncthreads();   // B2

    // ---- GEMM2: m = silu(y1 @ W2 + b2) ----
    s8 aYh[2][4], aYl[2][4];
#pragma unroll
    for (int t = 0; t < 2; ++t)
#pragma unroll
        for (int kt = 0; kt < 4; ++kt) {
            int off = (t * 16 + lo) * SACT + kt * 32 + q * 8;
            aYh[t][kt] = *(const s8*)&s_acth[off];
            aYl[t][kt] = expand_fp8lo(*(const uint2*)&s_actl8[off]);
        }
    __syncthreads();   // B3

    int rowm[2][4];
#pragma unroll
    for (int t = 0; t < 2; ++t)
#pragma unroll
        for (int r = 0; r < 4; ++r) rowm[t][r] = s_row[t * 16 + q * 4 + r];

    f4 mv[2][8];
#pragma unroll
    for (int nt = 0; nt < 8; ++nt) {
        f4 aH[2], aL[2];
#pragma unroll
        for (int t = 0; t < 2; ++t) { aH[t] = (f4){0.f,0.f,0.f,0.f}; aL[t] = (f4){0.f,0.f,0.f,0.f}; }
#pragma unroll
        for (int kt = 0; kt < 4; ++kt) {
            size_t base = ((size_t)(nt * 4 + kt) * 64 + lane) * 8;
            s8 bh = *(const s8*)(wW2h + base);
            s8 bl = *(const s8*)(wW2l + base);
#pragma unroll
            for (int t = 0; t < 2; ++t) {
                aH[t] = mfma16(aYh[t][kt], bh, aH[t]);
                aL[t] = mfma16(aYh[t][kt], bl, aL[t]);
                aL[t] = mfma16(aYl[t][kt], bh, aL[t]);
            }
        }
        float bb = b2v[nt * 16 + lo];
#pragma unroll
        for (int t = 0; t < 2; ++t) {
#pragma unroll
            for (int r = 0; r < 4; ++r) aH[t][r] = silu_f(aH[t][r] + aL[t][r] * INV4096 + bb);
            mv[t][nt] = aH[t];
        }
    }
    // store m (hi only -- GEMM3 runs hi-only) for GEMM3 A-frags
#pragma unroll
    for (int nt = 0; nt < 8; ++nt)
#pragma unroll
        for (int t = 0; t < 2; ++t)
#pragma unroll
            for (int r = 0; r < 4; ++r) {
                int off = (t * 16 + q * 4 + r) * SACT + nt * 16 + lo;
                _Float16 hh = (_Float16)mv[t][nt][r];
                s_acth[off] = __builtin_bit_cast(ushort_t, hh);
            }
    // segmented reduce m over the wave's 32 slots -> atomics per distinct row
    {
        int dcnt = s_dcnt[0];
        for (int di = 0; di < dcnt; ++di) {
            int dr = s_drows[di];
#pragma unroll
            for (int nt = 0; nt < 8; ++nt) {
                float v = 0.f;
#pragma unroll
                for (int t = 0; t < 2; ++t)
#pragma unroll
                    for (int r = 0; r < 4; ++r) v += (rowm[t][r] == dr) ? mv[t][nt][r] : 0.f;
                v += __shfl_xor(v, 16, 64);
                v += __shfl_xor(v, 32, 64);
                if (lane < 16) atomicAdd(&agg_h[(size_t)dr * HDIM + nt * 16 + lane], v);
            }
        }
    }
    __syncthreads();   // B4

    // ---- GEMM3 (hi-only): c = silu(m @ C1 + cb) ; w = tanh(c . c2) ----
    s8 aMh[2][4];
#pragma unroll
    for (int t = 0; t < 2; ++t)
#pragma unroll
        for (int kt = 0; kt < 4; ++kt) {
            int off = (t * 16 + lo) * SACT + kt * 32 + q * 8;
            aMh[t][kt] = *(const s8*)&s_acth[off];
        }

    float wpart[2][4] = {{0.f,0.f,0.f,0.f},{0.f,0.f,0.f,0.f}};
#pragma unroll
    for (int nt = 0; nt < 8; ++nt) {
        f4 aH[2];
#pragma unroll
        for (int t = 0; t < 2; ++t) aH[t] = (f4){0.f,0.f,0.f,0.f};
#pragma unroll
        for (int kt = 0; kt < 4; ++kt) {
            size_t base = ((size_t)(nt * 4 + kt) * 64 + lane) * 8;
            s8 bh = *(const s8*)(wC1h + base);
#pragma unroll
            for (int t = 0; t < 2; ++t)
                aH[t] = mfma16(aMh[t][kt], bh, aH[t]);
        }
        float bb = cbv[nt * 16 + lo];
        float cc = c2v[nt * 16 + lo];
#pragma unroll
        for (int t = 0; t < 2; ++t)
#pragma unroll
            for (int r = 0; r < 4; ++r)
                wpart[t][r] += silu_f(aH[t][r] + bb) * cc;
    }
#pragma unroll
    for (int t = 0; t < 2; ++t)
#pragma unroll
        for (int r = 0; r < 4; ++r) {
#pragma unroll
            for (int mask = 1; mask < 16; mask <<= 1)
                wpart[t][r] += __shfl_xor(wpart[t][r], mask, 16);
        }
    // trans vector + segmented reduce -> agg_x atomics per distinct row
    {
        float val[2][4];
#pragma unroll
        for (int t = 0; t < 2; ++t)
#pragma unroll
            for (int r = 0; r < 4; ++r) {
                int mm = t * 16 + q * 4 + r;
                val[t][r] = (lo < 3)
                    ? s_diff[mm][lo] / (s_dist[mm] + EPSV) * tanhf(wpart[t][r])
                    : 0.f;
            }
        int dcnt = s_dcnt[0];
        for (int di = 0; di < dcnt; ++di) {
            int dr = s_drows[di];
            float v = 0.f;
#pragma unroll
            for (int t = 0; t < 2; ++t)
#pragma unroll
                for (int r = 0; r < 4; ++r) v += (rowm[t][r] == dr) ? val[t][r] : 0.f;
            v += __shfl_xor(v, 16, 64);
            v += __shfl_xor(v, 32, 64);
            if (lane < 3) atomicAdd(&agg_x[dr * 3 + lane], v);
        }
    }
}

// ============ node kernel: 8 nodes/block, weights amortized ============
__global__ __launch_bounds__(128) void node_kernel(
    float* __restrict__ h_feat, float* __restrict__ x_cur,
    ushort_t* __restrict__ hbf_hi, ushort_t* __restrict__ hbf_lo,
    const float* __restrict__ agg_h, const float* __restrict__ agg_x,
    const float* __restrict__ mask,
    const float* __restrict__ n1p, const float* __restrict__ nb1p,
    const float* __restrict__ n2p, const float* __restrict__ nb2p, int layer) {
    __shared__ float s_cat[8][2 * HDIM];
    __shared__ float s_u[8][HDIM];
    int nb = blockIdx.x * 8, j = threadIdx.x;
    const size_t w1o = (size_t)layer * 2 * HDIM * HDIM;
    const size_t w2o = (size_t)layer * HDIM * HDIM;
    const size_t bo  = (size_t)layer * HDIM;

#pragma unroll
    for (int e = 0; e < 8; ++e) {
        s_cat[e][j] = h_feat[(size_t)(nb + e) * HDIM + j];
        s_cat[e][HDIM + j] = agg_h[(size_t)(nb + e) * HDIM + j];
    }
    __syncthreads();

    float u[8];
    float b1 = nb1p[bo + j];
#pragma unroll
    for (int e = 0; e < 8; ++e) u[e] = b1;
    for (int i0 = 0; i0 < 2 * HDIM; i0 += 2) {
        float w0 = n1p[w1o + (size_t)i0 * HDIM + j];
        float w1 = n1p[w1o + (size_t)(i0 + 1) * HDIM + j];
#pragma unroll
        for (int e = 0; e < 8; ++e)
            u[e] += s_cat[e][i0] * w0 + s_cat[e][i0 + 1] * w1;
    }
#pragma unroll
    for (int e = 0; e < 8; ++e) s_u[e][j] = silu_f(u[e]);
    __syncthreads();

    float acc[8];
    float b2 = nb2p[bo + j];
#pragma unroll
    for (int e = 0; e < 8; ++e) acc[e] = b2;
    for (int i0 = 0; i0 < HDIM; i0 += 2) {
        float w0 = n2p[w2o + (size_t)i0 * HDIM + j];
        float w1 = n2p[w2o + (size_t)(i0 + 1) * HDIM + j];
#pragma unroll
        for (int e = 0; e < 8; ++e)
            acc[e] += s_u[e][i0] * w0 + s_u[e][i0 + 1] * w1;
    }
#pragma unroll
    for (int e = 0; e < 8; ++e) {
        float nh = s_cat[e][j] + acc[e];
        h_feat[(size_t)(nb + e) * HDIM + j] = nh;
        split_f16(nh, hbf_hi[(size_t)(nb + e) * HDIM + j], hbf_lo[(size_t)(nb + e) * HDIM + j]);
    }
    if (j < 24) {
        int e = j / 3, c = j - e * 3;
        x_cur[(nb + e) * 3 + c] += agg_x[(nb + e) * 3 + c] * mask[nb + e];
    }
}

__global__ void out_kernel(const float* __restrict__ x_cur, const float* __restrict__ x_in,
                           const float* __restrict__ mask, float* __restrict__ out) {
    int idx = blockIdx.x * blockDim.x + threadIdx.x;
    if (idx < N_NODES * 3) {
        int n = idx / 3;
        out[idx] = (x_cur[idx] - x_in[idx]) * mask[n];
    }
}

extern "C" void kernel_launch(void* const* d_in, const int* in_sizes, int n_in,
                              void* d_out, int out_size, void* d_ws, size_t ws_size,
                              hipStream_t stream) {
    const float* h    = (const float*)d_in[0];
    const float* x    = (const float*)d_in[1];
    const int*   ei   = (const int*)d_in[2];
    const float* ea   = (const float*)d_in[3];
    const float* t    = (const float*)d_in[4];
    const float* mask = (const float*)d_in[5];
    const float* tw1  = (const float*)d_in[6];
    const float* tb1  = (const float*)d_in[7];
    const float* tw2  = (const float*)d_in[8];
    const float* tb2  = (const float*)d_in[9];
    const float* new_ = (const float*)d_in[10];
    const float* neb  = (const float*)d_in[11];
    const float* eew  = (const float*)d_in[12];
    const float* eeb  = (const float*)d_in[13];
    const float* ew1  = (const float*)d_in[14];
    const float* eb1  = (const float*)d_in[15];
    const float* ew2  = (const float*)d_in[16];
    const float* eb2  = (const float*)d_in[17];
    const float* cw1  = (const float*)d_in[18];
    const float* cb1  = (const float*)d_in[19];
    const float* cw2  = (const float*)d_in[20];
    const float* nw1  = (const float*)d_in[21];
    const float* nb1  = (const float*)d_in[22];
    const float* nw2  = (const float*)d_in[23];
    const float* nb2  = (const float*)d_in[24];

    // ---- workspace carve-out (256 B aligned) ----
    char* p = (char*)d_ws;
    auto alloc = [&](size_t bytes) -> char* {
        char* r = p;
        p += (bytes + 255) & ~(size_t)255;
        return r;
    };
    float* t_emb    = (float*)alloc(HDIM * 4);
    float* h_feat   = (float*)alloc((size_t)N_NODES * HDIM * 4);
    float* x_cur    = (float*)alloc((size_t)N_NODES * 3 * 4);
    float* agg_h    = (float*)alloc((size_t)N_NODES * HDIM * 4);
    float* agg_x    = (float*)alloc((size_t)N_NODES * 3 * 4);
    float* bias1c   = (float*)alloc(NLAYERS * HDIM * 4);
    ushort_t* hbf_hi = (ushort_t*)alloc((size_t)N_NODES * HDIM * 2);
    ushort_t* hbf_lo = (ushort_t*)alloc((size_t)N_NODES * HDIM * 2);
    ushort_t* wf_hi  = (ushort_t*)alloc((size_t)NLAYERS * 4 * 16384 * 2);
    ushort_t* wf_lo  = (ushort_t*)alloc((size_t)NLAYERS * 4 * 16384 * 2);
    ushort_t* g_hi   = (ushort_t*)alloc((size_t)NLAYERS * 4096 * 2);
    ushort_t* g_lo   = (ushort_t*)alloc((size_t)NLAYERS * 4096 * 2);
    int* deg        = (int*)alloc((size_t)N_NODES * 4);
    int* row_start  = (int*)alloc((size_t)(N_NODES + 1) * 4);
    int* cursor     = (int*)alloc((size_t)N_NODES * 4);
    int* csr_eid    = (int*)alloc((size_t)N_EDGES * 4);

    repack_weights<<<(NLAYERS * 4 * 16384 + 255) / 256, 256, 0, stream>>>(ew1, ew2, cw1, wf_hi, wf_lo);
    prep_g<<<(NLAYERS * 4096 + NLAYERS * 128 + 255) / 256, 256, 0, stream>>>(eew, eeb, ew1, eb1, g_hi, g_lo, bias1c);
    temb_kernel<<<1, HDIM, 0, stream>>>(t, tw1, tb1, tw2, tb2, t_emb);
    hfeat_kernel<<<N_NODES, HDIM, 0, stream>>>(h, new_, neb, t_emb, h_feat, hbf_hi, hbf_lo);
    xinit_kernel<<<(N_NODES * 3 + 255) / 256, 256, 0, stream>>>(x, x_cur);

    hipMemsetAsync(deg, 0, (size_t)N_NODES * 4, stream);
    deg_kernel<<<(N_EDGES + 255) / 256, 256, 0, stream>>>(ei, deg);
    scan_kernel<<<1, 256, 0, stream>>>(deg, row_start, cursor);
    scatter_kernel<<<(N_EDGES + 255) / 256, 256, 0, stream>>>(ei, cursor, csr_eid);

    for (int l = 0; l < NLAYERS; ++l) {
        hipMemsetAsync(agg_h, 0, (size_t)N_NODES * HDIM * 4, stream);
        hipMemsetAsync(agg_x, 0, (size_t)N_NODES * 3 * 4, stream);
        edge_mfma_kernel<<<N_EDGES / 32, 64, 0, stream>>>(
            ei, ea, x_cur, hbf_hi, hbf_lo, wf_hi, wf_lo, g_hi, g_lo, bias1c,
            eb2, cb1, cw2, csr_eid, l, agg_h, agg_x);
        node_kernel<<<N_NODES / 8, 128, 0, stream>>>(
            h_feat, x_cur, hbf_hi, hbf_lo, agg_h, agg_x, mask, nw1, nb1, nw2, nb2, l);
    }

    out_kernel<<<(N_NODES * 3 + 255) / 256, 256, 0, stream>>>(x_cur, x, mask, (float*)d_out);
}

// Round 11
// 1167.850 us; speedup vs baseline: 4.9737x; 1.1435x over previous
//
#include <hip/hip_runtime.h>
#include <hip/hip_bf16.h>

#define N_NODES 10000
#define N_EDGES 320000
#define HDIM 128
#define NODE_IN 64
#define EDGE_IN 16
#define NLAYERS 4
#define EPSV 1e-8f
#define SACT 136       // LDS activation row stride (elems)
#define INV4096 2.44140625e-4f

typedef unsigned short ushort_t;
typedef __attribute__((ext_vector_type(8))) short s8;        // 8 fp16 bit-pattern (4 VGPRs)
typedef __attribute__((ext_vector_type(8))) _Float16 h8;
typedef __attribute__((ext_vector_type(4))) float f4;

__device__ __forceinline__ float silu_f(float z) { return z / (1.0f + __expf(-z)); }

__device__ __forceinline__ f4 mfma16(s8 a, s8 b, f4 c) {
    return __builtin_amdgcn_mfma_f32_16x16x32_f16(
        __builtin_bit_cast(h8, a), __builtin_bit_cast(h8, b), c, 0, 0, 0);
}

// fp32 -> fp16 hi + (residual*4096) lo   (rep error ~2^-23 relative)
__device__ __forceinline__ void split_f16(float x, ushort_t& hi, ushort_t& lo) {
    _Float16 h = (_Float16)x;
    float hf = (float)h;
    _Float16 l = (_Float16)((x - hf) * 4096.0f);
    hi = __builtin_bit_cast(ushort_t, h);
    lo = __builtin_bit_cast(ushort_t, l);
}

// ============ CSR build ============
__global__ void deg_kernel(const int* __restrict__ ei, int* __restrict__ deg) {
    int e = blockIdx.x * 256 + threadIdx.x;
    if (e < N_EDGES) atomicAdd(&deg[ei[e]], 1);
}

__global__ void scan_kernel(const int* __restrict__ deg, int* __restrict__ row_start,
                            int* __restrict__ cursor) {
    __shared__ int s_part[256];
    const int CH = 40;   // 256*40 = 10240 >= N_NODES
    int t = threadIdx.x;
    int base = t * CH;
    int sum = 0;
    for (int i = 0; i < CH; ++i) { int n = base + i; if (n < N_NODES) sum += deg[n]; }
    s_part[t] = sum;
    __syncthreads();
    for (int d = 1; d < 256; d <<= 1) {
        int v = (t >= d) ? s_part[t - d] : 0;
        __syncthreads();
        s_part[t] += v;
        __syncthreads();
    }
    int off = s_part[t] - sum;
    for (int i = 0; i < CH; ++i) {
        int n = base + i;
        if (n < N_NODES) { row_start[n] = off; cursor[n] = off; off += deg[n]; }
    }
    if (t == 255) row_start[N_NODES] = s_part[255];
}

__global__ void scatter_kernel(const int* __restrict__ ei, int* __restrict__ cursor,
                               int* __restrict__ csr_eid) {
    int e = blockIdx.x * 256 + threadIdx.x;
    if (e < N_EDGES) {
        int r = ei[e];
        int pos = atomicAdd(&cursor[r], 1);
        csr_eid[pos] = e;
    }
}

// ============ one-time slot-order prepack: rows/cols + ea split fp16 ============
__global__ void prep_edges(const int* __restrict__ ei, const int* __restrict__ csr_eid,
                           const float* __restrict__ ea,
                           int* __restrict__ rows_s, int* __restrict__ cols_s,
                           ushort_t* __restrict__ eah, ushort_t* __restrict__ eal) {
    int slot = blockIdx.x * 256 + threadIdx.x;
    if (slot >= N_EDGES) return;
    int eid = csr_eid[slot];
    rows_s[slot] = ei[eid];
    cols_s[slot] = ei[N_EDGES + eid];
    const float* src = ea + (size_t)eid * EDGE_IN;
#pragma unroll
    for (int i = 0; i < EDGE_IN; ++i) {
        ushort_t hh, ll;
        split_f16(src[i], hh, ll);
        eah[(size_t)slot * EDGE_IN + i] = hh;
        eal[(size_t)slot * EDGE_IN + i] = ll;
    }
}

// ============ prep 1: repack W1a,W1b,W2,C1 into MFMA B-frag order, split fp16 hi/lo ============
__global__ void repack_weights(const float* __restrict__ ew1, const float* __restrict__ ew2,
                               const float* __restrict__ cw1,
                               ushort_t* __restrict__ wf_hi, ushort_t* __restrict__ wf_lo) {
    int gid = blockIdx.x * 256 + threadIdx.x;
    const int total = NLAYERS * 4 * 16384;
    if (gid >= total) return;
    int l   = gid / (4 * 16384);
    int rem = gid % (4 * 16384);
    int m4  = rem / 16384;
    int idx = rem & 16383;
    int b    = idx >> 9;
    int lane = (idx >> 3) & 63;
    int j    = idx & 7;
    int nt = b >> 2, kt = b & 3;
    int k = kt * 32 + ((lane >> 4) << 3) + j;
    int n = (nt << 4) + (lane & 15);
    float v;
    if (m4 == 0)      v = ew1[(size_t)l * 385 * 128 + (size_t)k * 128 + n];
    else if (m4 == 1) v = ew1[(size_t)l * 385 * 128 + (size_t)(128 + k) * 128 + n];
    else if (m4 == 2) v = ew2[(size_t)l * 16384 + k * 128 + n];
    else              v = cw1[(size_t)l * 16384 + k * 128 + n];
    split_f16(v, wf_hi[gid], wf_lo[gid]);
}

// ============ prep 2: G = eew @ W1c (K rows 0-15) + d2 weight row at k=16; frag-packed, split ============
__global__ void prep_g(const float* __restrict__ eew, const float* __restrict__ eeb,
                       const float* __restrict__ ew1, const float* __restrict__ eb1,
                       ushort_t* __restrict__ g_hi, ushort_t* __restrict__ g_lo,
                       float* __restrict__ bias1c) {
    int gid = blockIdx.x * 256 + threadIdx.x;
    const int T1 = NLAYERS * 4096;
    if (gid < T1) {
        int l = gid >> 12;
        int idx = gid & 4095;
        int nt = idx >> 9;
        int lane = (idx >> 3) & 63;
        int j = idx & 7;
        int q = lane >> 4;
        int n = (nt << 4) + (lane & 15);
        int k = q * 8 + j;
        float v = 0.f;
        if (k < EDGE_IN) {
            const float* w1c = ew1 + (size_t)l * 385 * 128 + (size_t)257 * 128;
            float acc = 0.f;
            for (int c = 0; c < HDIM; ++c) acc += eew[k * 128 + c] * w1c[(size_t)c * 128 + n];
            v = acc;
        } else if (k == EDGE_IN) {
            v = ew1[(size_t)l * 385 * 128 + (size_t)256 * 128 + n];   // d2 weight row
        }
        split_f16(v, g_hi[gid], g_lo[gid]);
    } else if (gid < T1 + NLAYERS * 128) {
        int r = gid - T1;
        int l = r >> 7;
        int n = r & 127;
        const float* w1c = ew1 + (size_t)l * 385 * 128 + (size_t)257 * 128;
        float acc = eb1[l * 128 + n];
        for (int c = 0; c < HDIM; ++c) acc += eeb[c] * w1c[(size_t)c * 128 + n];
        bias1c[r] = acc;
    }
}

// ============ t_emb ============
__global__ void temb_kernel(const float* t, const float* tw1, const float* tb1,
                            const float* tw2, const float* tb2, float* t_emb) {
    __shared__ float s_a[HDIM];
    int j = threadIdx.x;
    s_a[j] = silu_f(t[0] * tw1[j] + tb1[j]);
    __syncthreads();
    float acc = tb2[j];
    for (int k = 0; k < HDIM; ++k) acc += s_a[k] * tw2[k * HDIM + j];
    t_emb[j] = acc;
}

// ============ h_feat init (fp32 + split fp16 mirror) ============
__global__ void hfeat_kernel(const float* __restrict__ h, const float* __restrict__ new_,
                             const float* __restrict__ neb, const float* __restrict__ t_emb,
                             float* __restrict__ h_feat,
                             ushort_t* __restrict__ hbf_hi, ushort_t* __restrict__ hbf_lo) {
    __shared__ float s_h[NODE_IN];
    int n = blockIdx.x, j = threadIdx.x;
    if (j < NODE_IN) s_h[j] = h[(size_t)n * NODE_IN + j];
    __syncthreads();
    float acc = neb[j] + t_emb[j];
#pragma unroll 8
    for (int i = 0; i < NODE_IN; ++i) acc += s_h[i] * new_[i * HDIM + j];
    h_feat[(size_t)n * HDIM + j] = acc;
    split_f16(acc, hbf_hi[(size_t)n * HDIM + j], hbf_lo[(size_t)n * HDIM + j]);
}

__global__ void xinit_kernel(const float* x, float* x_cur) {
    int idx = blockIdx.x * blockDim.x + threadIdx.x;
    if (idx < N_NODES * 3) x_cur[idx] = x[idx];
}

// ============ MFMA edge kernel: 1 block = 1 wave = 32 CSR slots (2 M-tiles) ============
// GEMM1 split fp16x2; GEMM2/GEMM3 hi-only. Slot-order prepacked rows/cols/ea.
__global__ __launch_bounds__(64, 2) void edge_mfma_kernel(
    const int* __restrict__ rows_s, const int* __restrict__ cols_s,
    const ushort_t* __restrict__ eah, const ushort_t* __restrict__ eal,
    const float* __restrict__ x_cur,
    const ushort_t* __restrict__ hbf_hi, const ushort_t* __restrict__ hbf_lo,
    const ushort_t* __restrict__ wf_hi, const ushort_t* __restrict__ wf_lo,
    const ushort_t* __restrict__ g_hi, const ushort_t* __restrict__ g_lo,
    const float* __restrict__ bias1c,
    const float* __restrict__ eb2, const float* __restrict__ cb1, const float* __restrict__ cw2,
    int layer, float* __restrict__ agg_h, float* __restrict__ agg_x)
{
    __shared__ __align__(16) ushort_t s_acth[32 * SACT];
    __shared__ float s_d2[32], s_dist[32], s_diff[32][3];
    __shared__ int s_row[32], s_col[32];
    __shared__ int s_drows[32];
    __shared__ int s_dcnt[1];

    const int lane = threadIdx.x;
    const int lo = lane & 15, q = lane >> 4;
    const int e0 = blockIdx.x * 32;

    const ushort_t* wAh  = wf_hi + (size_t)layer * 4 * 16384;
    const ushort_t* wAl  = wf_lo + (size_t)layer * 4 * 16384;
    const ushort_t* wBh  = wAh + 16384;
    const ushort_t* wBl  = wAl + 16384;
    const ushort_t* wW2h = wAh + 32768;
    const ushort_t* wC1h = wAh + 49152;
    const ushort_t* wgh  = g_hi + (size_t)layer * 4096;
    const ushort_t* wgl  = g_lo + (size_t)layer * 4096;
    const float* b1v = bias1c + layer * 128;
    const float* b2v = eb2 + layer * 128;
    const float* cbv = cb1 + layer * 128;
    const float* c2v = cw2 + layer * 128;

    // ---- phase 0: geometry for 32 slots (coalesced slot-order reads) ----
    if (lane < 32) {
        int slot = e0 + lane;
        int r = rows_s[slot], c = cols_s[slot];
        s_row[lane] = r; s_col[lane] = c;
        float dx = x_cur[r * 3 + 0] - x_cur[c * 3 + 0];
        float dy = x_cur[r * 3 + 1] - x_cur[c * 3 + 1];
        float dz = x_cur[r * 3 + 2] - x_cur[c * 3 + 2];
        float d2 = dx * dx + dy * dy + dz * dz;
        s_d2[lane] = d2;
        s_dist[lane] = sqrtf(d2 + EPSV);
        s_diff[lane][0] = dx; s_diff[lane][1] = dy; s_diff[lane][2] = dz;
    }
    __syncthreads();   // B1 (single-wave: cheap)

    // distinct-row list via ballot (CSR slots row-sorted)
    {
        bool head = false;
        if (lane < 32) {
            int r = s_row[lane];
            int prev = (lane == 0) ? -1 : s_row[lane - 1];
            head = (r != prev);
        }
        unsigned long long b = __ballot(head);
        if (head) {
            int idx = __popcll(b & ((1ull << lane) - 1ull));
            s_drows[idx] = s_row[lane];
        }
        if (lane == 0) s_dcnt[0] = __popcll(b);
    }

    // ---- A fragments for both tiles ----
    int erT[2], ecT[2];
#pragma unroll
    for (int t = 0; t < 2; ++t) { erT[t] = s_row[t * 16 + lo]; ecT[t] = s_col[t * 16 + lo]; }

    s8 aRh[2][4], aRl[2][4], aCh[2][4], aCl[2][4];
#pragma unroll
    for (int t = 0; t < 2; ++t)
#pragma unroll
        for (int kt = 0; kt < 4; ++kt) {
            size_t ro = (size_t)erT[t] * 128 + kt * 32 + q * 8;
            size_t co = (size_t)ecT[t] * 128 + kt * 32 + q * 8;
            aRh[t][kt] = *(const s8*)(hbf_hi + ro);
            aRl[t][kt] = *(const s8*)(hbf_lo + ro);
            aCh[t][kt] = *(const s8*)(hbf_hi + co);
            aCl[t][kt] = *(const s8*)(hbf_lo + co);
        }
    // ea (k=0..15, prepacked fp16 split, coalesced) + d2 (k=16, lanes q==2 slot j=0)
    s8 aEAh[2], aEAl[2];
#pragma unroll
    for (int t = 0; t < 2; ++t) {
        aEAh[t] = (s8){0,0,0,0,0,0,0,0};
        aEAl[t] = (s8){0,0,0,0,0,0,0,0};
        if (q < 2) {
            size_t off = (size_t)(e0 + t * 16 + lo) * EDGE_IN + q * 8;
            aEAh[t] = *(const s8*)(eah + off);
            aEAl[t] = *(const s8*)(eal + off);
        } else if (q == 2) {
            ushort_t hh, ll;
            split_f16(s_d2[t * 16 + lo], hh, ll);
            aEAh[t][0] = (short)hh; aEAl[t][0] = (short)ll;
        }
    }

    // ---- GEMM1 (split): y1 = silu(hR@W1a + hC@W1b + [ea|d2]@G + b1') ----
#pragma unroll
    for (int nt = 0; nt < 8; ++nt) {
        f4 aH[2], aL[2];
#pragma unroll
        for (int t = 0; t < 2; ++t) { aH[t] = (f4){0.f,0.f,0.f,0.f}; aL[t] = (f4){0.f,0.f,0.f,0.f}; }
        {
            s8 bGh = *(const s8*)(wgh + ((size_t)nt * 64 + lane) * 8);
            s8 bGl = *(const s8*)(wgl + ((size_t)nt * 64 + lane) * 8);
#pragma unroll
            for (int t = 0; t < 2; ++t) {
                aH[t] = mfma16(aEAh[t], bGh, aH[t]);
                aL[t] = mfma16(aEAh[t], bGl, aL[t]);
                aL[t] = mfma16(aEAl[t], bGh, aL[t]);
            }
        }
#pragma unroll
        for (int kt = 0; kt < 4; ++kt) {
            size_t base = ((size_t)(nt * 4 + kt) * 64 + lane) * 8;
            s8 bh = *(const s8*)(wAh + base);
            s8 bl = *(const s8*)(wAl + base);
            s8 ch = *(const s8*)(wBh + base);
            s8 cl = *(const s8*)(wBl + base);
#pragma unroll
            for (int t = 0; t < 2; ++t) {
                aH[t] = mfma16(aRh[t][kt], bh, aH[t]);
                aL[t] = mfma16(aRh[t][kt], bl, aL[t]);
                aL[t] = mfma16(aRl[t][kt], bh, aL[t]);
                aH[t] = mfma16(aCh[t][kt], ch, aH[t]);
                aL[t] = mfma16(aCh[t][kt], cl, aL[t]);
                aL[t] = mfma16(aCl[t][kt], ch, aL[t]);
            }
        }
        float bb = b1v[nt * 16 + lo];
#pragma unroll
        for (int t = 0; t < 2; ++t)
#pragma unroll
            for (int r = 0; r < 4; ++r) {
                float v = silu_f(aH[t][r] + aL[t][r] * INV4096 + bb);
                int off = (t * 16 + q * 4 + r) * SACT + nt * 16 + lo;
                _Float16 hh = (_Float16)v;
                s_acth[off] = __builtin_bit_cast(ushort_t, hh);
            }
    }
    __syncthreads();   // B2

    // ---- GEMM2 (hi-only): m = silu(y1 @ W2 + b2) ----
    s8 aYh[2][4];
#pragma unroll
    for (int t = 0; t < 2; ++t)
#pragma unroll
        for (int kt = 0; kt < 4; ++kt) {
            int off = (t * 16 + lo) * SACT + kt * 32 + q * 8;
            aYh[t][kt] = *(const s8*)&s_acth[off];
        }
    __syncthreads();   // B3

    int rowm[2][4];
#pragma unroll
    for (int t = 0; t < 2; ++t)
#pragma unroll
        for (int r = 0; r < 4; ++r) rowm[t][r] = s_row[t * 16 + q * 4 + r];

    f4 mv[2][8];
#pragma unroll
    for (int nt = 0; nt < 8; ++nt) {
        f4 aH[2];
#pragma unroll
        for (int t = 0; t < 2; ++t) aH[t] = (f4){0.f,0.f,0.f,0.f};
#pragma unroll
        for (int kt = 0; kt < 4; ++kt) {
            size_t base = ((size_t)(nt * 4 + kt) * 64 + lane) * 8;
            s8 bh = *(const s8*)(wW2h + base);
#pragma unroll
            for (int t = 0; t < 2; ++t)
                aH[t] = mfma16(aYh[t][kt], bh, aH[t]);
        }
        float bb = b2v[nt * 16 + lo];
#pragma unroll
        for (int t = 0; t < 2; ++t) {
#pragma unroll
            for (int r = 0; r < 4; ++r) aH[t][r] = silu_f(aH[t][r] + bb);
            mv[t][nt] = aH[t];
        }
    }
    // store m (hi) for GEMM3 A-frags
#pragma unroll
    for (int nt = 0; nt < 8; ++nt)
#pragma unroll
        for (int t = 0; t < 2; ++t)
#pragma unroll
            for (int r = 0; r < 4; ++r) {
                int off = (t * 16 + q * 4 + r) * SACT + nt * 16 + lo;
                _Float16 hh = (_Float16)mv[t][nt][r];
                s_acth[off] = __builtin_bit_cast(ushort_t, hh);
            }
    // segmented reduce m over the wave's 32 slots -> atomics per distinct row
    {
        int dcnt = s_dcnt[0];
        for (int di = 0; di < dcnt; ++di) {
            int dr = s_drows[di];
#pragma unroll
            for (int nt = 0; nt < 8; ++nt) {
                float v = 0.f;
#pragma unroll
                for (int t = 0; t < 2; ++t)
#pragma unroll
                    for (int r = 0; r < 4; ++r) v += (rowm[t][r] == dr) ? mv[t][nt][r] : 0.f;
                v += __shfl_xor(v, 16, 64);
                v += __shfl_xor(v, 32, 64);
                if (lane < 16) atomicAdd(&agg_h[(size_t)dr * HDIM + nt * 16 + lane], v);
            }
        }
    }
    __syncthreads();   // B4

    // ---- GEMM3 (hi-only): c = silu(m @ C1 + cb) ; w = tanh(c . c2) ----
    s8 aMh[2][4];
#pragma unroll
    for (int t = 0; t < 2; ++t)
#pragma unroll
        for (int kt = 0; kt < 4; ++kt) {
            int off = (t * 16 + lo) * SACT + kt * 32 + q * 8;
            aMh[t][kt] = *(const s8*)&s_acth[off];
        }

    float wpart[2][4] = {{0.f,0.f,0.f,0.f},{0.f,0.f,0.f,0.f}};
#pragma unroll
    for (int nt = 0; nt < 8; ++nt) {
        f4 aH[2];
#pragma unroll
        for (int t = 0; t < 2; ++t) aH[t] = (f4){0.f,0.f,0.f,0.f};
#pragma unroll
        for (int kt = 0; kt < 4; ++kt) {
            size_t base = ((size_t)(nt * 4 + kt) * 64 + lane) * 8;
            s8 bh = *(const s8*)(wC1h + base);
#pragma unroll
            for (int t = 0; t < 2; ++t)
                aH[t] = mfma16(aMh[t][kt], bh, aH[t]);
        }
        float bb = cbv[nt * 16 + lo];
        float cc = c2v[nt * 16 + lo];
#pragma unroll
        for (int t = 0; t < 2; ++t)
#pragma unroll
            for (int r = 0; r < 4; ++r)
                wpart[t][r] += silu_f(aH[t][r] + bb) * cc;
    }
#pragma unroll
    for (int t = 0; t < 2; ++t)
#pragma unroll
        for (int r = 0; r < 4; ++r) {
#pragma unroll
            for (int mask = 1; mask < 16; mask <<= 1)
                wpart[t][r] += __shfl_xor(wpart[t][r], mask, 16);
        }
    // trans vector + segmented reduce -> agg_x atomics per distinct row
    {
        float val[2][4];
#pragma unroll
        for (int t = 0; t < 2; ++t)
#pragma unroll
            for (int r = 0; r < 4; ++r) {
                int mm = t * 16 + q * 4 + r;
                val[t][r] = (lo < 3)
                    ? s_diff[mm][lo] / (s_dist[mm] + EPSV) * tanhf(wpart[t][r])
                    : 0.f;
            }
        int dcnt = s_dcnt[0];
        for (int di = 0; di < dcnt; ++di) {
            int dr = s_drows[di];
            float v = 0.f;
#pragma unroll
            for (int t = 0; t < 2; ++t)
#pragma unroll
                for (int r = 0; r < 4; ++r) v += (rowm[t][r] == dr) ? val[t][r] : 0.f;
            v += __shfl_xor(v, 16, 64);
            v += __shfl_xor(v, 32, 64);
            if (lane < 3) atomicAdd(&agg_x[dr * 3 + lane], v);
        }
    }
}

// ============ node kernel: 8 nodes/block, weights amortized ============
__global__ __launch_bounds__(128) void node_kernel(
    float* __restrict__ h_feat, float* __restrict__ x_cur,
    ushort_t* __restrict__ hbf_hi, ushort_t* __restrict__ hbf_lo,
    const float* __restrict__ agg_h, const float* __restrict__ agg_x,
    const float* __restrict__ mask,
    const float* __restrict__ n1p, const float* __restrict__ nb1p,
    const float* __restrict__ n2p, const float* __restrict__ nb2p, int layer) {
    __shared__ float s_cat[8][2 * HDIM];
    __shared__ float s_u[8][HDIM];
    int nb = blockIdx.x * 8, j = threadIdx.x;
    const size_t w1o = (size_t)layer * 2 * HDIM * HDIM;
    const size_t w2o = (size_t)layer * HDIM * HDIM;
    const size_t bo  = (size_t)layer * HDIM;

#pragma unroll
    for (int e = 0; e < 8; ++e) {
        s_cat[e][j] = h_feat[(size_t)(nb + e) * HDIM + j];
        s_cat[e][HDIM + j] = agg_h[(size_t)(nb + e) * HDIM + j];
    }
    __syncthreads();

    float u[8];
    float b1 = nb1p[bo + j];
#pragma unroll
    for (int e = 0; e < 8; ++e) u[e] = b1;
    for (int i0 = 0; i0 < 2 * HDIM; i0 += 2) {
        float w0 = n1p[w1o + (size_t)i0 * HDIM + j];
        float w1 = n1p[w1o + (size_t)(i0 + 1) * HDIM + j];
#pragma unroll
        for (int e = 0; e < 8; ++e)
            u[e] += s_cat[e][i0] * w0 + s_cat[e][i0 + 1] * w1;
    }
#pragma unroll
    for (int e = 0; e < 8; ++e) s_u[e][j] = silu_f(u[e]);
    __syncthreads();

    float acc[8];
    float b2 = nb2p[bo + j];
#pragma unroll
    for (int e = 0; e < 8; ++e) acc[e] = b2;
    for (int i0 = 0; i0 < HDIM; i0 += 2) {
        float w0 = n2p[w2o + (size_t)i0 * HDIM + j];
        float w1 = n2p[w2o + (size_t)(i0 + 1) * HDIM + j];
#pragma unroll
        for (int e = 0; e < 8; ++e)
            acc[e] += s_u[e][i0] * w0 + s_u[e][i0 + 1] * w1;
    }
#pragma unroll
    for (int e = 0; e < 8; ++e) {
        float nh = s_cat[e][j] + acc[e];
        h_feat[(size_t)(nb + e) * HDIM + j] = nh;
        split_f16(nh, hbf_hi[(size_t)(nb + e) * HDIM + j], hbf_lo[(size_t)(nb + e) * HDIM + j]);
    }
    if (j < 24) {
        int e = j / 3, c = j - e * 3;
        x_cur[(nb + e) * 3 + c] += agg_x[(nb + e) * 3 + c] * mask[nb + e];
    }
}

__global__ void out_kernel(const float* __restrict__ x_cur, const float* __restrict__ x_in,
                           const float* __restrict__ mask, float* __restrict__ out) {
    int idx = blockIdx.x * blockDim.x + threadIdx.x;
    if (idx < N_NODES * 3) {
        int n = idx / 3;
        out[idx] = (x_cur[idx] - x_in[idx]) * mask[n];
    }
}

extern "C" void kernel_launch(void* const* d_in, const int* in_sizes, int n_in,
                              void* d_out, int out_size, void* d_ws, size_t ws_size,
                              hipStream_t stream) {
    const float* h    = (const float*)d_in[0];
    const float* x    = (const float*)d_in[1];
    const int*   ei   = (const int*)d_in[2];
    const float* ea   = (const float*)d_in[3];
    const float* t    = (const float*)d_in[4];
    const float* mask = (const float*)d_in[5];
    const float* tw1  = (const float*)d_in[6];
    const float* tb1  = (const float*)d_in[7];
    const float* tw2  = (const float*)d_in[8];
    const float* tb2  = (const float*)d_in[9];
    const float* new_ = (const float*)d_in[10];
    const float* neb  = (const float*)d_in[11];
    const float* eew  = (const float*)d_in[12];
    const float* eeb  = (const float*)d_in[13];
    const float* ew1  = (const float*)d_in[14];
    const float* eb1  = (const float*)d_in[15];
    const float* ew2  = (const float*)d_in[16];
    const float* eb2  = (const float*)d_in[17];
    const float* cw1  = (const float*)d_in[18];
    const float* cb1  = (const float*)d_in[19];
    const float* cw2  = (const float*)d_in[20];
    const float* nw1  = (const float*)d_in[21];
    const float* nb1  = (const float*)d_in[22];
    const float* nw2  = (const float*)d_in[23];
    const float* nb2  = (const float*)d_in[24];

    // ---- workspace carve-out (256 B aligned) ----
    char* p = (char*)d_ws;
    auto alloc = [&](size_t bytes) -> char* {
        char* r = p;
        p += (bytes + 255) & ~(size_t)255;
        return r;
    };
    float* t_emb    = (float*)alloc(HDIM * 4);
    float* h_feat   = (float*)alloc((size_t)N_NODES * HDIM * 4);
    float* x_cur    = (float*)alloc((size_t)N_NODES * 3 * 4);
    float* agg_h    = (float*)alloc((size_t)N_NODES * HDIM * 4);
    float* agg_x    = (float*)alloc((size_t)N_NODES * 3 * 4);
    float* bias1c   = (float*)alloc(NLAYERS * HDIM * 4);
    ushort_t* hbf_hi = (ushort_t*)alloc((size_t)N_NODES * HDIM * 2);
    ushort_t* hbf_lo = (ushort_t*)alloc((size_t)N_NODES * HDIM * 2);
    ushort_t* wf_hi  = (ushort_t*)alloc((size_t)NLAYERS * 4 * 16384 * 2);
    ushort_t* wf_lo  = (ushort_t*)alloc((size_t)NLAYERS * 4 * 16384 * 2);
    ushort_t* g_hi   = (ushort_t*)alloc((size_t)NLAYERS * 4096 * 2);
    ushort_t* g_lo   = (ushort_t*)alloc((size_t)NLAYERS * 4096 * 2);
    int* deg        = (int*)alloc((size_t)N_NODES * 4);
    int* row_start  = (int*)alloc((size_t)(N_NODES + 1) * 4);
    int* cursor     = (int*)alloc((size_t)N_NODES * 4);
    int* csr_eid    = (int*)alloc((size_t)N_EDGES * 4);
    int* rows_s     = (int*)alloc((size_t)N_EDGES * 4);
    int* cols_s     = (int*)alloc((size_t)N_EDGES * 4);
    ushort_t* eah   = (ushort_t*)alloc((size_t)N_EDGES * EDGE_IN * 2);
    ushort_t* eal   = (ushort_t*)alloc((size_t)N_EDGES * EDGE_IN * 2);

    repack_weights<<<(NLAYERS * 4 * 16384 + 255) / 256, 256, 0, stream>>>(ew1, ew2, cw1, wf_hi, wf_lo);
    prep_g<<<(NLAYERS * 4096 + NLAYERS * 128 + 255) / 256, 256, 0, stream>>>(eew, eeb, ew1, eb1, g_hi, g_lo, bias1c);
    temb_kernel<<<1, HDIM, 0, stream>>>(t, tw1, tb1, tw2, tb2, t_emb);
    hfeat_kernel<<<N_NODES, HDIM, 0, stream>>>(h, new_, neb, t_emb, h_feat, hbf_hi, hbf_lo);
    xinit_kernel<<<(N_NODES * 3 + 255) / 256, 256, 0, stream>>>(x, x_cur);

    hipMemsetAsync(deg, 0, (size_t)N_NODES * 4, stream);
    deg_kernel<<<(N_EDGES + 255) / 256, 256, 0, stream>>>(ei, deg);
    scan_kernel<<<1, 256, 0, stream>>>(deg, row_start, cursor);
    scatter_kernel<<<(N_EDGES + 255) / 256, 256, 0, stream>>>(ei, cursor, csr_eid);
    prep_edges<<<(N_EDGES + 255) / 256, 256, 0, stream>>>(ei, csr_eid, ea, rows_s, cols_s, eah, eal);

    for (int l = 0; l < NLAYERS; ++l) {
        hipMemsetAsync(agg_h, 0, (size_t)N_NODES * HDIM * 4, stream);
        hipMemsetAsync(agg_x, 0, (size_t)N_NODES * 3 * 4, stream);
        edge_mfma_kernel<<<N_EDGES / 32, 64, 0, stream>>>(
            rows_s, cols_s, eah, eal, x_cur, hbf_hi, hbf_lo, wf_hi, wf_lo, g_hi, g_lo, bias1c,
            eb2, cb1, cw2, l, agg_h, agg_x);
        node_kernel<<<N_NODES / 8, 128, 0, stream>>>(
            h_feat, x_cur, hbf_hi, hbf_lo, agg_h, agg_x, mask, nw1, nb1, nw2, nb2, l);
    }

    out_kernel<<<(N_NODES * 3 + 255) / 256, 256, 0, stream>>>(x_cur, x, mask, (float*)d_out);
}

// Round 12
// 1136.527 us; speedup vs baseline: 5.1108x; 1.0276x over previous
//
#include <hip/hip_runtime.h>
#include <hip/hip_bf16.h>

#define N_NODES 10000
#define N_EDGES 320000
#define HDIM 128
#define NODE_IN 64
#define EDGE_IN 16
#define NLAYERS 4
#define EPSV 1e-8f
#define SACT 136       // LDS activation row stride (elems)
#define INV4096 2.44140625e-4f

typedef unsigned short ushort_t;
typedef __attribute__((ext_vector_type(8))) short s8;        // 8 fp16 bit-pattern (4 VGPRs)
typedef __attribute__((ext_vector_type(8))) _Float16 h8;
typedef __attribute__((ext_vector_type(4))) float f4;

__device__ __forceinline__ float silu_f(float z) { return z / (1.0f + __expf(-z)); }

__device__ __forceinline__ f4 mfma16(s8 a, s8 b, f4 c) {
    return __builtin_amdgcn_mfma_f32_16x16x32_f16(
        __builtin_bit_cast(h8, a), __builtin_bit_cast(h8, b), c, 0, 0, 0);
}

// fp32 -> fp16 hi + (residual*4096) lo   (rep error ~2^-23 relative)
__device__ __forceinline__ void split_f16(float x, ushort_t& hi, ushort_t& lo) {
    _Float16 h = (_Float16)x;
    float hf = (float)h;
    _Float16 l = (_Float16)((x - hf) * 4096.0f);
    hi = __builtin_bit_cast(ushort_t, h);
    lo = __builtin_bit_cast(ushort_t, l);
}

// ============ CSR build ============
__global__ void deg_kernel(const int* __restrict__ ei, int* __restrict__ deg) {
    int e = blockIdx.x * 256 + threadIdx.x;
    if (e < N_EDGES) atomicAdd(&deg[ei[e]], 1);
}

__global__ void scan_kernel(const int* __restrict__ deg, int* __restrict__ row_start,
                            int* __restrict__ cursor) {
    __shared__ int s_part[256];
    const int CH = 40;   // 256*40 = 10240 >= N_NODES
    int t = threadIdx.x;
    int base = t * CH;
    int sum = 0;
    for (int i = 0; i < CH; ++i) { int n = base + i; if (n < N_NODES) sum += deg[n]; }
    s_part[t] = sum;
    __syncthreads();
    for (int d = 1; d < 256; d <<= 1) {
        int v = (t >= d) ? s_part[t - d] : 0;
        __syncthreads();
        s_part[t] += v;
        __syncthreads();
    }
    int off = s_part[t] - sum;
    for (int i = 0; i < CH; ++i) {
        int n = base + i;
        if (n < N_NODES) { row_start[n] = off; cursor[n] = off; off += deg[n]; }
    }
    if (t == 255) row_start[N_NODES] = s_part[255];
}

__global__ void scatter_kernel(const int* __restrict__ ei, int* __restrict__ cursor,
                               int* __restrict__ csr_eid) {
    int e = blockIdx.x * 256 + threadIdx.x;
    if (e < N_EDGES) {
        int r = ei[e];
        int pos = atomicAdd(&cursor[r], 1);
        csr_eid[pos] = e;
    }
}

// ============ one-time slot-order prepack: rows/cols + ea split fp16 ============
__global__ void prep_edges(const int* __restrict__ ei, const int* __restrict__ csr_eid,
                           const float* __restrict__ ea,
                           int* __restrict__ rows_s, int* __restrict__ cols_s,
                           ushort_t* __restrict__ eah, ushort_t* __restrict__ eal) {
    int slot = blockIdx.x * 256 + threadIdx.x;
    if (slot >= N_EDGES) return;
    int eid = csr_eid[slot];
    rows_s[slot] = ei[eid];
    cols_s[slot] = ei[N_EDGES + eid];
    const float* src = ea + (size_t)eid * EDGE_IN;
#pragma unroll
    for (int i = 0; i < EDGE_IN; ++i) {
        ushort_t hh, ll;
        split_f16(src[i], hh, ll);
        eah[(size_t)slot * EDGE_IN + i] = hh;
        eal[(size_t)slot * EDGE_IN + i] = ll;
    }
}

// ============ prep 1: repack W1a,W1b,W2,C1 into MFMA B-frag order, split fp16 hi/lo ============
__global__ void repack_weights(const float* __restrict__ ew1, const float* __restrict__ ew2,
                               const float* __restrict__ cw1,
                               ushort_t* __restrict__ wf_hi, ushort_t* __restrict__ wf_lo) {
    int gid = blockIdx.x * 256 + threadIdx.x;
    const int total = NLAYERS * 4 * 16384;
    if (gid >= total) return;
    int l   = gid / (4 * 16384);
    int rem = gid % (4 * 16384);
    int m4  = rem / 16384;
    int idx = rem & 16383;
    int b    = idx >> 9;
    int lane = (idx >> 3) & 63;
    int j    = idx & 7;
    int nt = b >> 2, kt = b & 3;
    int k = kt * 32 + ((lane >> 4) << 3) + j;
    int n = (nt << 4) + (lane & 15);
    float v;
    if (m4 == 0)      v = ew1[(size_t)l * 385 * 128 + (size_t)k * 128 + n];
    else if (m4 == 1) v = ew1[(size_t)l * 385 * 128 + (size_t)(128 + k) * 128 + n];
    else if (m4 == 2) v = ew2[(size_t)l * 16384 + k * 128 + n];
    else              v = cw1[(size_t)l * 16384 + k * 128 + n];
    split_f16(v, wf_hi[gid], wf_lo[gid]);
}

// ============ prep 2: G = eew @ W1c (K rows 0-15) + d2 weight row at k=16; frag-packed, split ============
__global__ void prep_g(const float* __restrict__ eew, const float* __restrict__ eeb,
                       const float* __restrict__ ew1, const float* __restrict__ eb1,
                       ushort_t* __restrict__ g_hi, ushort_t* __restrict__ g_lo,
                       float* __restrict__ bias1c) {
    int gid = blockIdx.x * 256 + threadIdx.x;
    const int T1 = NLAYERS * 4096;
    if (gid < T1) {
        int l = gid >> 12;
        int idx = gid & 4095;
        int nt = idx >> 9;
        int lane = (idx >> 3) & 63;
        int j = idx & 7;
        int q = lane >> 4;
        int n = (nt << 4) + (lane & 15);
        int k = q * 8 + j;
        float v = 0.f;
        if (k < EDGE_IN) {
            const float* w1c = ew1 + (size_t)l * 385 * 128 + (size_t)257 * 128;
            float acc = 0.f;
            for (int c = 0; c < HDIM; ++c) acc += eew[k * 128 + c] * w1c[(size_t)c * 128 + n];
            v = acc;
        } else if (k == EDGE_IN) {
            v = ew1[(size_t)l * 385 * 128 + (size_t)256 * 128 + n];   // d2 weight row
        }
        split_f16(v, g_hi[gid], g_lo[gid]);
    } else if (gid < T1 + NLAYERS * 128) {
        int r = gid - T1;
        int l = r >> 7;
        int n = r & 127;
        const float* w1c = ew1 + (size_t)l * 385 * 128 + (size_t)257 * 128;
        float acc = eb1[l * 128 + n];
        for (int c = 0; c < HDIM; ++c) acc += eeb[c] * w1c[(size_t)c * 128 + n];
        bias1c[r] = acc;
    }
}

// ============ t_emb ============
__global__ void temb_kernel(const float* t, const float* tw1, const float* tb1,
                            const float* tw2, const float* tb2, float* t_emb) {
    __shared__ float s_a[HDIM];
    int j = threadIdx.x;
    s_a[j] = silu_f(t[0] * tw1[j] + tb1[j]);
    __syncthreads();
    float acc = tb2[j];
    for (int k = 0; k < HDIM; ++k) acc += s_a[k] * tw2[k * HDIM + j];
    t_emb[j] = acc;
}

// ============ h_feat init (fp32 + split fp16 mirror) ============
__global__ void hfeat_kernel(const float* __restrict__ h, const float* __restrict__ new_,
                             const float* __restrict__ neb, const float* __restrict__ t_emb,
                             float* __restrict__ h_feat,
                             ushort_t* __restrict__ hbf_hi, ushort_t* __restrict__ hbf_lo) {
    __shared__ float s_h[NODE_IN];
    int n = blockIdx.x, j = threadIdx.x;
    if (j < NODE_IN) s_h[j] = h[(size_t)n * NODE_IN + j];
    __syncthreads();
    float acc = neb[j] + t_emb[j];
#pragma unroll 8
    for (int i = 0; i < NODE_IN; ++i) acc += s_h[i] * new_[i * HDIM + j];
    h_feat[(size_t)n * HDIM + j] = acc;
    split_f16(acc, hbf_hi[(size_t)n * HDIM + j], hbf_lo[(size_t)n * HDIM + j]);
}

__global__ void xinit_kernel(const float* x, float* x_cur) {
    int idx = blockIdx.x * blockDim.x + threadIdx.x;
    if (idx < N_NODES * 3) x_cur[idx] = x[idx];
}

// ============ MFMA edge kernel: 1 block = 1 wave = 32 CSR slots (2 M-tiles) ============
// GEMM1 split fp16x2 (aL split into two chains); GEMM2/GEMM3 hi-only.
// GEMM2 fuses m-store + segmented reduce per nt (no mv[2][8] live range).
__global__ __launch_bounds__(64, 2) void edge_mfma_kernel(
    const int* __restrict__ rows_s, const int* __restrict__ cols_s,
    const ushort_t* __restrict__ eah, const ushort_t* __restrict__ eal,
    const float* __restrict__ x_cur,
    const ushort_t* __restrict__ hbf_hi, const ushort_t* __restrict__ hbf_lo,
    const ushort_t* __restrict__ wf_hi, const ushort_t* __restrict__ wf_lo,
    const ushort_t* __restrict__ g_hi, const ushort_t* __restrict__ g_lo,
    const float* __restrict__ bias1c,
    const float* __restrict__ eb2, const float* __restrict__ cb1, const float* __restrict__ cw2,
    int layer, float* __restrict__ agg_h, float* __restrict__ agg_x)
{
    __shared__ __align__(16) ushort_t s_acth[32 * SACT];
    __shared__ float s_d2[32], s_dist[32], s_diff[32][3];
    __shared__ int s_row[32], s_col[32];
    __shared__ int s_drows[32];
    __shared__ int s_dcnt[1];

    const int lane = threadIdx.x;
    const int lo = lane & 15, q = lane >> 4;
    const int e0 = blockIdx.x * 32;

    const ushort_t* wAh  = wf_hi + (size_t)layer * 4 * 16384;
    const ushort_t* wAl  = wf_lo + (size_t)layer * 4 * 16384;
    const ushort_t* wBh  = wAh + 16384;
    const ushort_t* wBl  = wAl + 16384;
    const ushort_t* wW2h = wAh + 32768;
    const ushort_t* wC1h = wAh + 49152;
    const ushort_t* wgh  = g_hi + (size_t)layer * 4096;
    const ushort_t* wgl  = g_lo + (size_t)layer * 4096;
    const float* b1v = bias1c + layer * 128;
    const float* b2v = eb2 + layer * 128;
    const float* cbv = cb1 + layer * 128;
    const float* c2v = cw2 + layer * 128;

    // ---- phase 0: geometry for 32 slots (coalesced slot-order reads) ----
    if (lane < 32) {
        int slot = e0 + lane;
        int r = rows_s[slot], c = cols_s[slot];
        s_row[lane] = r; s_col[lane] = c;
        float dx = x_cur[r * 3 + 0] - x_cur[c * 3 + 0];
        float dy = x_cur[r * 3 + 1] - x_cur[c * 3 + 1];
        float dz = x_cur[r * 3 + 2] - x_cur[c * 3 + 2];
        float d2 = dx * dx + dy * dy + dz * dz;
        s_d2[lane] = d2;
        s_dist[lane] = sqrtf(d2 + EPSV);
        s_diff[lane][0] = dx; s_diff[lane][1] = dy; s_diff[lane][2] = dz;
    }
    __syncthreads();   // B1 (single-wave: cheap)

    // distinct-row list via ballot (CSR slots row-sorted)
    {
        bool head = false;
        if (lane < 32) {
            int r = s_row[lane];
            int prev = (lane == 0) ? -1 : s_row[lane - 1];
            head = (r != prev);
        }
        unsigned long long b = __ballot(head);
        if (head) {
            int idx = __popcll(b & ((1ull << lane) - 1ull));
            s_drows[idx] = s_row[lane];
        }
        if (lane == 0) s_dcnt[0] = __popcll(b);
    }

    // ---- A fragments for both tiles ----
    int erT[2], ecT[2];
#pragma unroll
    for (int t = 0; t < 2; ++t) { erT[t] = s_row[t * 16 + lo]; ecT[t] = s_col[t * 16 + lo]; }

    s8 aRh[2][4], aRl[2][4], aCh[2][4], aCl[2][4];
#pragma unroll
    for (int t = 0; t < 2; ++t)
#pragma unroll
        for (int kt = 0; kt < 4; ++kt) {
            size_t ro = (size_t)erT[t] * 128 + kt * 32 + q * 8;
            size_t co = (size_t)ecT[t] * 128 + kt * 32 + q * 8;
            aRh[t][kt] = *(const s8*)(hbf_hi + ro);
            aRl[t][kt] = *(const s8*)(hbf_lo + ro);
            aCh[t][kt] = *(const s8*)(hbf_hi + co);
            aCl[t][kt] = *(const s8*)(hbf_lo + co);
        }
    // ea (k=0..15, prepacked fp16 split, coalesced) + d2 (k=16, lanes q==2 slot j=0)
    s8 aEAh[2], aEAl[2];
#pragma unroll
    for (int t = 0; t < 2; ++t) {
        aEAh[t] = (s8){0,0,0,0,0,0,0,0};
        aEAl[t] = (s8){0,0,0,0,0,0,0,0};
        if (q < 2) {
            size_t off = (size_t)(e0 + t * 16 + lo) * EDGE_IN + q * 8;
            aEAh[t] = *(const s8*)(eah + off);
            aEAl[t] = *(const s8*)(eal + off);
        } else if (q == 2) {
            ushort_t hh, ll;
            split_f16(s_d2[t * 16 + lo], hh, ll);
            aEAh[t][0] = (short)hh; aEAl[t][0] = (short)ll;
        }
    }

    // ---- GEMM1 (split, dual lo-chains): y1 = silu(hR@W1a + hC@W1b + [ea|d2]@G + b1') ----
#pragma unroll
    for (int nt = 0; nt < 8; ++nt) {
        f4 aH[2], aL0[2], aL1[2];
#pragma unroll
        for (int t = 0; t < 2; ++t) {
            aH[t] = (f4){0.f,0.f,0.f,0.f};
            aL0[t] = (f4){0.f,0.f,0.f,0.f};
            aL1[t] = (f4){0.f,0.f,0.f,0.f};
        }
        {
            s8 bGh = *(const s8*)(wgh + ((size_t)nt * 64 + lane) * 8);
            s8 bGl = *(const s8*)(wgl + ((size_t)nt * 64 + lane) * 8);
#pragma unroll
            for (int t = 0; t < 2; ++t) {
                aH[t] = mfma16(aEAh[t], bGh, aH[t]);
                aL0[t] = mfma16(aEAh[t], bGl, aL0[t]);
                aL1[t] = mfma16(aEAl[t], bGh, aL1[t]);
            }
        }
#pragma unroll
        for (int kt = 0; kt < 4; ++kt) {
            size_t base = ((size_t)(nt * 4 + kt) * 64 + lane) * 8;
            s8 bh = *(const s8*)(wAh + base);
            s8 bl = *(const s8*)(wAl + base);
            s8 ch = *(const s8*)(wBh + base);
            s8 cl = *(const s8*)(wBl + base);
#pragma unroll
            for (int t = 0; t < 2; ++t) {
                aH[t] = mfma16(aRh[t][kt], bh, aH[t]);
                aL0[t] = mfma16(aRh[t][kt], bl, aL0[t]);
                aL0[t] = mfma16(aRl[t][kt], bh, aL0[t]);
                aH[t] = mfma16(aCh[t][kt], ch, aH[t]);
                aL1[t] = mfma16(aCh[t][kt], cl, aL1[t]);
                aL1[t] = mfma16(aCl[t][kt], ch, aL1[t]);
            }
        }
        float bb = b1v[nt * 16 + lo];
#pragma unroll
        for (int t = 0; t < 2; ++t)
#pragma unroll
            for (int r = 0; r < 4; ++r) {
                float v = silu_f(aH[t][r] + (aL0[t][r] + aL1[t][r]) * INV4096 + bb);
                int off = (t * 16 + q * 4 + r) * SACT + nt * 16 + lo;
                _Float16 hh = (_Float16)v;
                s_acth[off] = __builtin_bit_cast(ushort_t, hh);
            }
    }
    __syncthreads();   // B2

    // ---- GEMM2 (hi-only): m = silu(y1 @ W2 + b2), fused store + segmented reduce ----
    s8 aYh[2][4];
#pragma unroll
    for (int t = 0; t < 2; ++t)
#pragma unroll
        for (int kt = 0; kt < 4; ++kt) {
            int off = (t * 16 + lo) * SACT + kt * 32 + q * 8;
            aYh[t][kt] = *(const s8*)&s_acth[off];
        }
    __syncthreads();   // B3

    int rowm[2][4];
#pragma unroll
    for (int t = 0; t < 2; ++t)
#pragma unroll
        for (int r = 0; r < 4; ++r) rowm[t][r] = s_row[t * 16 + q * 4 + r];
    const int dcnt = s_dcnt[0];

#pragma unroll
    for (int nt = 0; nt < 8; ++nt) {
        f4 aH[2];
#pragma unroll
        for (int t = 0; t < 2; ++t) aH[t] = (f4){0.f,0.f,0.f,0.f};
#pragma unroll
        for (int kt = 0; kt < 4; ++kt) {
            size_t base = ((size_t)(nt * 4 + kt) * 64 + lane) * 8;
            s8 bh = *(const s8*)(wW2h + base);
#pragma unroll
            for (int t = 0; t < 2; ++t)
                aH[t] = mfma16(aYh[t][kt], bh, aH[t]);
        }
        float bb = b2v[nt * 16 + lo];
#pragma unroll
        for (int t = 0; t < 2; ++t) {
#pragma unroll
            for (int r = 0; r < 4; ++r) {
                aH[t][r] = silu_f(aH[t][r] + bb);
                int off = (t * 16 + q * 4 + r) * SACT + nt * 16 + lo;
                _Float16 hh = (_Float16)aH[t][r];
                s_acth[off] = __builtin_bit_cast(ushort_t, hh);
            }
        }
        // segmented reduce of this nt's m-slice -> atomics per distinct row
        for (int di = 0; di < dcnt; ++di) {
            int dr = s_drows[di];
            float v = 0.f;
#pragma unroll
            for (int t = 0; t < 2; ++t)
#pragma unroll
                for (int r = 0; r < 4; ++r) v += (rowm[t][r] == dr) ? aH[t][r] : 0.f;
            v += __shfl_xor(v, 16, 64);
            v += __shfl_xor(v, 32, 64);
            if (lane < 16) atomicAdd(&agg_h[(size_t)dr * HDIM + nt * 16 + lane], v);
        }
    }
    __syncthreads();   // B4

    // ---- GEMM3 (hi-only): c = silu(m @ C1 + cb) ; w = tanh(c . c2) ----
    s8 aMh[2][4];
#pragma unroll
    for (int t = 0; t < 2; ++t)
#pragma unroll
        for (int kt = 0; kt < 4; ++kt) {
            int off = (t * 16 + lo) * SACT + kt * 32 + q * 8;
            aMh[t][kt] = *(const s8*)&s_acth[off];
        }

    float wpart[2][4] = {{0.f,0.f,0.f,0.f},{0.f,0.f,0.f,0.f}};
#pragma unroll
    for (int nt = 0; nt < 8; ++nt) {
        f4 aH[2];
#pragma unroll
        for (int t = 0; t < 2; ++t) aH[t] = (f4){0.f,0.f,0.f,0.f};
#pragma unroll
        for (int kt = 0; kt < 4; ++kt) {
            size_t base = ((size_t)(nt * 4 + kt) * 64 + lane) * 8;
            s8 bh = *(const s8*)(wC1h + base);
#pragma unroll
            for (int t = 0; t < 2; ++t)
                aH[t] = mfma16(aMh[t][kt], bh, aH[t]);
        }
        float bb = cbv[nt * 16 + lo];
        float cc = c2v[nt * 16 + lo];
#pragma unroll
        for (int t = 0; t < 2; ++t)
#pragma unroll
            for (int r = 0; r < 4; ++r)
                wpart[t][r] += silu_f(aH[t][r] + bb) * cc;
    }
#pragma unroll
    for (int t = 0; t < 2; ++t)
#pragma unroll
        for (int r = 0; r < 4; ++r) {
#pragma unroll
            for (int mask = 1; mask < 16; mask <<= 1)
                wpart[t][r] += __shfl_xor(wpart[t][r], mask, 16);
        }
    // trans vector + segmented reduce -> agg_x atomics per distinct row
    {
        float val[2][4];
#pragma unroll
        for (int t = 0; t < 2; ++t)
#pragma unroll
            for (int r = 0; r < 4; ++r) {
                int mm = t * 16 + q * 4 + r;
                val[t][r] = (lo < 3)
                    ? s_diff[mm][lo] / (s_dist[mm] + EPSV) * tanhf(wpart[t][r])
                    : 0.f;
            }
        for (int di = 0; di < dcnt; ++di) {
            int dr = s_drows[di];
            float v = 0.f;
#pragma unroll
            for (int t = 0; t < 2; ++t)
#pragma unroll
                for (int r = 0; r < 4; ++r) v += (rowm[t][r] == dr) ? val[t][r] : 0.f;
            v += __shfl_xor(v, 16, 64);
            v += __shfl_xor(v, 32, 64);
            if (lane < 3) atomicAdd(&agg_x[dr * 3 + lane], v);
        }
    }
}

// ============ node kernel: 8 nodes/block, weights amortized ============
__global__ __launch_bounds__(128) void node_kernel(
    float* __restrict__ h_feat, float* __restrict__ x_cur,
    ushort_t* __restrict__ hbf_hi, ushort_t* __restrict__ hbf_lo,
    const float* __restrict__ agg_h, const float* __restrict__ agg_x,
    const float* __restrict__ mask,
    const float* __restrict__ n1p, const float* __restrict__ nb1p,
    const float* __restrict__ n2p, const float* __restrict__ nb2p, int layer) {
    __shared__ float s_cat[8][2 * HDIM];
    __shared__ float s_u[8][HDIM];
    int nb = blockIdx.x * 8, j = threadIdx.x;
    const size_t w1o = (size_t)layer * 2 * HDIM * HDIM;
    const size_t w2o = (size_t)layer * HDIM * HDIM;
    const size_t bo  = (size_t)layer * HDIM;

#pragma unroll
    for (int e = 0; e < 8; ++e) {
        s_cat[e][j] = h_feat[(size_t)(nb + e) * HDIM + j];
        s_cat[e][HDIM + j] = agg_h[(size_t)(nb + e) * HDIM + j];
    }
    __syncthreads();

    float u[8];
    float b1 = nb1p[bo + j];
#pragma unroll
    for (int e = 0; e < 8; ++e) u[e] = b1;
    for (int i0 = 0; i0 < 2 * HDIM; i0 += 2) {
        float w0 = n1p[w1o + (size_t)i0 * HDIM + j];
        float w1 = n1p[w1o + (size_t)(i0 + 1) * HDIM + j];
#pragma unroll
        for (int e = 0; e < 8; ++e)
            u[e] += s_cat[e][i0] * w0 + s_cat[e][i0 + 1] * w1;
    }
#pragma unroll
    for (int e = 0; e < 8; ++e) s_u[e][j] = silu_f(u[e]);
    __syncthreads();

    float acc[8];
    float b2 = nb2p[bo + j];
#pragma unroll
    for (int e = 0; e < 8; ++e) acc[e] = b2;
    for (int i0 = 0; i0 < HDIM; i0 += 2) {
        float w0 = n2p[w2o + (size_t)i0 * HDIM + j];
        float w1 = n2p[w2o + (size_t)(i0 + 1) * HDIM + j];
#pragma unroll
        for (int e = 0; e < 8; ++e)
            acc[e] += s_u[e][i0] * w0 + s_u[e][i0 + 1] * w1;
    }
#pragma unroll
    for (int e = 0; e < 8; ++e) {
        float nh = s_cat[e][j] + acc[e];
        h_feat[(size_t)(nb + e) * HDIM + j] = nh;
        split_f16(nh, hbf_hi[(size_t)(nb + e) * HDIM + j], hbf_lo[(size_t)(nb + e) * HDIM + j]);
    }
    if (j < 24) {
        int e = j / 3, c = j - e * 3;
        x_cur[(nb + e) * 3 + c] += agg_x[(nb + e) * 3 + c] * mask[nb + e];
    }
}

__global__ void out_kernel(const float* __restrict__ x_cur, const float* __restrict__ x_in,
                           const float* __restrict__ mask, float* __restrict__ out) {
    int idx = blockIdx.x * blockDim.x + threadIdx.x;
    if (idx < N_NODES * 3) {
        int n = idx / 3;
        out[idx] = (x_cur[idx] - x_in[idx]) * mask[n];
    }
}

extern "C" void kernel_launch(void* const* d_in, const int* in_sizes, int n_in,
                              void* d_out, int out_size, void* d_ws, size_t ws_size,
                              hipStream_t stream) {
    const float* h    = (const float*)d_in[0];
    const float* x    = (const float*)d_in[1];
    const int*   ei   = (const int*)d_in[2];
    const float* ea   = (const float*)d_in[3];
    const float* t    = (const float*)d_in[4];
    const float* mask = (const float*)d_in[5];
    const float* tw1  = (const float*)d_in[6];
    const float* tb1  = (const float*)d_in[7];
    const float* tw2  = (const float*)d_in[8];
    const float* tb2  = (const float*)d_in[9];
    const float* new_ = (const float*)d_in[10];
    const float* neb  = (const float*)d_in[11];
    const float* eew  = (const float*)d_in[12];
    const float* eeb  = (const float*)d_in[13];
    const float* ew1  = (const float*)d_in[14];
    const float* eb1  = (const float*)d_in[15];
    const float* ew2  = (const float*)d_in[16];
    const float* eb2  = (const float*)d_in[17];
    const float* cw1  = (const float*)d_in[18];
    const float* cb1  = (const float*)d_in[19];
    const float* cw2  = (const float*)d_in[20];
    const float* nw1  = (const float*)d_in[21];
    const float* nb1  = (const float*)d_in[22];
    const float* nw2  = (const float*)d_in[23];
    const float* nb2  = (const float*)d_in[24];

    // ---- workspace carve-out (256 B aligned) ----
    char* p = (char*)d_ws;
    auto alloc = [&](size_t bytes) -> char* {
        char* r = p;
        p += (bytes + 255) & ~(size_t)255;
        return r;
    };
    float* t_emb    = (float*)alloc(HDIM * 4);
    float* h_feat   = (float*)alloc((size_t)N_NODES * HDIM * 4);
    float* x_cur    = (float*)alloc((size_t)N_NODES * 3 * 4);
    float* agg_h    = (float*)alloc((size_t)N_NODES * HDIM * 4);
    float* agg_x    = (float*)alloc((size_t)N_NODES * 3 * 4);
    float* bias1c   = (float*)alloc(NLAYERS * HDIM * 4);
    ushort_t* hbf_hi = (ushort_t*)alloc((size_t)N_NODES * HDIM * 2);
    ushort_t* hbf_lo = (ushort_t*)alloc((size_t)N_NODES * HDIM * 2);
    ushort_t* wf_hi  = (ushort_t*)alloc((size_t)NLAYERS * 4 * 16384 * 2);
    ushort_t* wf_lo  = (ushort_t*)alloc((size_t)NLAYERS * 4 * 16384 * 2);
    ushort_t* g_hi   = (ushort_t*)alloc((size_t)NLAYERS * 4096 * 2);
    ushort_t* g_lo   = (ushort_t*)alloc((size_t)NLAYERS * 4096 * 2);
    int* deg        = (int*)alloc((size_t)N_NODES * 4);
    int* row_start  = (int*)alloc((size_t)(N_NODES + 1) * 4);
    int* cursor     = (int*)alloc((size_t)N_NODES * 4);
    int* csr_eid    = (int*)alloc((size_t)N_EDGES * 4);
    int* rows_s     = (int*)alloc((size_t)N_EDGES * 4);
    int* cols_s     = (int*)alloc((size_t)N_EDGES * 4);
    ushort_t* eah   = (ushort_t*)alloc((size_t)N_EDGES * EDGE_IN * 2);
    ushort_t* eal   = (ushort_t*)alloc((size_t)N_EDGES * EDGE_IN * 2);

    repack_weights<<<(NLAYERS * 4 * 16384 + 255) / 256, 256, 0, stream>>>(ew1, ew2, cw1, wf_hi, wf_lo);
    prep_g<<<(NLAYERS * 4096 + NLAYERS * 128 + 255) / 256, 256, 0, stream>>>(eew, eeb, ew1, eb1, g_hi, g_lo, bias1c);
    temb_kernel<<<1, HDIM, 0, stream>>>(t, tw1, tb1, tw2, tb2, t_emb);
    hfeat_kernel<<<N_NODES, HDIM, 0, stream>>>(h, new_, neb, t_emb, h_feat, hbf_hi, hbf_lo);
    xinit_kernel<<<(N_NODES * 3 + 255) / 256, 256, 0, stream>>>(x, x_cur);

    hipMemsetAsync(deg, 0, (size_t)N_NODES * 4, stream);
    deg_kernel<<<(N_EDGES + 255) / 256, 256, 0, stream>>>(ei, deg);
    scan_kernel<<<1, 256, 0, stream>>>(deg, row_start, cursor);
    scatter_kernel<<<(N_EDGES + 255) / 256, 256, 0, stream>>>(ei, cursor, csr_eid);
    prep_edges<<<(N_EDGES + 255) / 256, 256, 0, stream>>>(ei, csr_eid, ea, rows_s, cols_s, eah, eal);

    for (int l = 0; l < NLAYERS; ++l) {
        hipMemsetAsync(agg_h, 0, (size_t)N_NODES * HDIM * 4, stream);
        hipMemsetAsync(agg_x, 0, (size_t)N_NODES * 3 * 4, stream);
        edge_mfma_kernel<<<N_EDGES / 32, 64, 0, stream>>>(
            rows_s, cols_s, eah, eal, x_cur, hbf_hi, hbf_lo, wf_hi, wf_lo, g_hi, g_lo, bias1c,
            eb2, cb1, cw2, l, agg_h, agg_x);
        node_kernel<<<N_NODES / 8, 128, 0, stream>>>(
            h_feat, x_cur, hbf_hi, hbf_lo, agg_h, agg_x, mask, nw1, nb1, nw2, nb2, l);
    }

    out_kernel<<<(N_NODES * 3 + 255) / 256, 256, 0, stream>>>(x_cur, x, mask, (float*)d_out);
}

// Round 13
// 976.464 us; speedup vs baseline: 5.9485x; 1.1639x over previous
//
#include <hip/hip_runtime.h>
#include <hip/hip_bf16.h>

#define N_NODES 10000
#define N_EDGES 320000
#define HDIM 128
#define NODE_IN 64
#define EDGE_IN 16
#define NLAYERS 4
#define EPSV 1e-8f
#define SACT 136       // LDS activation row stride (elems)
#define INV4096 2.44140625e-4f

typedef unsigned short ushort_t;
typedef __attribute__((ext_vector_type(8))) short s8;        // 8 fp16 bit-pattern (4 VGPRs)
typedef __attribute__((ext_vector_type(8))) _Float16 h8;
typedef __attribute__((ext_vector_type(4))) float f4;

__device__ __forceinline__ float silu_f(float z) { return z / (1.0f + __expf(-z)); }
// tanh(x) = 1 - 2/(exp(2x)+1); exact limits at +-inf, ~1ulp of __expf otherwise
__device__ __forceinline__ float tanh_fast(float x) {
    float e = __expf(2.0f * x);
    return 1.0f - 2.0f / (e + 1.0f);
}

__device__ __forceinline__ f4 mfma16(s8 a, s8 b, f4 c) {
    return __builtin_amdgcn_mfma_f32_16x16x32_f16(
        __builtin_bit_cast(h8, a), __builtin_bit_cast(h8, b), c, 0, 0, 0);
}

// fp32 -> fp16 hi + (residual*4096) lo   (rep error ~2^-23 relative)
__device__ __forceinline__ void split_f16(float x, ushort_t& hi, ushort_t& lo) {
    _Float16 h = (_Float16)x;
    float hf = (float)h;
    _Float16 l = (_Float16)((x - hf) * 4096.0f);
    hi = __builtin_bit_cast(ushort_t, h);
    lo = __builtin_bit_cast(ushort_t, l);
}

// ============ CSR build ============
__global__ void deg_kernel(const int* __restrict__ ei, int* __restrict__ deg) {
    int e = blockIdx.x * 256 + threadIdx.x;
    if (e < N_EDGES) atomicAdd(&deg[ei[e]], 1);
}

__global__ void scan_kernel(const int* __restrict__ deg, int* __restrict__ row_start,
                            int* __restrict__ cursor) {
    __shared__ int s_part[256];
    const int CH = 40;   // 256*40 = 10240 >= N_NODES
    int t = threadIdx.x;
    int base = t * CH;
    int sum = 0;
    for (int i = 0; i < CH; ++i) { int n = base + i; if (n < N_NODES) sum += deg[n]; }
    s_part[t] = sum;
    __syncthreads();
    for (int d = 1; d < 256; d <<= 1) {
        int v = (t >= d) ? s_part[t - d] : 0;
        __syncthreads();
        s_part[t] += v;
        __syncthreads();
    }
    int off = s_part[t] - sum;
    for (int i = 0; i < CH; ++i) {
        int n = base + i;
        if (n < N_NODES) { row_start[n] = off; cursor[n] = off; off += deg[n]; }
    }
    if (t == 255) row_start[N_NODES] = s_part[255];
}

__global__ void scatter_kernel(const int* __restrict__ ei, int* __restrict__ cursor,
                               int* __restrict__ csr_eid) {
    int e = blockIdx.x * 256 + threadIdx.x;
    if (e < N_EDGES) {
        int r = ei[e];
        int pos = atomicAdd(&cursor[r], 1);
        csr_eid[pos] = e;
    }
}

// ============ one-time slot-order prepack: rows/cols + ea split fp16 ============
__global__ void prep_edges(const int* __restrict__ ei, const int* __restrict__ csr_eid,
                           const float* __restrict__ ea,
                           int* __restrict__ rows_s, int* __restrict__ cols_s,
                           ushort_t* __restrict__ eah, ushort_t* __restrict__ eal) {
    int slot = blockIdx.x * 256 + threadIdx.x;
    if (slot >= N_EDGES) return;
    int eid = csr_eid[slot];
    rows_s[slot] = ei[eid];
    cols_s[slot] = ei[N_EDGES + eid];
    const float* src = ea + (size_t)eid * EDGE_IN;
#pragma unroll
    for (int i = 0; i < EDGE_IN; ++i) {
        ushort_t hh, ll;
        split_f16(src[i], hh, ll);
        eah[(size_t)slot * EDGE_IN + i] = hh;
        eal[(size_t)slot * EDGE_IN + i] = ll;
    }
}

// ============ prep 1: repack W1a,W1b,W2,C1 into MFMA B-frag order, split fp16 hi/lo ============
__global__ void repack_weights(const float* __restrict__ ew1, const float* __restrict__ ew2,
                               const float* __restrict__ cw1,
                               ushort_t* __restrict__ wf_hi, ushort_t* __restrict__ wf_lo) {
    int gid = blockIdx.x * 256 + threadIdx.x;
    const int total = NLAYERS * 4 * 16384;
    if (gid >= total) return;
    int l   = gid / (4 * 16384);
    int rem = gid % (4 * 16384);
    int m4  = rem / 16384;
    int idx = rem & 16383;
    int b    = idx >> 9;
    int lane = (idx >> 3) & 63;
    int j    = idx & 7;
    int nt = b >> 2, kt = b & 3;
    int k = kt * 32 + ((lane >> 4) << 3) + j;
    int n = (nt << 4) + (lane & 15);
    float v;
    if (m4 == 0)      v = ew1[(size_t)l * 385 * 128 + (size_t)k * 128 + n];
    else if (m4 == 1) v = ew1[(size_t)l * 385 * 128 + (size_t)(128 + k) * 128 + n];
    else if (m4 == 2) v = ew2[(size_t)l * 16384 + k * 128 + n];
    else              v = cw1[(size_t)l * 16384 + k * 128 + n];
    split_f16(v, wf_hi[gid], wf_lo[gid]);
}

// ============ prep 2: G = eew @ W1c (K rows 0-15) + d2 weight row at k=16; frag-packed, split ============
__global__ void prep_g(const float* __restrict__ eew, const float* __restrict__ eeb,
                       const float* __restrict__ ew1, const float* __restrict__ eb1,
                       ushort_t* __restrict__ g_hi, ushort_t* __restrict__ g_lo,
                       float* __restrict__ bias1c) {
    int gid = blockIdx.x * 256 + threadIdx.x;
    const int T1 = NLAYERS * 4096;
    if (gid < T1) {
        int l = gid >> 12;
        int idx = gid & 4095;
        int nt = idx >> 9;
        int lane = (idx >> 3) & 63;
        int j = idx & 7;
        int q = lane >> 4;
        int n = (nt << 4) + (lane & 15);
        int k = q * 8 + j;
        float v = 0.f;
        if (k < EDGE_IN) {
            const float* w1c = ew1 + (size_t)l * 385 * 128 + (size_t)257 * 128;
            float acc = 0.f;
            for (int c = 0; c < HDIM; ++c) acc += eew[k * 128 + c] * w1c[(size_t)c * 128 + n];
            v = acc;
        } else if (k == EDGE_IN) {
            v = ew1[(size_t)l * 385 * 128 + (size_t)256 * 128 + n];   // d2 weight row
        }
        split_f16(v, g_hi[gid], g_lo[gid]);
    } else if (gid < T1 + NLAYERS * 128) {
        int r = gid - T1;
        int l = r >> 7;
        int n = r & 127;
        const float* w1c = ew1 + (size_t)l * 385 * 128 + (size_t)257 * 128;
        float acc = eb1[l * 128 + n];
        for (int c = 0; c < HDIM; ++c) acc += eeb[c] * w1c[(size_t)c * 128 + n];
        bias1c[r] = acc;
    }
}

// ============ t_emb ============
__global__ void temb_kernel(const float* t, const float* tw1, const float* tb1,
                            const float* tw2, const float* tb2, float* t_emb) {
    __shared__ float s_a[HDIM];
    int j = threadIdx.x;
    s_a[j] = silu_f(t[0] * tw1[j] + tb1[j]);
    __syncthreads();
    float acc = tb2[j];
    for (int k = 0; k < HDIM; ++k) acc += s_a[k] * tw2[k * HDIM + j];
    t_emb[j] = acc;
}

// ============ h_feat init (fp32 + split fp16 mirror) ============
__global__ void hfeat_kernel(const float* __restrict__ h, const float* __restrict__ new_,
                             const float* __restrict__ neb, const float* __restrict__ t_emb,
                             float* __restrict__ h_feat,
                             ushort_t* __restrict__ hbf_hi, ushort_t* __restrict__ hbf_lo) {
    __shared__ float s_h[NODE_IN];
    int n = blockIdx.x, j = threadIdx.x;
    if (j < NODE_IN) s_h[j] = h[(size_t)n * NODE_IN + j];
    __syncthreads();
    float acc = neb[j] + t_emb[j];
#pragma unroll 8
    for (int i = 0; i < NODE_IN; ++i) acc += s_h[i] * new_[i * HDIM + j];
    h_feat[(size_t)n * HDIM + j] = acc;
    split_f16(acc, hbf_hi[(size_t)n * HDIM + j], hbf_lo[(size_t)n * HDIM + j]);
}

__global__ void xinit_kernel(const float* x, float* x_cur) {
    int idx = blockIdx.x * blockDim.x + threadIdx.x;
    if (idx < N_NODES * 3) x_cur[idx] = x[idx];
}

// ============ MFMA edge kernel: 1 block = 1 wave = 32 CSR slots (2 M-tiles) ============
// GEMM1: hi + single lo chain (h_row + ea/d2 corrections; h_col hi-only).
// GEMM2/GEMM3 hi-only. GEMM2 fuses m-store + segmented reduce per nt.
__global__ __launch_bounds__(64, 2) void edge_mfma_kernel(
    const int* __restrict__ rows_s, const int* __restrict__ cols_s,
    const ushort_t* __restrict__ eah, const ushort_t* __restrict__ eal,
    const float* __restrict__ x_cur,
    const ushort_t* __restrict__ hbf_hi, const ushort_t* __restrict__ hbf_lo,
    const ushort_t* __restrict__ wf_hi, const ushort_t* __restrict__ wf_lo,
    const ushort_t* __restrict__ g_hi, const ushort_t* __restrict__ g_lo,
    const float* __restrict__ bias1c,
    const float* __restrict__ eb2, const float* __restrict__ cb1, const float* __restrict__ cw2,
    int layer, float* __restrict__ agg_h, float* __restrict__ agg_x)
{
    __shared__ __align__(16) ushort_t s_acth[32 * SACT];
    __shared__ float s_d2[32], s_dist[32], s_diff[32][3];
    __shared__ int s_row[32], s_col[32];
    __shared__ int s_drows[32];
    __shared__ int s_dcnt[1];

    const int lane = threadIdx.x;
    const int lo = lane & 15, q = lane >> 4;
    const int e0 = blockIdx.x * 32;

    const ushort_t* wAh  = wf_hi + (size_t)layer * 4 * 16384;
    const ushort_t* wAl  = wf_lo + (size_t)layer * 4 * 16384;
    const ushort_t* wBh  = wAh + 16384;
    const ushort_t* wW2h = wAh + 32768;
    const ushort_t* wC1h = wAh + 49152;
    const ushort_t* wgh  = g_hi + (size_t)layer * 4096;
    const ushort_t* wgl  = g_lo + (size_t)layer * 4096;
    const float* b1v = bias1c + layer * 128;
    const float* b2v = eb2 + layer * 128;
    const float* cbv = cb1 + layer * 128;
    const float* c2v = cw2 + layer * 128;

    // ---- phase 0: geometry for 32 slots (coalesced slot-order reads) ----
    if (lane < 32) {
        int slot = e0 + lane;
        int r = rows_s[slot], c = cols_s[slot];
        s_row[lane] = r; s_col[lane] = c;
        float dx = x_cur[r * 3 + 0] - x_cur[c * 3 + 0];
        float dy = x_cur[r * 3 + 1] - x_cur[c * 3 + 1];
        float dz = x_cur[r * 3 + 2] - x_cur[c * 3 + 2];
        float d2 = dx * dx + dy * dy + dz * dz;
        s_d2[lane] = d2;
        s_dist[lane] = sqrtf(d2 + EPSV);
        s_diff[lane][0] = dx; s_diff[lane][1] = dy; s_diff[lane][2] = dz;
    }
    __syncthreads();   // B1 (single-wave: cheap)

    // distinct-row list via ballot (CSR slots row-sorted)
    {
        bool head = false;
        if (lane < 32) {
            int r = s_row[lane];
            int prev = (lane == 0) ? -1 : s_row[lane - 1];
            head = (r != prev);
        }
        unsigned long long b = __ballot(head);
        if (head) {
            int idx = __popcll(b & ((1ull << lane) - 1ull));
            s_drows[idx] = s_row[lane];
        }
        if (lane == 0) s_dcnt[0] = __popcll(b);
    }

    // ---- A fragments for both tiles ----
    int erT[2], ecT[2];
#pragma unroll
    for (int t = 0; t < 2; ++t) { erT[t] = s_row[t * 16 + lo]; ecT[t] = s_col[t * 16 + lo]; }

    s8 aRh[2][4], aRl[2][4], aCh[2][4];
#pragma unroll
    for (int t = 0; t < 2; ++t)
#pragma unroll
        for (int kt = 0; kt < 4; ++kt) {
            size_t ro = (size_t)erT[t] * 128 + kt * 32 + q * 8;
            size_t co = (size_t)ecT[t] * 128 + kt * 32 + q * 8;
            aRh[t][kt] = *(const s8*)(hbf_hi + ro);
            aRl[t][kt] = *(const s8*)(hbf_lo + ro);
            aCh[t][kt] = *(const s8*)(hbf_hi + co);
        }
    // ea (k=0..15, prepacked fp16 split, coalesced) + d2 (k=16, lanes q==2 slot j=0)
    s8 aEAh[2], aEAl[2];
#pragma unroll
    for (int t = 0; t < 2; ++t) {
        aEAh[t] = (s8){0,0,0,0,0,0,0,0};
        aEAl[t] = (s8){0,0,0,0,0,0,0,0};
        if (q < 2) {
            size_t off = (size_t)(e0 + t * 16 + lo) * EDGE_IN + q * 8;
            aEAh[t] = *(const s8*)(eah + off);
            aEAl[t] = *(const s8*)(eal + off);
        } else if (q == 2) {
            ushort_t hh, ll;
            split_f16(s_d2[t * 16 + lo], hh, ll);
            aEAh[t][0] = (short)hh; aEAl[t][0] = (short)ll;
        }
    }

    // ---- GEMM1: y1 = silu(hR@W1a + hC@W1b + [ea|d2]@G + b1')
    //      hi everywhere + lo corrections for hR and ea/d2 (hC hi-only) ----
#pragma unroll
    for (int nt = 0; nt < 8; ++nt) {
        f4 aH[2], aL0[2];
#pragma unroll
        for (int t = 0; t < 2; ++t) {
            aH[t] = (f4){0.f,0.f,0.f,0.f};
            aL0[t] = (f4){0.f,0.f,0.f,0.f};
        }
        {
            s8 bGh = *(const s8*)(wgh + ((size_t)nt * 64 + lane) * 8);
            s8 bGl = *(const s8*)(wgl + ((size_t)nt * 64 + lane) * 8);
#pragma unroll
            for (int t = 0; t < 2; ++t) {
                aH[t] = mfma16(aEAh[t], bGh, aH[t]);
                aL0[t] = mfma16(aEAh[t], bGl, aL0[t]);
                aL0[t] = mfma16(aEAl[t], bGh, aL0[t]);
            }
        }
#pragma unroll
        for (int kt = 0; kt < 4; ++kt) {
            size_t base = ((size_t)(nt * 4 + kt) * 64 + lane) * 8;
            s8 bh = *(const s8*)(wAh + base);
            s8 bl = *(const s8*)(wAl + base);
            s8 ch = *(const s8*)(wBh + base);
#pragma unroll
            for (int t = 0; t < 2; ++t) {
                aH[t] = mfma16(aRh[t][kt], bh, aH[t]);
                aL0[t] = mfma16(aRh[t][kt], bl, aL0[t]);
                aL0[t] = mfma16(aRl[t][kt], bh, aL0[t]);
                aH[t] = mfma16(aCh[t][kt], ch, aH[t]);
            }
        }
        float bb = b1v[nt * 16 + lo];
#pragma unroll
        for (int t = 0; t < 2; ++t)
#pragma unroll
            for (int r = 0; r < 4; ++r) {
                float v = silu_f(aH[t][r] + aL0[t][r] * INV4096 + bb);
                int off = (t * 16 + q * 4 + r) * SACT + nt * 16 + lo;
                _Float16 hh = (_Float16)v;
                s_acth[off] = __builtin_bit_cast(ushort_t, hh);
            }
    }
    __syncthreads();   // B2

    // ---- GEMM2 (hi-only): m = silu(y1 @ W2 + b2), fused store + segmented reduce ----
    s8 aYh[2][4];
#pragma unroll
    for (int t = 0; t < 2; ++t)
#pragma unroll
        for (int kt = 0; kt < 4; ++kt) {
            int off = (t * 16 + lo) * SACT + kt * 32 + q * 8;
            aYh[t][kt] = *(const s8*)&s_acth[off];
        }
    __syncthreads();   // B3

    int rowm[2][4];
#pragma unroll
    for (int t = 0; t < 2; ++t)
#pragma unroll
        for (int r = 0; r < 4; ++r) rowm[t][r] = s_row[t * 16 + q * 4 + r];
    const int dcnt = s_dcnt[0];

#pragma unroll
    for (int nt = 0; nt < 8; ++nt) {
        f4 aH[2];
#pragma unroll
        for (int t = 0; t < 2; ++t) aH[t] = (f4){0.f,0.f,0.f,0.f};
#pragma unroll
        for (int kt = 0; kt < 4; ++kt) {
            size_t base = ((size_t)(nt * 4 + kt) * 64 + lane) * 8;
            s8 bh = *(const s8*)(wW2h + base);
#pragma unroll
            for (int t = 0; t < 2; ++t)
                aH[t] = mfma16(aYh[t][kt], bh, aH[t]);
        }
        float bb = b2v[nt * 16 + lo];
#pragma unroll
        for (int t = 0; t < 2; ++t) {
#pragma unroll
            for (int r = 0; r < 4; ++r) {
                aH[t][r] = silu_f(aH[t][r] + bb);
                int off = (t * 16 + q * 4 + r) * SACT + nt * 16 + lo;
                _Float16 hh = (_Float16)aH[t][r];
                s_acth[off] = __builtin_bit_cast(ushort_t, hh);
            }
        }
        // segmented reduce of this nt's m-slice -> atomics per distinct row
        for (int di = 0; di < dcnt; ++di) {
            int dr = s_drows[di];
            float v = 0.f;
#pragma unroll
            for (int t = 0; t < 2; ++t)
#pragma unroll
                for (int r = 0; r < 4; ++r) v += (rowm[t][r] == dr) ? aH[t][r] : 0.f;
            v += __shfl_xor(v, 16, 64);
            v += __shfl_xor(v, 32, 64);
            if (lane < 16) atomicAdd(&agg_h[(size_t)dr * HDIM + nt * 16 + lane], v);
        }
    }
    __syncthreads();   // B4

    // ---- GEMM3 (hi-only): c = silu(m @ C1 + cb) ; w = tanh(c . c2) ----
    s8 aMh[2][4];
#pragma unroll
    for (int t = 0; t < 2; ++t)
#pragma unroll
        for (int kt = 0; kt < 4; ++kt) {
            int off = (t * 16 + lo) * SACT + kt * 32 + q * 8;
            aMh[t][kt] = *(const s8*)&s_acth[off];
        }

    float wpart[2][4] = {{0.f,0.f,0.f,0.f},{0.f,0.f,0.f,0.f}};
#pragma unroll
    for (int nt = 0; nt < 8; ++nt) {
        f4 aH[2];
#pragma unroll
        for (int t = 0; t < 2; ++t) aH[t] = (f4){0.f,0.f,0.f,0.f};
#pragma unroll
        for (int kt = 0; kt < 4; ++kt) {
            size_t base = ((size_t)(nt * 4 + kt) * 64 + lane) * 8;
            s8 bh = *(const s8*)(wC1h + base);
#pragma unroll
            for (int t = 0; t < 2; ++t)
                aH[t] = mfma16(aMh[t][kt], bh, aH[t]);
        }
        float bb = cbv[nt * 16 + lo];
        float cc = c2v[nt * 16 + lo];
#pragma unroll
        for (int t = 0; t < 2; ++t)
#pragma unroll
            for (int r = 0; r < 4; ++r)
                wpart[t][r] += silu_f(aH[t][r] + bb) * cc;
    }
#pragma unroll
    for (int t = 0; t < 2; ++t)
#pragma unroll
        for (int r = 0; r < 4; ++r) {
#pragma unroll
            for (int mask = 1; mask < 16; mask <<= 1)
                wpart[t][r] += __shfl_xor(wpart[t][r], mask, 16);
        }
    // trans vector + segmented reduce -> agg_x atomics per distinct row
    {
        float val[2][4];
#pragma unroll
        for (int t = 0; t < 2; ++t)
#pragma unroll
            for (int r = 0; r < 4; ++r) {
                int mm = t * 16 + q * 4 + r;
                val[t][r] = (lo < 3)
                    ? s_diff[mm][lo] / (s_dist[mm] + EPSV) * tanh_fast(wpart[t][r])
                    : 0.f;
            }
        for (int di = 0; di < dcnt; ++di) {
            int dr = s_drows[di];
            float v = 0.f;
#pragma unroll
            for (int t = 0; t < 2; ++t)
#pragma unroll
                for (int r = 0; r < 4; ++r) v += (rowm[t][r] == dr) ? val[t][r] : 0.f;
            v += __shfl_xor(v, 16, 64);
            v += __shfl_xor(v, 32, 64);
            if (lane < 3) atomicAdd(&agg_x[dr * 3 + lane], v);
        }
    }
}

// ============ node kernel: 8 nodes/block, weights amortized ============
__global__ __launch_bounds__(128) void node_kernel(
    float* __restrict__ h_feat, float* __restrict__ x_cur,
    ushort_t* __restrict__ hbf_hi, ushort_t* __restrict__ hbf_lo,
    const float* __restrict__ agg_h, const float* __restrict__ agg_x,
    const float* __restrict__ mask,
    const float* __restrict__ n1p, const float* __restrict__ nb1p,
    const float* __restrict__ n2p, const float* __restrict__ nb2p, int layer) {
    __shared__ float s_cat[8][2 * HDIM];
    __shared__ float s_u[8][HDIM];
    int nb = blockIdx.x * 8, j = threadIdx.x;
    const size_t w1o = (size_t)layer * 2 * HDIM * HDIM;
    const size_t w2o = (size_t)layer * HDIM * HDIM;
    const size_t bo  = (size_t)layer * HDIM;

#pragma unroll
    for (int e = 0; e < 8; ++e) {
        s_cat[e][j] = h_feat[(size_t)(nb + e) * HDIM + j];
        s_cat[e][HDIM + j] = agg_h[(size_t)(nb + e) * HDIM + j];
    }
    __syncthreads();

    float u[8];
    float b1 = nb1p[bo + j];
#pragma unroll
    for (int e = 0; e < 8; ++e) u[e] = b1;
    for (int i0 = 0; i0 < 2 * HDIM; i0 += 2) {
        float w0 = n1p[w1o + (size_t)i0 * HDIM + j];
        float w1 = n1p[w1o + (size_t)(i0 + 1) * HDIM + j];
#pragma unroll
        for (int e = 0; e < 8; ++e)
            u[e] += s_cat[e][i0] * w0 + s_cat[e][i0 + 1] * w1;
    }
#pragma unroll
    for (int e = 0; e < 8; ++e) s_u[e][j] = silu_f(u[e]);
    __syncthreads();

    float acc[8];
    float b2 = nb2p[bo + j];
#pragma unroll
    for (int e = 0; e < 8; ++e) acc[e] = b2;
    for (int i0 = 0; i0 < HDIM; i0 += 2) {
        float w0 = n2p[w2o + (size_t)i0 * HDIM + j];
        float w1 = n2p[w2o + (size_t)(i0 + 1) * HDIM + j];
#pragma unroll
        for (int e = 0; e < 8; ++e)
            acc[e] += s_u[e][i0] * w0 + s_u[e][i0 + 1] * w1;
    }
#pragma unroll
    for (int e = 0; e < 8; ++e) {
        float nh = s_cat[e][j] + acc[e];
        h_feat[(size_t)(nb + e) * HDIM + j] = nh;
        split_f16(nh, hbf_hi[(size_t)(nb + e) * HDIM + j], hbf_lo[(size_t)(nb + e) * HDIM + j]);
    }
    if (j < 24) {
        int e = j / 3, c = j - e * 3;
        x_cur[(nb + e) * 3 + c] += agg_x[(nb + e) * 3 + c] * mask[nb + e];
    }
}

__global__ void out_kernel(const float* __restrict__ x_cur, const float* __restrict__ x_in,
                           const float* __restrict__ mask, float* __restrict__ out) {
    int idx = blockIdx.x * blockDim.x + threadIdx.x;
    if (idx < N_NODES * 3) {
        int n = idx / 3;
        out[idx] = (x_cur[idx] - x_in[idx]) * mask[n];
    }
}

extern "C" void kernel_launch(void* const* d_in, const int* in_sizes, int n_in,
                              void* d_out, int out_size, void* d_ws, size_t ws_size,
                              hipStream_t stream) {
    const float* h    = (const float*)d_in[0];
    const float* x    = (const float*)d_in[1];
    const int*   ei   = (const int*)d_in[2];
    const float* ea   = (const float*)d_in[3];
    const float* t    = (const float*)d_in[4];
    const float* mask = (const float*)d_in[5];
    const float* tw1  = (const float*)d_in[6];
    const float* tb1  = (const float*)d_in[7];
    const float* tw2  = (const float*)d_in[8];
    const float* tb2  = (const float*)d_in[9];
    const float* new_ = (const float*)d_in[10];
    const float* neb  = (const float*)d_in[11];
    const float* eew  = (const float*)d_in[12];
    const float* eeb  = (const float*)d_in[13];
    const float* ew1  = (const float*)d_in[14];
    const float* eb1  = (const float*)d_in[15];
    const float* ew2  = (const float*)d_in[16];
    const float* eb2  = (const float*)d_in[17];
    const float* cw1  = (const float*)d_in[18];
    const float* cb1  = (const float*)d_in[19];
    const float* cw2  = (const float*)d_in[20];
    const float* nw1  = (const float*)d_in[21];
    const float* nb1  = (const float*)d_in[22];
    const float* nw2  = (const float*)d_in[23];
    const float* nb2  = (const float*)d_in[24];

    // ---- workspace carve-out (256 B aligned) ----
    char* p = (char*)d_ws;
    auto alloc = [&](size_t bytes) -> char* {
        char* r = p;
        p += (bytes + 255) & ~(size_t)255;
        return r;
    };
    float* t_emb    = (float*)alloc(HDIM * 4);
    float* h_feat   = (float*)alloc((size_t)N_NODES * HDIM * 4);
    float* x_cur    = (float*)alloc((size_t)N_NODES * 3 * 4);
    float* agg_h    = (float*)alloc((size_t)N_NODES * HDIM * 4);
    float* agg_x    = (float*)alloc((size_t)N_NODES * 3 * 4);
    float* bias1c   = (float*)alloc(NLAYERS * HDIM * 4);
    ushort_t* hbf_hi = (ushort_t*)alloc((size_t)N_NODES * HDIM * 2);
    ushort_t* hbf_lo = (ushort_t*)alloc((size_t)N_NODES * HDIM * 2);
    ushort_t* wf_hi  = (ushort_t*)alloc((size_t)NLAYERS * 4 * 16384 * 2);
    ushort_t* wf_lo  = (ushort_t*)alloc((size_t)NLAYERS * 4 * 16384 * 2);
    ushort_t* g_hi   = (ushort_t*)alloc((size_t)NLAYERS * 4096 * 2);
    ushort_t* g_lo   = (ushort_t*)alloc((size_t)NLAYERS * 4096 * 2);
    int* deg        = (int*)alloc((size_t)N_NODES * 4);
    int* row_start  = (int*)alloc((size_t)(N_NODES + 1) * 4);
    int* cursor     = (int*)alloc((size_t)N_NODES * 4);
    int* csr_eid    = (int*)alloc((size_t)N_EDGES * 4);
    int* rows_s     = (int*)alloc((size_t)N_EDGES * 4);
    int* cols_s     = (int*)alloc((size_t)N_EDGES * 4);
    ushort_t* eah   = (ushort_t*)alloc((size_t)N_EDGES * EDGE_IN * 2);
    ushort_t* eal   = (ushort_t*)alloc((size_t)N_EDGES * EDGE_IN * 2);

    // single memset spans agg_h..agg_x (adjacent allocations; ends before bias1c)
    size_t agg_span = (size_t)((char*)(agg_x + (size_t)N_NODES * 3) - (char*)agg_h);

    repack_weights<<<(NLAYERS * 4 * 16384 + 255) / 256, 256, 0, stream>>>(ew1, ew2, cw1, wf_hi, wf_lo);
    prep_g<<<(NLAYERS * 4096 + NLAYERS * 128 + 255) / 256, 256, 0, stream>>>(eew, eeb, ew1, eb1, g_hi, g_lo, bias1c);
    temb_kernel<<<1, HDIM, 0, stream>>>(t, tw1, tb1, tw2, tb2, t_emb);
    hfeat_kernel<<<N_NODES, HDIM, 0, stream>>>(h, new_, neb, t_emb, h_feat, hbf_hi, hbf_lo);
    xinit_kernel<<<(N_NODES * 3 + 255) / 256, 256, 0, stream>>>(x, x_cur);

    hipMemsetAsync(deg, 0, (size_t)N_NODES * 4, stream);
    deg_kernel<<<(N_EDGES + 255) / 256, 256, 0, stream>>>(ei, deg);
    scan_kernel<<<1, 256, 0, stream>>>(deg, row_start, cursor);
    scatter_kernel<<<(N_EDGES + 255) / 256, 256, 0, stream>>>(ei, cursor, csr_eid);
    prep_edges<<<(N_EDGES + 255) / 256, 256, 0, stream>>>(ei, csr_eid, ea, rows_s, cols_s, eah, eal);

    for (int l = 0; l < NLAYERS; ++l) {
        hipMemsetAsync(agg_h, 0, agg_span, stream);
        edge_mfma_kernel<<<N_EDGES / 32, 64, 0, stream>>>(
            rows_s, cols_s, eah, eal, x_cur, hbf_hi, hbf_lo, wf_hi, wf_lo, g_hi, g_lo, bias1c,
            eb2, cb1, cw2, l, agg_h, agg_x);
        node_kernel<<<N_NODES / 8, 128, 0, stream>>>(
            h_feat, x_cur, hbf_hi, hbf_lo, agg_h, agg_x, mask, nw1, nb1, nw2, nb2, l);
    }

    out_kernel<<<(N_NODES * 3 + 255) / 256, 256, 0, stream>>>(x_cur, x, mask, (float*)d_out);
}

// Round 14
// 917.356 us; speedup vs baseline: 6.3318x; 1.0644x over previous
//
#include <hip/hip_runtime.h>
#include <hip/hip_bf16.h>

#define N_NODES 10000
#define N_EDGES 320000
#define HDIM 128
#define NODE_IN 64
#define EDGE_IN 16
#define NLAYERS 4
#define EPSV 1e-8f
#define SACT 136       // LDS activation row stride (elems)
#define INV4096 2.44140625e-4f

typedef unsigned short ushort_t;
typedef __attribute__((ext_vector_type(8))) short s8;        // 8 fp16 bit-pattern (4 VGPRs)
typedef __attribute__((ext_vector_type(8))) _Float16 h8;
typedef __attribute__((ext_vector_type(4))) float f4;

// silu via v_rcp_f32 (1 ulp) instead of IEEE divide (~10 instr)
__device__ __forceinline__ float silu_f(float z) {
    return z * __builtin_amdgcn_rcpf(1.0f + __expf(-z));
}
// tanh(x) = 1 - 2*rcp(exp(2x)+1); exact limits at +-inf
__device__ __forceinline__ float tanh_fast(float x) {
    float e = __expf(2.0f * x);
    return 1.0f - 2.0f * __builtin_amdgcn_rcpf(e + 1.0f);
}

__device__ __forceinline__ f4 mfma16(s8 a, s8 b, f4 c) {
    return __builtin_amdgcn_mfma_f32_16x16x32_f16(
        __builtin_bit_cast(h8, a), __builtin_bit_cast(h8, b), c, 0, 0, 0);
}

// fp32 -> fp16 hi + (residual*4096) lo   (rep error ~2^-23 relative)
__device__ __forceinline__ void split_f16(float x, ushort_t& hi, ushort_t& lo) {
    _Float16 h = (_Float16)x;
    float hf = (float)h;
    _Float16 l = (_Float16)((x - hf) * 4096.0f);
    hi = __builtin_bit_cast(ushort_t, h);
    lo = __builtin_bit_cast(ushort_t, l);
}

// ============ CSR build ============
__global__ void deg_kernel(const int* __restrict__ ei, int* __restrict__ deg) {
    int e = blockIdx.x * 256 + threadIdx.x;
    if (e < N_EDGES) atomicAdd(&deg[ei[e]], 1);
}

__global__ void scan_kernel(const int* __restrict__ deg, int* __restrict__ row_start,
                            int* __restrict__ cursor) {
    __shared__ int s_part[256];
    const int CH = 40;   // 256*40 = 10240 >= N_NODES
    int t = threadIdx.x;
    int base = t * CH;
    int sum = 0;
    for (int i = 0; i < CH; ++i) { int n = base + i; if (n < N_NODES) sum += deg[n]; }
    s_part[t] = sum;
    __syncthreads();
    for (int d = 1; d < 256; d <<= 1) {
        int v = (t >= d) ? s_part[t - d] : 0;
        __syncthreads();
        s_part[t] += v;
        __syncthreads();
    }
    int off = s_part[t] - sum;
    for (int i = 0; i < CH; ++i) {
        int n = base + i;
        if (n < N_NODES) { row_start[n] = off; cursor[n] = off; off += deg[n]; }
    }
    if (t == 255) row_start[N_NODES] = s_part[255];
}

__global__ void scatter_kernel(const int* __restrict__ ei, int* __restrict__ cursor,
                               int* __restrict__ csr_eid) {
    int e = blockIdx.x * 256 + threadIdx.x;
    if (e < N_EDGES) {
        int r = ei[e];
        int pos = atomicAdd(&cursor[r], 1);
        csr_eid[pos] = e;
    }
}

// ============ one-time slot-order prepack: rows/cols + ea split fp16 ============
__global__ void prep_edges(const int* __restrict__ ei, const int* __restrict__ csr_eid,
                           const float* __restrict__ ea,
                           int* __restrict__ rows_s, int* __restrict__ cols_s,
                           ushort_t* __restrict__ eah, ushort_t* __restrict__ eal) {
    int slot = blockIdx.x * 256 + threadIdx.x;
    if (slot >= N_EDGES) return;
    int eid = csr_eid[slot];
    rows_s[slot] = ei[eid];
    cols_s[slot] = ei[N_EDGES + eid];
    const float* src = ea + (size_t)eid * EDGE_IN;
#pragma unroll
    for (int i = 0; i < EDGE_IN; ++i) {
        ushort_t hh, ll;
        split_f16(src[i], hh, ll);
        eah[(size_t)slot * EDGE_IN + i] = hh;
        eal[(size_t)slot * EDGE_IN + i] = ll;
    }
}

// ============ prep 1: repack W1a,W1b,W2,C1 into MFMA B-frag order, split fp16 hi/lo ============
__global__ void repack_weights(const float* __restrict__ ew1, const float* __restrict__ ew2,
                               const float* __restrict__ cw1,
                               ushort_t* __restrict__ wf_hi, ushort_t* __restrict__ wf_lo) {
    int gid = blockIdx.x * 256 + threadIdx.x;
    const int total = NLAYERS * 4 * 16384;
    if (gid >= total) return;
    int l   = gid / (4 * 16384);
    int rem = gid % (4 * 16384);
    int m4  = rem / 16384;
    int idx = rem & 16383;
    int b    = idx >> 9;
    int lane = (idx >> 3) & 63;
    int j    = idx & 7;
    int nt = b >> 2, kt = b & 3;
    int k = kt * 32 + ((lane >> 4) << 3) + j;
    int n = (nt << 4) + (lane & 15);
    float v;
    if (m4 == 0)      v = ew1[(size_t)l * 385 * 128 + (size_t)k * 128 + n];
    else if (m4 == 1) v = ew1[(size_t)l * 385 * 128 + (size_t)(128 + k) * 128 + n];
    else if (m4 == 2) v = ew2[(size_t)l * 16384 + k * 128 + n];
    else              v = cw1[(size_t)l * 16384 + k * 128 + n];
    split_f16(v, wf_hi[gid], wf_lo[gid]);
}

// ============ prep 2: G = eew @ W1c (K rows 0-15) + d2 weight row at k=16; frag-packed, split ============
__global__ void prep_g(const float* __restrict__ eew, const float* __restrict__ eeb,
                       const float* __restrict__ ew1, const float* __restrict__ eb1,
                       ushort_t* __restrict__ g_hi, ushort_t* __restrict__ g_lo,
                       float* __restrict__ bias1c) {
    int gid = blockIdx.x * 256 + threadIdx.x;
    const int T1 = NLAYERS * 4096;
    if (gid < T1) {
        int l = gid >> 12;
        int idx = gid & 4095;
        int nt = idx >> 9;
        int lane = (idx >> 3) & 63;
        int j = idx & 7;
        int q = lane >> 4;
        int n = (nt << 4) + (lane & 15);
        int k = q * 8 + j;
        float v = 0.f;
        if (k < EDGE_IN) {
            const float* w1c = ew1 + (size_t)l * 385 * 128 + (size_t)257 * 128;
            float acc = 0.f;
            for (int c = 0; c < HDIM; ++c) acc += eew[k * 128 + c] * w1c[(size_t)c * 128 + n];
            v = acc;
        } else if (k == EDGE_IN) {
            v = ew1[(size_t)l * 385 * 128 + (size_t)256 * 128 + n];   // d2 weight row
        }
        split_f16(v, g_hi[gid], g_lo[gid]);
    } else if (gid < T1 + NLAYERS * 128) {
        int r = gid - T1;
        int l = r >> 7;
        int n = r & 127;
        const float* w1c = ew1 + (size_t)l * 385 * 128 + (size_t)257 * 128;
        float acc = eb1[l * 128 + n];
        for (int c = 0; c < HDIM; ++c) acc += eeb[c] * w1c[(size_t)c * 128 + n];
        bias1c[r] = acc;
    }
}

// ============ t_emb ============
__global__ void temb_kernel(const float* t, const float* tw1, const float* tb1,
                            const float* tw2, const float* tb2, float* t_emb) {
    __shared__ float s_a[HDIM];
    int j = threadIdx.x;
    s_a[j] = silu_f(t[0] * tw1[j] + tb1[j]);
    __syncthreads();
    float acc = tb2[j];
    for (int k = 0; k < HDIM; ++k) acc += s_a[k] * tw2[k * HDIM + j];
    t_emb[j] = acc;
}

// ============ h_feat init: 8 nodes/block, weights amortized ============
__global__ __launch_bounds__(128) void hfeat_kernel(
    const float* __restrict__ h, const float* __restrict__ new_,
    const float* __restrict__ neb, const float* __restrict__ t_emb,
    float* __restrict__ h_feat,
    ushort_t* __restrict__ hbf_hi, ushort_t* __restrict__ hbf_lo) {
    __shared__ float s_h[8][NODE_IN];
    int nb = blockIdx.x * 8, j = threadIdx.x;
#pragma unroll
    for (int it = 0; it < 4; ++it) {
        int idx = it * 128 + j;
        int e = idx >> 6, i = idx & 63;
        s_h[e][i] = h[(size_t)(nb + e) * NODE_IN + i];
    }
    __syncthreads();
    float base = neb[j] + t_emb[j];
    float acc[8];
#pragma unroll
    for (int e = 0; e < 8; ++e) acc[e] = base;
    for (int i = 0; i < NODE_IN; i += 2) {
        float w0 = new_[i * HDIM + j];
        float w1 = new_[(i + 1) * HDIM + j];
#pragma unroll
        for (int e = 0; e < 8; ++e)
            acc[e] += s_h[e][i] * w0 + s_h[e][i + 1] * w1;
    }
#pragma unroll
    for (int e = 0; e < 8; ++e) {
        h_feat[(size_t)(nb + e) * HDIM + j] = acc[e];
        split_f16(acc[e], hbf_hi[(size_t)(nb + e) * HDIM + j], hbf_lo[(size_t)(nb + e) * HDIM + j]);
    }
}

__global__ void xinit_kernel(const float* x, float* x_cur) {
    int idx = blockIdx.x * blockDim.x + threadIdx.x;
    if (idx < N_NODES * 3) x_cur[idx] = x[idx];
}

// ============ MFMA edge kernel: 1 block = 1 wave = 32 CSR slots (2 M-tiles) ============
// GEMM1: hi + single lo chain (h_row + ea/d2 corrections; h_col hi-only).
// GEMM2/GEMM3 hi-only. GEMM2 fuses m-store + segmented reduce per nt.
__global__ __launch_bounds__(64, 2) void edge_mfma_kernel(
    const int* __restrict__ rows_s, const int* __restrict__ cols_s,
    const ushort_t* __restrict__ eah, const ushort_t* __restrict__ eal,
    const float* __restrict__ x_cur,
    const ushort_t* __restrict__ hbf_hi, const ushort_t* __restrict__ hbf_lo,
    const ushort_t* __restrict__ wf_hi, const ushort_t* __restrict__ wf_lo,
    const ushort_t* __restrict__ g_hi, const ushort_t* __restrict__ g_lo,
    const float* __restrict__ bias1c,
    const float* __restrict__ eb2, const float* __restrict__ cb1, const float* __restrict__ cw2,
    int layer, float* __restrict__ agg_h, float* __restrict__ agg_x)
{
    __shared__ __align__(16) ushort_t s_acth[32 * SACT];
    __shared__ float s_d2[32], s_dist[32], s_diff[32][3];
    __shared__ int s_row[32], s_col[32];
    __shared__ int s_drows[32];
    __shared__ int s_dcnt[1];

    const int lane = threadIdx.x;
    const int lo = lane & 15, q = lane >> 4;
    const int e0 = blockIdx.x * 32;

    const ushort_t* wAh  = wf_hi + (size_t)layer * 4 * 16384;
    const ushort_t* wAl  = wf_lo + (size_t)layer * 4 * 16384;
    const ushort_t* wBh  = wAh + 16384;
    const ushort_t* wW2h = wAh + 32768;
    const ushort_t* wC1h = wAh + 49152;
    const ushort_t* wgh  = g_hi + (size_t)layer * 4096;
    const ushort_t* wgl  = g_lo + (size_t)layer * 4096;
    const float* b1v = bias1c + layer * 128;
    const float* b2v = eb2 + layer * 128;
    const float* cbv = cb1 + layer * 128;
    const float* c2v = cw2 + layer * 128;

    // ---- phase 0: geometry for 32 slots (coalesced slot-order reads) ----
    if (lane < 32) {
        int slot = e0 + lane;
        int r = rows_s[slot], c = cols_s[slot];
        s_row[lane] = r; s_col[lane] = c;
        float dx = x_cur[r * 3 + 0] - x_cur[c * 3 + 0];
        float dy = x_cur[r * 3 + 1] - x_cur[c * 3 + 1];
        float dz = x_cur[r * 3 + 2] - x_cur[c * 3 + 2];
        float d2 = dx * dx + dy * dy + dz * dz;
        s_d2[lane] = d2;
        s_dist[lane] = sqrtf(d2 + EPSV);
        s_diff[lane][0] = dx; s_diff[lane][1] = dy; s_diff[lane][2] = dz;
    }
    __syncthreads();   // B1 (single-wave: cheap)

    // distinct-row list via ballot (CSR slots row-sorted)
    {
        bool head = false;
        if (lane < 32) {
            int r = s_row[lane];
            int prev = (lane == 0) ? -1 : s_row[lane - 1];
            head = (r != prev);
        }
        unsigned long long b = __ballot(head);
        if (head) {
            int idx = __popcll(b & ((1ull << lane) - 1ull));
            s_drows[idx] = s_row[lane];
        }
        if (lane == 0) s_dcnt[0] = __popcll(b);
    }

    // ---- A fragments for both tiles ----
    int erT[2], ecT[2];
#pragma unroll
    for (int t = 0; t < 2; ++t) { erT[t] = s_row[t * 16 + lo]; ecT[t] = s_col[t * 16 + lo]; }

    s8 aRh[2][4], aRl[2][4], aCh[2][4];
#pragma unroll
    for (int t = 0; t < 2; ++t)
#pragma unroll
        for (int kt = 0; kt < 4; ++kt) {
            size_t ro = (size_t)erT[t] * 128 + kt * 32 + q * 8;
            size_t co = (size_t)ecT[t] * 128 + kt * 32 + q * 8;
            aRh[t][kt] = *(const s8*)(hbf_hi + ro);
            aRl[t][kt] = *(const s8*)(hbf_lo + ro);
            aCh[t][kt] = *(const s8*)(hbf_hi + co);
        }
    // ea (k=0..15, prepacked fp16 split, coalesced) + d2 (k=16, lanes q==2 slot j=0)
    s8 aEAh[2], aEAl[2];
#pragma unroll
    for (int t = 0; t < 2; ++t) {
        aEAh[t] = (s8){0,0,0,0,0,0,0,0};
        aEAl[t] = (s8){0,0,0,0,0,0,0,0};
        if (q < 2) {
            size_t off = (size_t)(e0 + t * 16 + lo) * EDGE_IN + q * 8;
            aEAh[t] = *(const s8*)(eah + off);
            aEAl[t] = *(const s8*)(eal + off);
        } else if (q == 2) {
            ushort_t hh, ll;
            split_f16(s_d2[t * 16 + lo], hh, ll);
            aEAh[t][0] = (short)hh; aEAl[t][0] = (short)ll;
        }
    }

    // ---- GEMM1: y1 = silu(hR@W1a + hC@W1b + [ea|d2]@G + b1')
    //      hi everywhere + lo corrections for hR and ea/d2 (hC hi-only) ----
#pragma unroll
    for (int nt = 0; nt < 8; ++nt) {
        f4 aH[2], aL0[2];
#pragma unroll
        for (int t = 0; t < 2; ++t) {
            aH[t] = (f4){0.f,0.f,0.f,0.f};
            aL0[t] = (f4){0.f,0.f,0.f,0.f};
        }
        {
            s8 bGh = *(const s8*)(wgh + ((size_t)nt * 64 + lane) * 8);
            s8 bGl = *(const s8*)(wgl + ((size_t)nt * 64 + lane) * 8);
#pragma unroll
            for (int t = 0; t < 2; ++t) {
                aH[t] = mfma16(aEAh[t], bGh, aH[t]);
                aL0[t] = mfma16(aEAh[t], bGl, aL0[t]);
                aL0[t] = mfma16(aEAl[t], bGh, aL0[t]);
            }
        }
#pragma unroll
        for (int kt = 0; kt < 4; ++kt) {
            size_t base = ((size_t)(nt * 4 + kt) * 64 + lane) * 8;
            s8 bh = *(const s8*)(wAh + base);
            s8 bl = *(const s8*)(wAl + base);
            s8 ch = *(const s8*)(wBh + base);
#pragma unroll
            for (int t = 0; t < 2; ++t) {
                aH[t] = mfma16(aRh[t][kt], bh, aH[t]);
                aL0[t] = mfma16(aRh[t][kt], bl, aL0[t]);
                aL0[t] = mfma16(aRl[t][kt], bh, aL0[t]);
                aH[t] = mfma16(aCh[t][kt], ch, aH[t]);
            }
        }
        float bb = b1v[nt * 16 + lo];
#pragma unroll
        for (int t = 0; t < 2; ++t)
#pragma unroll
            for (int r = 0; r < 4; ++r) {
                float v = silu_f(aH[t][r] + aL0[t][r] * INV4096 + bb);
                int off = (t * 16 + q * 4 + r) * SACT + nt * 16 + lo;
                _Float16 hh = (_Float16)v;
                s_acth[off] = __builtin_bit_cast(ushort_t, hh);
            }
    }
    __syncthreads();   // B2

    // ---- GEMM2 (hi-only): m = silu(y1 @ W2 + b2), fused store + segmented reduce ----
    s8 aYh[2][4];
#pragma unroll
    for (int t = 0; t < 2; ++t)
#pragma unroll
        for (int kt = 0; kt < 4; ++kt) {
            int off = (t * 16 + lo) * SACT + kt * 32 + q * 8;
            aYh[t][kt] = *(const s8*)&s_acth[off];
        }
    __syncthreads();   // B3

    int rowm[2][4];
#pragma unroll
    for (int t = 0; t < 2; ++t)
#pragma unroll
        for (int r = 0; r < 4; ++r) rowm[t][r] = s_row[t * 16 + q * 4 + r];
    const int dcnt = s_dcnt[0];

#pragma unroll
    for (int nt = 0; nt < 8; ++nt) {
        f4 aH[2];
#pragma unroll
        for (int t = 0; t < 2; ++t) aH[t] = (f4){0.f,0.f,0.f,0.f};
#pragma unroll
        for (int kt = 0; kt < 4; ++kt) {
            size_t base = ((size_t)(nt * 4 + kt) * 64 + lane) * 8;
            s8 bh = *(const s8*)(wW2h + base);
#pragma unroll
            for (int t = 0; t < 2; ++t)
                aH[t] = mfma16(aYh[t][kt], bh, aH[t]);
        }
        float bb = b2v[nt * 16 + lo];
#pragma unroll
        for (int t = 0; t < 2; ++t) {
#pragma unroll
            for (int r = 0; r < 4; ++r) {
                aH[t][r] = silu_f(aH[t][r] + bb);
                int off = (t * 16 + q * 4 + r) * SACT + nt * 16 + lo;
                _Float16 hh = (_Float16)aH[t][r];
                s_acth[off] = __builtin_bit_cast(ushort_t, hh);
            }
        }
        // segmented reduce of this nt's m-slice -> atomics per distinct row
        for (int di = 0; di < dcnt; ++di) {
            int dr = s_drows[di];
            float v = 0.f;
#pragma unroll
            for (int t = 0; t < 2; ++t)
#pragma unroll
                for (int r = 0; r < 4; ++r) v += (rowm[t][r] == dr) ? aH[t][r] : 0.f;
            v += __shfl_xor(v, 16, 64);
            v += __shfl_xor(v, 32, 64);
            if (lane < 16) atomicAdd(&agg_h[(size_t)dr * HDIM + nt * 16 + lane], v);
        }
    }
    __syncthreads();   // B4

    // ---- GEMM3 (hi-only): c = silu(m @ C1 + cb) ; w = tanh(c . c2) ----
    s8 aMh[2][4];
#pragma unroll
    for (int t = 0; t < 2; ++t)
#pragma unroll
        for (int kt = 0; kt < 4; ++kt) {
            int off = (t * 16 + lo) * SACT + kt * 32 + q * 8;
            aMh[t][kt] = *(const s8*)&s_acth[off];
        }

    float wpart[2][4] = {{0.f,0.f,0.f,0.f},{0.f,0.f,0.f,0.f}};
#pragma unroll
    for (int nt = 0; nt < 8; ++nt) {
        f4 aH[2];
#pragma unroll
        for (int t = 0; t < 2; ++t) aH[t] = (f4){0.f,0.f,0.f,0.f};
#pragma unroll
        for (int kt = 0; kt < 4; ++kt) {
            size_t base = ((size_t)(nt * 4 + kt) * 64 + lane) * 8;
            s8 bh = *(const s8*)(wC1h + base);
#pragma unroll
            for (int t = 0; t < 2; ++t)
                aH[t] = mfma16(aMh[t][kt], bh, aH[t]);
        }
        float bb = cbv[nt * 16 + lo];
        float cc = c2v[nt * 16 + lo];
#pragma unroll
        for (int t = 0; t < 2; ++t)
#pragma unroll
            for (int r = 0; r < 4; ++r)
                wpart[t][r] += silu_f(aH[t][r] + bb) * cc;
    }
#pragma unroll
    for (int t = 0; t < 2; ++t)
#pragma unroll
        for (int r = 0; r < 4; ++r) {
#pragma unroll
            for (int mask = 1; mask < 16; mask <<= 1)
                wpart[t][r] += __shfl_xor(wpart[t][r], mask, 16);
        }
    // trans vector + segmented reduce -> agg_x atomics per distinct row
    {
        float val[2][4];
#pragma unroll
        for (int t = 0; t < 2; ++t)
#pragma unroll
            for (int r = 0; r < 4; ++r) {
                int mm = t * 16 + q * 4 + r;
                val[t][r] = (lo < 3)
                    ? s_diff[mm][lo] * __builtin_amdgcn_rcpf(s_dist[mm] + EPSV) * tanh_fast(wpart[t][r])
                    : 0.f;
            }
        for (int di = 0; di < dcnt; ++di) {
            int dr = s_drows[di];
            float v = 0.f;
#pragma unroll
            for (int t = 0; t < 2; ++t)
#pragma unroll
                for (int r = 0; r < 4; ++r) v += (rowm[t][r] == dr) ? val[t][r] : 0.f;
            v += __shfl_xor(v, 16, 64);
            v += __shfl_xor(v, 32, 64);
            if (lane < 3) atomicAdd(&agg_x[dr * 3 + lane], v);
        }
    }
}

// ============ node kernel: 8 nodes/block, weights amortized ============
__global__ __launch_bounds__(128) void node_kernel(
    float* __restrict__ h_feat, float* __restrict__ x_cur,
    ushort_t* __restrict__ hbf_hi, ushort_t* __restrict__ hbf_lo,
    const float* __restrict__ agg_h, const float* __restrict__ agg_x,
    const float* __restrict__ mask,
    const float* __restrict__ n1p, const float* __restrict__ nb1p,
    const float* __restrict__ n2p, const float* __restrict__ nb2p, int layer) {
    __shared__ float s_cat[8][2 * HDIM];
    __shared__ float s_u[8][HDIM];
    int nb = blockIdx.x * 8, j = threadIdx.x;
    const size_t w1o = (size_t)layer * 2 * HDIM * HDIM;
    const size_t w2o = (size_t)layer * HDIM * HDIM;
    const size_t bo  = (size_t)layer * HDIM;

#pragma unroll
    for (int e = 0; e < 8; ++e) {
        s_cat[e][j] = h_feat[(size_t)(nb + e) * HDIM + j];
        s_cat[e][HDIM + j] = agg_h[(size_t)(nb + e) * HDIM + j];
    }
    __syncthreads();

    float u[8];
    float b1 = nb1p[bo + j];
#pragma unroll
    for (int e = 0; e < 8; ++e) u[e] = b1;
    for (int i0 = 0; i0 < 2 * HDIM; i0 += 2) {
        float w0 = n1p[w1o + (size_t)i0 * HDIM + j];
        float w1 = n1p[w1o + (size_t)(i0 + 1) * HDIM + j];
#pragma unroll
        for (int e = 0; e < 8; ++e)
            u[e] += s_cat[e][i0] * w0 + s_cat[e][i0 + 1] * w1;
    }
#pragma unroll
    for (int e = 0; e < 8; ++e) s_u[e][j] = silu_f(u[e]);
    __syncthreads();

    float acc[8];
    float b2 = nb2p[bo + j];
#pragma unroll
    for (int e = 0; e < 8; ++e) acc[e] = b2;
    for (int i0 = 0; i0 < HDIM; i0 += 2) {
        float w0 = n2p[w2o + (size_t)i0 * HDIM + j];
        float w1 = n2p[w2o + (size_t)(i0 + 1) * HDIM + j];
#pragma unroll
        for (int e = 0; e < 8; ++e)
            acc[e] += s_u[e][i0] * w0 + s_u[e][i0 + 1] * w1;
    }
#pragma unroll
    for (int e = 0; e < 8; ++e) {
        float nh = s_cat[e][j] + acc[e];
        h_feat[(size_t)(nb + e) * HDIM + j] = nh;
        split_f16(nh, hbf_hi[(size_t)(nb + e) * HDIM + j], hbf_lo[(size_t)(nb + e) * HDIM + j]);
    }
    if (j < 24) {
        int e = j / 3, c = j - e * 3;
        x_cur[(nb + e) * 3 + c] += agg_x[(nb + e) * 3 + c] * mask[nb + e];
    }
}

__global__ void out_kernel(const float* __restrict__ x_cur, const float* __restrict__ x_in,
                           const float* __restrict__ mask, float* __restrict__ out) {
    int idx = blockIdx.x * blockDim.x + threadIdx.x;
    if (idx < N_NODES * 3) {
        int n = idx / 3;
        out[idx] = (x_cur[idx] - x_in[idx]) * mask[n];
    }
}

extern "C" void kernel_launch(void* const* d_in, const int* in_sizes, int n_in,
                              void* d_out, int out_size, void* d_ws, size_t ws_size,
                              hipStream_t stream) {
    const float* h    = (const float*)d_in[0];
    const float* x    = (const float*)d_in[1];
    const int*   ei   = (const int*)d_in[2];
    const float* ea   = (const float*)d_in[3];
    const float* t    = (const float*)d_in[4];
    const float* mask = (const float*)d_in[5];
    const float* tw1  = (const float*)d_in[6];
    const float* tb1  = (const float*)d_in[7];
    const float* tw2  = (const float*)d_in[8];
    const float* tb2  = (const float*)d_in[9];
    const float* new_ = (const float*)d_in[10];
    const float* neb  = (const float*)d_in[11];
    const float* eew  = (const float*)d_in[12];
    const float* eeb  = (const float*)d_in[13];
    const float* ew1  = (const float*)d_in[14];
    const float* eb1  = (const float*)d_in[15];
    const float* ew2  = (const float*)d_in[16];
    const float* eb2  = (const float*)d_in[17];
    const float* cw1  = (const float*)d_in[18];
    const float* cb1  = (const float*)d_in[19];
    const float* cw2  = (const float*)d_in[20];
    const float* nw1  = (const float*)d_in[21];
    const float* nb1  = (const float*)d_in[22];
    const float* nw2  = (const float*)d_in[23];
    const float* nb2  = (const float*)d_in[24];

    // ---- workspace carve-out (256 B aligned) ----
    char* p = (char*)d_ws;
    auto alloc = [&](size_t bytes) -> char* {
        char* r = p;
        p += (bytes + 255) & ~(size_t)255;
        return r;
    };
    float* t_emb    = (float*)alloc(HDIM * 4);
    float* h_feat   = (float*)alloc((size_t)N_NODES * HDIM * 4);
    float* x_cur    = (float*)alloc((size_t)N_NODES * 3 * 4);
    float* agg_h    = (float*)alloc((size_t)N_NODES * HDIM * 4);
    float* agg_x    = (float*)alloc((size_t)N_NODES * 3 * 4);
    float* bias1c   = (float*)alloc(NLAYERS * HDIM * 4);
    ushort_t* hbf_hi = (ushort_t*)alloc((size_t)N_NODES * HDIM * 2);
    ushort_t* hbf_lo = (ushort_t*)alloc((size_t)N_NODES * HDIM * 2);
    ushort_t* wf_hi  = (ushort_t*)alloc((size_t)NLAYERS * 4 * 16384 * 2);
    ushort_t* wf_lo  = (ushort_t*)alloc((size_t)NLAYERS * 4 * 16384 * 2);
    ushort_t* g_hi   = (ushort_t*)alloc((size_t)NLAYERS * 4096 * 2);
    ushort_t* g_lo   = (ushort_t*)alloc((size_t)NLAYERS * 4096 * 2);
    int* deg        = (int*)alloc((size_t)N_NODES * 4);
    int* row_start  = (int*)alloc((size_t)(N_NODES + 1) * 4);
    int* cursor     = (int*)alloc((size_t)N_NODES * 4);
    int* csr_eid    = (int*)alloc((size_t)N_EDGES * 4);
    int* rows_s     = (int*)alloc((size_t)N_EDGES * 4);
    int* cols_s     = (int*)alloc((size_t)N_EDGES * 4);
    ushort_t* eah   = (ushort_t*)alloc((size_t)N_EDGES * EDGE_IN * 2);
    ushort_t* eal   = (ushort_t*)alloc((size_t)N_EDGES * EDGE_IN * 2);

    // single memset spans agg_h..agg_x (adjacent allocations; ends before bias1c)
    size_t agg_span = (size_t)((char*)(agg_x + (size_t)N_NODES * 3) - (char*)agg_h);

    repack_weights<<<(NLAYERS * 4 * 16384 + 255) / 256, 256, 0, stream>>>(ew1, ew2, cw1, wf_hi, wf_lo);
    prep_g<<<(NLAYERS * 4096 + NLAYERS * 128 + 255) / 256, 256, 0, stream>>>(eew, eeb, ew1, eb1, g_hi, g_lo, bias1c);
    temb_kernel<<<1, HDIM, 0, stream>>>(t, tw1, tb1, tw2, tb2, t_emb);
    hfeat_kernel<<<(N_NODES + 7) / 8, 128, 0, stream>>>(h, new_, neb, t_emb, h_feat, hbf_hi, hbf_lo);
    xinit_kernel<<<(N_NODES * 3 + 255) / 256, 256, 0, stream>>>(x, x_cur);

    hipMemsetAsync(deg, 0, (size_t)N_NODES * 4, stream);
    deg_kernel<<<(N_EDGES + 255) / 256, 256, 0, stream>>>(ei, deg);
    scan_kernel<<<1, 256, 0, stream>>>(deg, row_start, cursor);
    scatter_kernel<<<(N_EDGES + 255) / 256, 256, 0, stream>>>(ei, cursor, csr_eid);
    prep_edges<<<(N_EDGES + 255) / 256, 256, 0, stream>>>(ei, csr_eid, ea, rows_s, cols_s, eah, eal);

    for (int l = 0; l < NLAYERS; ++l) {
        hipMemsetAsync(agg_h, 0, agg_span, stream);
        edge_mfma_kernel<<<N_EDGES / 32, 64, 0, stream>>>(
            rows_s, cols_s, eah, eal, x_cur, hbf_hi, hbf_lo, wf_hi, wf_lo, g_hi, g_lo, bias1c,
            eb2, cb1, cw2, l, agg_h, agg_x);
        node_kernel<<<N_NODES / 8, 128, 0, stream>>>(
            h_feat, x_cur, hbf_hi, hbf_lo, agg_h, agg_x, mask, nw1, nb1, nw2, nb2, l);
    }

    out_kernel<<<(N_NODES * 3 + 255) / 256, 256, 0, stream>>>(x_cur, x, mask, (float*)d_out);
}

// Round 15
// 860.457 us; speedup vs baseline: 6.7505x; 1.0661x over previous
//
#include <hip/hip_runtime.h>
#include <hip/hip_bf16.h>

#define N_NODES 10000
#define N_EDGES 320000
#define HDIM 128
#define NODE_IN 64
#define EDGE_IN 16
#define NLAYERS 4
#define EPSV 1e-8f
#define SACT 136       // LDS activation row stride (elems)
#define INV4096 2.44140625e-4f

typedef unsigned short ushort_t;
typedef __attribute__((ext_vector_type(8))) short s8;        // 8 fp16 bit-pattern (4 VGPRs)
typedef __attribute__((ext_vector_type(8))) _Float16 h8;
typedef __attribute__((ext_vector_type(4))) float f4;

// silu via v_rcp_f32 (1 ulp) instead of IEEE divide (~10 instr)
__device__ __forceinline__ float silu_f(float z) {
    return z * __builtin_amdgcn_rcpf(1.0f + __expf(-z));
}
// tanh(x) = 1 - 2*rcp(exp(2x)+1); exact limits at +-inf
__device__ __forceinline__ float tanh_fast(float x) {
    float e = __expf(2.0f * x);
    return 1.0f - 2.0f * __builtin_amdgcn_rcpf(e + 1.0f);
}

__device__ __forceinline__ f4 mfma16(s8 a, s8 b, f4 c) {
    return __builtin_amdgcn_mfma_f32_16x16x32_f16(
        __builtin_bit_cast(h8, a), __builtin_bit_cast(h8, b), c, 0, 0, 0);
}

// fp32 -> fp16 hi + (residual*4096) lo   (rep error ~2^-23 relative)
__device__ __forceinline__ void split_f16(float x, ushort_t& hi, ushort_t& lo) {
    _Float16 h = (_Float16)x;
    float hf = (float)h;
    _Float16 l = (_Float16)((x - hf) * 4096.0f);
    hi = __builtin_bit_cast(ushort_t, h);
    lo = __builtin_bit_cast(ushort_t, l);
}

// ============ CSR build ============
__global__ void deg_kernel(const int* __restrict__ ei, int* __restrict__ deg) {
    int e = blockIdx.x * 256 + threadIdx.x;
    if (e < N_EDGES) atomicAdd(&deg[ei[e]], 1);
}

__global__ void scan_kernel(const int* __restrict__ deg, int* __restrict__ row_start,
                            int* __restrict__ cursor) {
    __shared__ int s_part[256];
    const int CH = 40;   // 256*40 = 10240 >= N_NODES
    int t = threadIdx.x;
    int base = t * CH;
    int sum = 0;
    for (int i = 0; i < CH; ++i) { int n = base + i; if (n < N_NODES) sum += deg[n]; }
    s_part[t] = sum;
    __syncthreads();
    for (int d = 1; d < 256; d <<= 1) {
        int v = (t >= d) ? s_part[t - d] : 0;
        __syncthreads();
        s_part[t] += v;
        __syncthreads();
    }
    int off = s_part[t] - sum;
    for (int i = 0; i < CH; ++i) {
        int n = base + i;
        if (n < N_NODES) { row_start[n] = off; cursor[n] = off; off += deg[n]; }
    }
    if (t == 255) row_start[N_NODES] = s_part[255];
}

__global__ void scatter_kernel(const int* __restrict__ ei, int* __restrict__ cursor,
                               int* __restrict__ csr_eid) {
    int e = blockIdx.x * 256 + threadIdx.x;
    if (e < N_EDGES) {
        int r = ei[e];
        int pos = atomicAdd(&cursor[r], 1);
        csr_eid[pos] = e;
    }
}

// ============ one-time slot-order prepack: rows/cols + ea split fp16 ============
__global__ void prep_edges(const int* __restrict__ ei, const int* __restrict__ csr_eid,
                           const float* __restrict__ ea,
                           int* __restrict__ rows_s, int* __restrict__ cols_s,
                           ushort_t* __restrict__ eah, ushort_t* __restrict__ eal) {
    int slot = blockIdx.x * 256 + threadIdx.x;
    if (slot >= N_EDGES) return;
    int eid = csr_eid[slot];
    rows_s[slot] = ei[eid];
    cols_s[slot] = ei[N_EDGES + eid];
    const float* src = ea + (size_t)eid * EDGE_IN;
#pragma unroll
    for (int i = 0; i < EDGE_IN; ++i) {
        ushort_t hh, ll;
        split_f16(src[i], hh, ll);
        eah[(size_t)slot * EDGE_IN + i] = hh;
        eal[(size_t)slot * EDGE_IN + i] = ll;
    }
}

// ============ prep 1: repack W1a,W1b,W2,C1 into MFMA B-frag order, split fp16 hi/lo ============
__global__ void repack_weights(const float* __restrict__ ew1, const float* __restrict__ ew2,
                               const float* __restrict__ cw1,
                               ushort_t* __restrict__ wf_hi, ushort_t* __restrict__ wf_lo) {
    int gid = blockIdx.x * 256 + threadIdx.x;
    const int total = NLAYERS * 4 * 16384;
    if (gid >= total) return;
    int l   = gid / (4 * 16384);
    int rem = gid % (4 * 16384);
    int m4  = rem / 16384;
    int idx = rem & 16383;
    int b    = idx >> 9;
    int lane = (idx >> 3) & 63;
    int j    = idx & 7;
    int nt = b >> 2, kt = b & 3;
    int k = kt * 32 + ((lane >> 4) << 3) + j;
    int n = (nt << 4) + (lane & 15);
    float v;
    if (m4 == 0)      v = ew1[(size_t)l * 385 * 128 + (size_t)k * 128 + n];
    else if (m4 == 1) v = ew1[(size_t)l * 385 * 128 + (size_t)(128 + k) * 128 + n];
    else if (m4 == 2) v = ew2[(size_t)l * 16384 + k * 128 + n];
    else              v = cw1[(size_t)l * 16384 + k * 128 + n];
    split_f16(v, wf_hi[gid], wf_lo[gid]);
}

// ============ prep 2: G = eew @ W1c (K rows 0-15) + d2 weight row at k=16; frag-packed, split ============
__global__ void prep_g(const float* __restrict__ eew, const float* __restrict__ eeb,
                       const float* __restrict__ ew1, const float* __restrict__ eb1,
                       ushort_t* __restrict__ g_hi, ushort_t* __restrict__ g_lo,
                       float* __restrict__ bias1c) {
    int gid = blockIdx.x * 256 + threadIdx.x;
    const int T1 = NLAYERS * 4096;
    if (gid < T1) {
        int l = gid >> 12;
        int idx = gid & 4095;
        int nt = idx >> 9;
        int lane = (idx >> 3) & 63;
        int j = idx & 7;
        int q = lane >> 4;
        int n = (nt << 4) + (lane & 15);
        int k = q * 8 + j;
        float v = 0.f;
        if (k < EDGE_IN) {
            const float* w1c = ew1 + (size_t)l * 385 * 128 + (size_t)257 * 128;
            float acc = 0.f;
            for (int c = 0; c < HDIM; ++c) acc += eew[k * 128 + c] * w1c[(size_t)c * 128 + n];
            v = acc;
        } else if (k == EDGE_IN) {
            v = ew1[(size_t)l * 385 * 128 + (size_t)256 * 128 + n];   // d2 weight row
        }
        split_f16(v, g_hi[gid], g_lo[gid]);
    } else if (gid < T1 + NLAYERS * 128) {
        int r = gid - T1;
        int l = r >> 7;
        int n = r & 127;
        const float* w1c = ew1 + (size_t)l * 385 * 128 + (size_t)257 * 128;
        float acc = eb1[l * 128 + n];
        for (int c = 0; c < HDIM; ++c) acc += eeb[c] * w1c[(size_t)c * 128 + n];
        bias1c[r] = acc;
    }
}

// ============ t_emb ============
__global__ void temb_kernel(const float* t, const float* tw1, const float* tb1,
                            const float* tw2, const float* tb2, float* t_emb) {
    __shared__ float s_a[HDIM];
    int j = threadIdx.x;
    s_a[j] = silu_f(t[0] * tw1[j] + tb1[j]);
    __syncthreads();
    float acc = tb2[j];
    for (int k = 0; k < HDIM; ++k) acc += s_a[k] * tw2[k * HDIM + j];
    t_emb[j] = acc;
}

// ============ h_feat init: 8 nodes/block, weights amortized ============
__global__ __launch_bounds__(128) void hfeat_kernel(
    const float* __restrict__ h, const float* __restrict__ new_,
    const float* __restrict__ neb, const float* __restrict__ t_emb,
    float* __restrict__ h_feat,
    ushort_t* __restrict__ hbf_hi, ushort_t* __restrict__ hbf_lo) {
    __shared__ float s_h[8][NODE_IN];
    int nb = blockIdx.x * 8, j = threadIdx.x;
#pragma unroll
    for (int it = 0; it < 4; ++it) {
        int idx = it * 128 + j;
        int e = idx >> 6, i = idx & 63;
        s_h[e][i] = h[(size_t)(nb + e) * NODE_IN + i];
    }
    __syncthreads();
    float base = neb[j] + t_emb[j];
    float acc[8];
#pragma unroll
    for (int e = 0; e < 8; ++e) acc[e] = base;
    for (int i = 0; i < NODE_IN; i += 2) {
        float w0 = new_[i * HDIM + j];
        float w1 = new_[(i + 1) * HDIM + j];
#pragma unroll
        for (int e = 0; e < 8; ++e)
            acc[e] += s_h[e][i] * w0 + s_h[e][i + 1] * w1;
    }
#pragma unroll
    for (int e = 0; e < 8; ++e) {
        h_feat[(size_t)(nb + e) * HDIM + j] = acc[e];
        split_f16(acc[e], hbf_hi[(size_t)(nb + e) * HDIM + j], hbf_lo[(size_t)(nb + e) * HDIM + j]);
    }
}

__global__ void xinit_kernel(const float* x, float* x_cur) {
    int idx = blockIdx.x * blockDim.x + threadIdx.x;
    if (idx < N_NODES * 3) x_cur[idx] = x[idx];
}

// ============ MFMA edge kernel: 1 block = 1 wave = 32 CSR slots (2 M-tiles) ============
// GEMM1: hi + single lo chain; GEMM2/GEMM3 hi-only. B-frags double-buffered across nt.
__global__ __launch_bounds__(64, 2) void edge_mfma_kernel(
    const int* __restrict__ rows_s, const int* __restrict__ cols_s,
    const ushort_t* __restrict__ eah, const ushort_t* __restrict__ eal,
    const float* __restrict__ x_cur,
    const ushort_t* __restrict__ hbf_hi, const ushort_t* __restrict__ hbf_lo,
    const ushort_t* __restrict__ wf_hi, const ushort_t* __restrict__ wf_lo,
    const ushort_t* __restrict__ g_hi, const ushort_t* __restrict__ g_lo,
    const float* __restrict__ bias1c,
    const float* __restrict__ eb2, const float* __restrict__ cb1, const float* __restrict__ cw2,
    int layer, float* __restrict__ agg_h, float* __restrict__ agg_x)
{
    __shared__ __align__(16) ushort_t s_acth[32 * SACT];
    __shared__ float s_d2[32], s_dist[32], s_diff[32][3];
    __shared__ int s_row[32], s_col[32];
    __shared__ int s_drows[32];
    __shared__ int s_dcnt[1];

    const int lane = threadIdx.x;
    const int lo = lane & 15, q = lane >> 4;
    const int e0 = blockIdx.x * 32;

    const ushort_t* wAh  = wf_hi + (size_t)layer * 4 * 16384;
    const ushort_t* wAl  = wf_lo + (size_t)layer * 4 * 16384;
    const ushort_t* wBh  = wAh + 16384;
    const ushort_t* wW2h = wAh + 32768;
    const ushort_t* wC1h = wAh + 49152;
    const ushort_t* wgh  = g_hi + (size_t)layer * 4096;
    const ushort_t* wgl  = g_lo + (size_t)layer * 4096;
    const float* b1v = bias1c + layer * 128;
    const float* b2v = eb2 + layer * 128;
    const float* cbv = cb1 + layer * 128;
    const float* c2v = cw2 + layer * 128;

    // ---- phase 0: geometry for 32 slots (coalesced slot-order reads) ----
    if (lane < 32) {
        int slot = e0 + lane;
        int r = rows_s[slot], c = cols_s[slot];
        s_row[lane] = r; s_col[lane] = c;
        float dx = x_cur[r * 3 + 0] - x_cur[c * 3 + 0];
        float dy = x_cur[r * 3 + 1] - x_cur[c * 3 + 1];
        float dz = x_cur[r * 3 + 2] - x_cur[c * 3 + 2];
        float d2 = dx * dx + dy * dy + dz * dz;
        s_d2[lane] = d2;
        s_dist[lane] = sqrtf(d2 + EPSV);
        s_diff[lane][0] = dx; s_diff[lane][1] = dy; s_diff[lane][2] = dz;
    }
    __syncthreads();   // B1 (single-wave: cheap)

    // distinct-row list via ballot (CSR slots row-sorted)
    {
        bool head = false;
        if (lane < 32) {
            int r = s_row[lane];
            int prev = (lane == 0) ? -1 : s_row[lane - 1];
            head = (r != prev);
        }
        unsigned long long b = __ballot(head);
        if (head) {
            int idx = __popcll(b & ((1ull << lane) - 1ull));
            s_drows[idx] = s_row[lane];
        }
        if (lane == 0) s_dcnt[0] = __popcll(b);
    }

    // ---- A fragments for both tiles ----
    int erT[2], ecT[2];
#pragma unroll
    for (int t = 0; t < 2; ++t) { erT[t] = s_row[t * 16 + lo]; ecT[t] = s_col[t * 16 + lo]; }

    s8 aRh[2][4], aRl[2][4], aCh[2][4];
#pragma unroll
    for (int t = 0; t < 2; ++t)
#pragma unroll
        for (int kt = 0; kt < 4; ++kt) {
            size_t ro = (size_t)erT[t] * 128 + kt * 32 + q * 8;
            size_t co = (size_t)ecT[t] * 128 + kt * 32 + q * 8;
            aRh[t][kt] = *(const s8*)(hbf_hi + ro);
            aRl[t][kt] = *(const s8*)(hbf_lo + ro);
            aCh[t][kt] = *(const s8*)(hbf_hi + co);
        }
    // ea (k=0..15, prepacked fp16 split, coalesced) + d2 (k=16, lanes q==2 slot j=0)
    s8 aEAh[2], aEAl[2];
#pragma unroll
    for (int t = 0; t < 2; ++t) {
        aEAh[t] = (s8){0,0,0,0,0,0,0,0};
        aEAl[t] = (s8){0,0,0,0,0,0,0,0};
        if (q < 2) {
            size_t off = (size_t)(e0 + t * 16 + lo) * EDGE_IN + q * 8;
            aEAh[t] = *(const s8*)(eah + off);
            aEAl[t] = *(const s8*)(eal + off);
        } else if (q == 2) {
            ushort_t hh, ll;
            split_f16(s_d2[t * 16 + lo], hh, ll);
            aEAh[t][0] = (short)hh; aEAl[t][0] = (short)ll;
        }
    }

    // ---- GEMM1 (double-buffered B-frags): y1 = silu(hR@W1a + hC@W1b + [ea|d2]@G + b1') ----
    {
        s8 nGh = *(const s8*)(wgh + (size_t)lane * 8);
        s8 nGl = *(const s8*)(wgl + (size_t)lane * 8);
        s8 nbh[4], nbl[4], nch[4];
#pragma unroll
        for (int kt = 0; kt < 4; ++kt) {
            size_t base = ((size_t)kt * 64 + lane) * 8;
            nbh[kt] = *(const s8*)(wAh + base);
            nbl[kt] = *(const s8*)(wAl + base);
            nch[kt] = *(const s8*)(wBh + base);
        }
#pragma unroll
        for (int nt = 0; nt < 8; ++nt) {
            s8 cGh = nGh, cGl = nGl;
            s8 cbh[4], cbl[4], cch[4];
#pragma unroll
            for (int kt = 0; kt < 4; ++kt) { cbh[kt] = nbh[kt]; cbl[kt] = nbl[kt]; cch[kt] = nch[kt]; }
            if (nt < 7) {
                nGh = *(const s8*)(wgh + ((size_t)(nt + 1) * 64 + lane) * 8);
                nGl = *(const s8*)(wgl + ((size_t)(nt + 1) * 64 + lane) * 8);
#pragma unroll
                for (int kt = 0; kt < 4; ++kt) {
                    size_t base = ((size_t)((nt + 1) * 4 + kt) * 64 + lane) * 8;
                    nbh[kt] = *(const s8*)(wAh + base);
                    nbl[kt] = *(const s8*)(wAl + base);
                    nch[kt] = *(const s8*)(wBh + base);
                }
            }
            f4 aH[2], aL0[2];
#pragma unroll
            for (int t = 0; t < 2; ++t) {
                aH[t] = (f4){0.f,0.f,0.f,0.f};
                aL0[t] = (f4){0.f,0.f,0.f,0.f};
            }
#pragma unroll
            for (int t = 0; t < 2; ++t) {
                aH[t] = mfma16(aEAh[t], cGh, aH[t]);
                aL0[t] = mfma16(aEAh[t], cGl, aL0[t]);
                aL0[t] = mfma16(aEAl[t], cGh, aL0[t]);
            }
#pragma unroll
            for (int kt = 0; kt < 4; ++kt) {
#pragma unroll
                for (int t = 0; t < 2; ++t) {
                    aH[t] = mfma16(aRh[t][kt], cbh[kt], aH[t]);
                    aL0[t] = mfma16(aRh[t][kt], cbl[kt], aL0[t]);
                    aL0[t] = mfma16(aRl[t][kt], cbh[kt], aL0[t]);
                    aH[t] = mfma16(aCh[t][kt], cch[kt], aH[t]);
                }
            }
            float bb = b1v[nt * 16 + lo];
#pragma unroll
            for (int t = 0; t < 2; ++t)
#pragma unroll
                for (int r = 0; r < 4; ++r) {
                    float v = silu_f(aH[t][r] + aL0[t][r] * INV4096 + bb);
                    int off = (t * 16 + q * 4 + r) * SACT + nt * 16 + lo;
                    _Float16 hh = (_Float16)v;
                    s_acth[off] = __builtin_bit_cast(ushort_t, hh);
                }
        }
    }
    __syncthreads();   // B2

    // ---- GEMM2 (hi-only, double-buffered): m = silu(y1 @ W2 + b2), fused reduce ----
    s8 aYh[2][4];
#pragma unroll
    for (int t = 0; t < 2; ++t)
#pragma unroll
        for (int kt = 0; kt < 4; ++kt) {
            int off = (t * 16 + lo) * SACT + kt * 32 + q * 8;
            aYh[t][kt] = *(const s8*)&s_acth[off];
        }
    __syncthreads();   // B3

    int rowm[2][4];
#pragma unroll
    for (int t = 0; t < 2; ++t)
#pragma unroll
        for (int r = 0; r < 4; ++r) rowm[t][r] = s_row[t * 16 + q * 4 + r];
    const int dcnt = s_dcnt[0];

    {
        s8 nbh[4];
#pragma unroll
        for (int kt = 0; kt < 4; ++kt)
            nbh[kt] = *(const s8*)(wW2h + ((size_t)kt * 64 + lane) * 8);
#pragma unroll
        for (int nt = 0; nt < 8; ++nt) {
            s8 cbh[4];
#pragma unroll
            for (int kt = 0; kt < 4; ++kt) cbh[kt] = nbh[kt];
            if (nt < 7) {
#pragma unroll
                for (int kt = 0; kt < 4; ++kt)
                    nbh[kt] = *(const s8*)(wW2h + ((size_t)((nt + 1) * 4 + kt) * 64 + lane) * 8);
            }
            f4 aH[2];
#pragma unroll
            for (int t = 0; t < 2; ++t) aH[t] = (f4){0.f,0.f,0.f,0.f};
#pragma unroll
            for (int kt = 0; kt < 4; ++kt)
#pragma unroll
                for (int t = 0; t < 2; ++t)
                    aH[t] = mfma16(aYh[t][kt], cbh[kt], aH[t]);
            float bb = b2v[nt * 16 + lo];
#pragma unroll
            for (int t = 0; t < 2; ++t) {
#pragma unroll
                for (int r = 0; r < 4; ++r) {
                    aH[t][r] = silu_f(aH[t][r] + bb);
                    int off = (t * 16 + q * 4 + r) * SACT + nt * 16 + lo;
                    _Float16 hh = (_Float16)aH[t][r];
                    s_acth[off] = __builtin_bit_cast(ushort_t, hh);
                }
            }
            for (int di = 0; di < dcnt; ++di) {
                int dr = s_drows[di];
                float v = 0.f;
#pragma unroll
                for (int t = 0; t < 2; ++t)
#pragma unroll
                    for (int r = 0; r < 4; ++r) v += (rowm[t][r] == dr) ? aH[t][r] : 0.f;
                v += __shfl_xor(v, 16, 64);
                v += __shfl_xor(v, 32, 64);
                if (lane < 16) atomicAdd(&agg_h[(size_t)dr * HDIM + nt * 16 + lane], v);
            }
        }
    }
    __syncthreads();   // B4

    // ---- GEMM3 (hi-only, double-buffered): c = silu(m @ C1 + cb) ; w = tanh(c . c2) ----
    s8 aMh[2][4];
#pragma unroll
    for (int t = 0; t < 2; ++t)
#pragma unroll
        for (int kt = 0; kt < 4; ++kt) {
            int off = (t * 16 + lo) * SACT + kt * 32 + q * 8;
            aMh[t][kt] = *(const s8*)&s_acth[off];
        }

    float wpart[2][4] = {{0.f,0.f,0.f,0.f},{0.f,0.f,0.f,0.f}};
    {
        s8 nbh[4];
#pragma unroll
        for (int kt = 0; kt < 4; ++kt)
            nbh[kt] = *(const s8*)(wC1h + ((size_t)kt * 64 + lane) * 8);
#pragma unroll
        for (int nt = 0; nt < 8; ++nt) {
            s8 cbh[4];
#pragma unroll
            for (int kt = 0; kt < 4; ++kt) cbh[kt] = nbh[kt];
            if (nt < 7) {
#pragma unroll
                for (int kt = 0; kt < 4; ++kt)
                    nbh[kt] = *(const s8*)(wC1h + ((size_t)((nt + 1) * 4 + kt) * 64 + lane) * 8);
            }
            f4 aH[2];
#pragma unroll
            for (int t = 0; t < 2; ++t) aH[t] = (f4){0.f,0.f,0.f,0.f};
#pragma unroll
            for (int kt = 0; kt < 4; ++kt)
#pragma unroll
                for (int t = 0; t < 2; ++t)
                    aH[t] = mfma16(aMh[t][kt], cbh[kt], aH[t]);
            float bb = cbv[nt * 16 + lo];
            float cc = c2v[nt * 16 + lo];
#pragma unroll
            for (int t = 0; t < 2; ++t)
#pragma unroll
                for (int r = 0; r < 4; ++r)
                    wpart[t][r] += silu_f(aH[t][r] + bb) * cc;
        }
    }
#pragma unroll
    for (int t = 0; t < 2; ++t)
#pragma unroll
        for (int r = 0; r < 4; ++r) {
#pragma unroll
            for (int mask = 1; mask < 16; mask <<= 1)
                wpart[t][r] += __shfl_xor(wpart[t][r], mask, 16);
        }
    // trans vector + segmented reduce -> agg_x atomics per distinct row
    {
        float val[2][4];
#pragma unroll
        for (int t = 0; t < 2; ++t)
#pragma unroll
            for (int r = 0; r < 4; ++r) {
                int mm = t * 16 + q * 4 + r;
                val[t][r] = (lo < 3)
                    ? s_diff[mm][lo] * __builtin_amdgcn_rcpf(s_dist[mm] + EPSV) * tanh_fast(wpart[t][r])
                    : 0.f;
            }
        for (int di = 0; di < dcnt; ++di) {
            int dr = s_drows[di];
            float v = 0.f;
#pragma unroll
            for (int t = 0; t < 2; ++t)
#pragma unroll
                for (int r = 0; r < 4; ++r) v += (rowm[t][r] == dr) ? val[t][r] : 0.f;
            v += __shfl_xor(v, 16, 64);
            v += __shfl_xor(v, 32, 64);
            if (lane < 3) atomicAdd(&agg_x[dr * 3 + lane], v);
        }
    }
}

// ============ node kernel: 8 nodes/block; zeroes agg buffers after reading ============
__global__ __launch_bounds__(128) void node_kernel(
    float* __restrict__ h_feat, float* __restrict__ x_cur,
    ushort_t* __restrict__ hbf_hi, ushort_t* __restrict__ hbf_lo,
    float* __restrict__ agg_h, float* __restrict__ agg_x,
    const float* __restrict__ mask,
    const float* __restrict__ n1p, const float* __restrict__ nb1p,
    const float* __restrict__ n2p, const float* __restrict__ nb2p, int layer) {
    __shared__ float s_cat[8][2 * HDIM];
    __shared__ float s_u[8][HDIM];
    int nb = blockIdx.x * 8, j = threadIdx.x;
    const size_t w1o = (size_t)layer * 2 * HDIM * HDIM;
    const size_t w2o = (size_t)layer * HDIM * HDIM;
    const size_t bo  = (size_t)layer * HDIM;

#pragma unroll
    for (int e = 0; e < 8; ++e) {
        s_cat[e][j] = h_feat[(size_t)(nb + e) * HDIM + j];
        s_cat[e][HDIM + j] = agg_h[(size_t)(nb + e) * HDIM + j];
        agg_h[(size_t)(nb + e) * HDIM + j] = 0.f;   // re-zero for next layer
    }
    __syncthreads();

    float u[8];
    float b1 = nb1p[bo + j];
#pragma unroll
    for (int e = 0; e < 8; ++e) u[e] = b1;
    for (int i0 = 0; i0 < 2 * HDIM; i0 += 2) {
        float w0 = n1p[w1o + (size_t)i0 * HDIM + j];
        float w1 = n1p[w1o + (size_t)(i0 + 1) * HDIM + j];
#pragma unroll
        for (int e = 0; e < 8; ++e)
            u[e] += s_cat[e][i0] * w0 + s_cat[e][i0 + 1] * w1;
    }
#pragma unroll
    for (int e = 0; e < 8; ++e) s_u[e][j] = silu_f(u[e]);
    __syncthreads();

    float acc[8];
    float b2 = nb2p[bo + j];
#pragma unroll
    for (int e = 0; e < 8; ++e) acc[e] = b2;
    for (int i0 = 0; i0 < HDIM; i0 += 2) {
        float w0 = n2p[w2o + (size_t)i0 * HDIM + j];
        float w1 = n2p[w2o + (size_t)(i0 + 1) * HDIM + j];
#pragma unroll
        for (int e = 0; e < 8; ++e)
            acc[e] += s_u[e][i0] * w0 + s_u[e][i0 + 1] * w1;
    }
#pragma unroll
    for (int e = 0; e < 8; ++e) {
        float nh = s_cat[e][j] + acc[e];
        h_feat[(size_t)(nb + e) * HDIM + j] = nh;
        split_f16(nh, hbf_hi[(size_t)(nb + e) * HDIM + j], hbf_lo[(size_t)(nb + e) * HDIM + j]);
    }
    if (j < 24) {
        int e = j / 3, c = j - e * 3;
        float ax = agg_x[(nb + e) * 3 + c];
        agg_x[(nb + e) * 3 + c] = 0.f;   // re-zero for next layer
        x_cur[(nb + e) * 3 + c] += ax * mask[nb + e];
    }
}

__global__ void out_kernel(const float* __restrict__ x_cur, const float* __restrict__ x_in,
                           const float* __restrict__ mask, float* __restrict__ out) {
    int idx = blockIdx.x * blockDim.x + threadIdx.x;
    if (idx < N_NODES * 3) {
        int n = idx / 3;
        out[idx] = (x_cur[idx] - x_in[idx]) * mask[n];
    }
}

extern "C" void kernel_launch(void* const* d_in, const int* in_sizes, int n_in,
                              void* d_out, int out_size, void* d_ws, size_t ws_size,
                              hipStream_t stream) {
    const float* h    = (const float*)d_in[0];
    const float* x    = (const float*)d_in[1];
    const int*   ei   = (const int*)d_in[2];
    const float* ea   = (const float*)d_in[3];
    const float* t    = (const float*)d_in[4];
    const float* mask = (const float*)d_in[5];
    const float* tw1  = (const float*)d_in[6];
    const float* tb1  = (const float*)d_in[7];
    const float* tw2  = (const float*)d_in[8];
    const float* tb2  = (const float*)d_in[9];
    const float* new_ = (const float*)d_in[10];
    const float* neb  = (const float*)d_in[11];
    const float* eew  = (const float*)d_in[12];
    const float* eeb  = (const float*)d_in[13];
    const float* ew1  = (const float*)d_in[14];
    const float* eb1  = (const float*)d_in[15];
    const float* ew2  = (const float*)d_in[16];
    const float* eb2  = (const float*)d_in[17];
    const float* cw1  = (const float*)d_in[18];
    const float* cb1  = (const float*)d_in[19];
    const float* cw2  = (const float*)d_in[20];
    const float* nw1  = (const float*)d_in[21];
    const float* nb1  = (const float*)d_in[22];
    const float* nw2  = (const float*)d_in[23];
    const float* nb2  = (const float*)d_in[24];

    // ---- workspace carve-out (256 B aligned) ----
    char* p = (char*)d_ws;
    auto alloc = [&](size_t bytes) -> char* {
        char* r = p;
        p += (bytes + 255) & ~(size_t)255;
        return r;
    };
    float* t_emb    = (float*)alloc(HDIM * 4);
    float* h_feat   = (float*)alloc((size_t)N_NODES * HDIM * 4);
    float* x_cur    = (float*)alloc((size_t)N_NODES * 3 * 4);
    float* agg_h    = (float*)alloc((size_t)N_NODES * HDIM * 4);
    float* agg_x    = (float*)alloc((size_t)N_NODES * 3 * 4);
    float* bias1c   = (float*)alloc(NLAYERS * HDIM * 4);
    ushort_t* hbf_hi = (ushort_t*)alloc((size_t)N_NODES * HDIM * 2);
    ushort_t* hbf_lo = (ushort_t*)alloc((size_t)N_NODES * HDIM * 2);
    ushort_t* wf_hi  = (ushort_t*)alloc((size_t)NLAYERS * 4 * 16384 * 2);
    ushort_t* wf_lo  = (ushort_t*)alloc((size_t)NLAYERS * 4 * 16384 * 2);
    ushort_t* g_hi   = (ushort_t*)alloc((size_t)NLAYERS * 4096 * 2);
    ushort_t* g_lo   = (ushort_t*)alloc((size_t)NLAYERS * 4096 * 2);
    int* deg        = (int*)alloc((size_t)N_NODES * 4);
    int* row_start  = (int*)alloc((size_t)(N_NODES + 1) * 4);
    int* cursor     = (int*)alloc((size_t)N_NODES * 4);
    int* csr_eid    = (int*)alloc((size_t)N_EDGES * 4);
    int* rows_s     = (int*)alloc((size_t)N_EDGES * 4);
    int* cols_s     = (int*)alloc((size_t)N_EDGES * 4);
    ushort_t* eah   = (ushort_t*)alloc((size_t)N_EDGES * EDGE_IN * 2);
    ushort_t* eal   = (ushort_t*)alloc((size_t)N_EDGES * EDGE_IN * 2);

    // single zero-init spans agg_h..agg_x (adjacent); node_kernel re-zeroes each layer
    size_t agg_span = (size_t)((char*)(agg_x + (size_t)N_NODES * 3) - (char*)agg_h);

    repack_weights<<<(NLAYERS * 4 * 16384 + 255) / 256, 256, 0, stream>>>(ew1, ew2, cw1, wf_hi, wf_lo);
    prep_g<<<(NLAYERS * 4096 + NLAYERS * 128 + 255) / 256, 256, 0, stream>>>(eew, eeb, ew1, eb1, g_hi, g_lo, bias1c);
    temb_kernel<<<1, HDIM, 0, stream>>>(t, tw1, tb1, tw2, tb2, t_emb);
    hfeat_kernel<<<(N_NODES + 7) / 8, 128, 0, stream>>>(h, new_, neb, t_emb, h_feat, hbf_hi, hbf_lo);
    xinit_kernel<<<(N_NODES * 3 + 255) / 256, 256, 0, stream>>>(x, x_cur);
    hipMemsetAsync(agg_h, 0, agg_span, stream);

    hipMemsetAsync(deg, 0, (size_t)N_NODES * 4, stream);
    deg_kernel<<<(N_EDGES + 255) / 256, 256, 0, stream>>>(ei, deg);
    scan_kernel<<<1, 256, 0, stream>>>(deg, row_start, cursor);
    scatter_kernel<<<(N_EDGES + 255) / 256, 256, 0, stream>>>(ei, cursor, csr_eid);
    prep_edges<<<(N_EDGES + 255) / 256, 256, 0, stream>>>(ei, csr_eid, ea, rows_s, cols_s, eah, eal);

    for (int l = 0; l < NLAYERS; ++l) {
        edge_mfma_kernel<<<N_EDGES / 32, 64, 0, stream>>>(
            rows_s, cols_s, eah, eal, x_cur, hbf_hi, hbf_lo, wf_hi, wf_lo, g_hi, g_lo, bias1c,
            eb2, cb1, cw2, l, agg_h, agg_x);
        node_kernel<<<N_NODES / 8, 128, 0, stream>>>(
            h_feat, x_cur, hbf_hi, hbf_lo, agg_h, agg_x, mask, nw1, nb1, nw2, nb2, l);
    }

    out_kernel<<<(N_NODES * 3 + 255) / 256, 256, 0, stream>>>(x_cur, x, mask, (float*)d_out);
}